// Round 1
// 33362.146 us; speedup vs baseline: 1.0674x; 1.0674x over previous
//
#include <hip/hip_runtime.h>
#include <hip/hip_bf16.h>
#include <cmath>

#define DEVI __device__ __forceinline__

constexpr int B_   = 4;
constexpr int M_   = 2048;
constexpr int C_   = 256;
constexpr int H_   = 4;
constexpr int HD_  = 64;
constexpr int L_   = 9;
constexpr int TOK_ = B_ * M_;     // 8192
constexpr int C2_  = 2 * C_;      // 512
constexpr int C3_  = 3 * C_;      // 768
constexpr int NS_  = 2049;        // scores dim

typedef __attribute__((ext_vector_type(8))) short s16x8;
typedef __attribute__((ext_vector_type(4))) float f32x4;
typedef __attribute__((ext_vector_type(4))) unsigned short u16x4;

// ---------------------------------------------------------------- helpers
DEVI float logsig_f(float x) {
  if (x >= 0.0f) return -log1pf(__expf(-x));
  return x - log1pf(__expf(x));
}

DEVI float gelu_tanh(float x) {
  float x3 = x * x * x;
  float t = tanhf(0.7978845608028654f * (x + 0.044715f * x3));
  return 0.5f * x * (1.0f + t);
}

DEVI unsigned short f2bf(float x) {            // RNE fp32 -> bf16
  unsigned u = __float_as_uint(x);
  u += 0x7fffu + ((u >> 16) & 1u);
  return (unsigned short)(u >> 16);
}
DEVI float bf2f(unsigned short h) { return __uint_as_float((unsigned)h << 16); }

// ---------------------------------------------------------------- posenc (compact: 32 cos + 32 sin per token)
__global__ void posenc_kernel(const float* __restrict__ kpts, const float* __restrict__ wh,
                              const float* __restrict__ Wr, float* __restrict__ cc,
                              float* __restrict__ sc) {
  int idx = blockIdx.x * blockDim.x + threadIdx.x;   // B*M*32
  if (idx >= B_ * M_ * 32) return;
  int j  = idx & 31;
  int bm = idx >> 5;
  float w = wh[0], h = wh[1];
  float smax = fmaxf(w, h) * 0.5f;
  float kx = (kpts[bm * 2 + 0] - w * 0.5f) / smax;
  float ky = (kpts[bm * 2 + 1] - h * 0.5f) / smax;
  float p = kx * Wr[j] + ky * Wr[32 + j];
  cc[bm * 32 + j] = cosf(p);
  sc[bm * 32 + j] = sinf(p);
}

// ---------------------------------------------------------------- weight transpose + bf16 hi/lo split
// W [K][N] fp32 -> Th/Tl [N][K] bf16. Total elems = N<<kbits, multiple of 256.
__global__ void wconv_kernel(const float* __restrict__ W, unsigned short* __restrict__ Th,
                             unsigned short* __restrict__ Tl, int kbits, int N) {
  int idx = blockIdx.x * 256 + threadIdx.x;
  int k = idx & ((1 << kbits) - 1);
  int n = idx >> kbits;
  float x = W[(size_t)k * N + n];
  unsigned short h = f2bf(x);
  Th[idx] = h;
  Tl[idx] = f2bf(x - bf2f(h));
}

// ---------------------------------------------------------------- split-bf16 MFMA GEMM (fp32-accurate)
// out[m][n] = (sum_k A[m][k] * W[k][n] + bias[n]) * oscale (+ res[m][n])
// A fp32 (split in-kernel); W pre-transposed+split: WTh/WTl [N][K] bf16.
// A = A1 rows for k < kSplit, A2 rows for k >= kSplit (cat support), both row stride lda.
// Tile: BM=128, BN=64, BK=64. 4 waves (2Mx2N), wave tile 64x32, frags 4x2.
__global__ __launch_bounds__(256, 3) void mgemm_kernel(
    const float* __restrict__ A1, const float* __restrict__ A2, int lda, int kSplit,
    const unsigned short* __restrict__ WTh, const unsigned short* __restrict__ WTl,
    const float* __restrict__ bias, const float* res, float* out,
    int K, int N, float oscale) {
  __shared__ alignas(16) unsigned short Ash[128 * 64];
  __shared__ alignas(16) unsigned short Asl[128 * 64];
  __shared__ alignas(16) unsigned short Bsh[64 * 64];
  __shared__ alignas(16) unsigned short Bsl[64 * 64];
  int tid = threadIdx.x;
  int rowBase = blockIdx.y << 7;
  int colBase = blockIdx.x << 6;
  int lr = tid & 15, lg = (tid >> 4) & 3;
  int wid = tid >> 6, wm = wid >> 1, wn = wid & 1;
  int sw = (lr & 7) << 3;                       // read-side XOR swizzle (elem units)
  f32x4 acc[4][2] = {};

  for (int k0 = 0; k0 < K; k0 += 64) {
    const float* Asrc;
    int kloc;
    if (k0 < kSplit) { Asrc = A1; kloc = k0; } else { Asrc = A2; kloc = k0 - kSplit; }
    __syncthreads();
    // stage A: 128x64 fp32 -> bf16 hi/lo planes (converted in flight)
#pragma unroll
    for (int i = 0; i < 8; i++) {
      int idx = tid + (i << 8);
      int r = idx >> 4;                         // 0..127
      int kc = (idx & 15) << 2;                 // 0..60
      float4 v = *(const float4*)(Asrc + (size_t)(rowBase + r) * lda + kloc + kc);
      unsigned short h0 = f2bf(v.x), h1 = f2bf(v.y), h2 = f2bf(v.z), h3 = f2bf(v.w);
      u16x4 hv = {h0, h1, h2, h3};
      u16x4 lv = {f2bf(v.x - bf2f(h0)), f2bf(v.y - bf2f(h1)),
                  f2bf(v.z - bf2f(h2)), f2bf(v.w - bf2f(h3))};
      int col = kc ^ ((r & 7) << 3);
      *(u16x4*)&Ash[r * 64 + col] = hv;
      *(u16x4*)&Asl[r * 64 + col] = lv;
    }
    // stage B: 64x64 bf16 hi/lo from pre-transposed weights
#pragma unroll
    for (int i = 0; i < 4; i++) {
      int idx = tid + (i << 8);
      int rn = idx >> 4;                        // 0..63
      int kc = (idx & 15) << 2;
      size_t g = (size_t)(colBase + rn) * K + k0 + kc;
      u16x4 hv = *(const u16x4*)(WTh + g);
      u16x4 lv = *(const u16x4*)(WTl + g);
      int col = kc ^ ((rn & 7) << 3);
      *(u16x4*)&Bsh[rn * 64 + col] = hv;
      *(u16x4*)&Bsl[rn * 64 + col] = lv;
    }
    __syncthreads();
#pragma unroll
    for (int c = 0; c < 2; c++) {
      int kcol = (c << 5) + (lg << 3);
      s16x8 ah[4], al[4], bh[2], bl[2];
#pragma unroll
      for (int mi = 0; mi < 4; mi++) {
        int off = (wm * 64 + mi * 16 + lr) * 64 + (kcol ^ sw);
        ah[mi] = *(const s16x8*)&Ash[off];
        al[mi] = *(const s16x8*)&Asl[off];
      }
#pragma unroll
      for (int ni = 0; ni < 2; ni++) {
        int off = (wn * 32 + ni * 16 + lr) * 64 + (kcol ^ sw);
        bh[ni] = *(const s16x8*)&Bsh[off];
        bl[ni] = *(const s16x8*)&Bsl[off];
      }
#pragma unroll
      for (int mi = 0; mi < 4; mi++)
#pragma unroll
        for (int ni = 0; ni < 2; ni++) {
          f32x4 t = acc[mi][ni];
          t = __builtin_amdgcn_mfma_f32_16x16x32_bf16(ah[mi], bl[ni], t, 0, 0, 0);
          t = __builtin_amdgcn_mfma_f32_16x16x32_bf16(al[mi], bh[ni], t, 0, 0, 0);
          t = __builtin_amdgcn_mfma_f32_16x16x32_bf16(ah[mi], bh[ni], t, 0, 0, 0);
          acc[mi][ni] = t;
        }
    }
  }
  // epilogue: C/D layout col = lane&15, row = (lane>>4)*4 + j
#pragma unroll
  for (int mi = 0; mi < 4; mi++) {
    int row0 = rowBase + wm * 64 + mi * 16 + lg * 4;
#pragma unroll
    for (int ni = 0; ni < 2; ni++) {
      int col = colBase + wn * 32 + ni * 16 + lr;
      float bc = bias[col];
#pragma unroll
      for (int j = 0; j < 4; j++) {
        size_t o = (size_t)(row0 + j) * N + col;
        float v = (acc[mi][ni][j] + bc) * oscale;
        if (res) v += res[o];
        out[o] = v;
      }
    }
  }
}

// ---------------------------------------------------------------- fused flash attention (fp32, unchanged this round)
__global__ __launch_bounds__(256) void flash_kernel(const float* __restrict__ Qb,
                                                    const float* __restrict__ Kb,
                                                    const float* __restrict__ Vb,
                                                    int ld, int qcol, int kcol, int vcol,
                                                    const float* __restrict__ cc,
                                                    const float* __restrict__ sc,
                                                    float* __restrict__ O, float scale) {
  __shared__ alignas(16) float Ks[64][68];
  __shared__ alignas(16) float Vs[64][68];
  __shared__ alignas(16) float Ps[64][68];
  int bh = blockIdx.y;
  int b = bh >> 2, h = bh & 3;
  int mBase = blockIdx.x * 64;
  size_t tokbase = (size_t)b * M_;
  const float* Qp = Qb + tokbase * ld + qcol + h * 64;
  const float* Kp = Kb + tokbase * ld + kcol + h * 64;
  const float* Vp = Vb + tokbase * ld + vcol + h * 64;
  const float* ccb = cc ? cc + tokbase * 32 : nullptr;
  const float* scb = sc ? sc + tokbase * 32 : nullptr;
  int tid = threadIdx.x;
  int r = tid >> 2, cq = tid & 3;

  float qreg[64];
  {
    int m = mBase + r;
    const float* qrow = Qp + (size_t)m * ld;
#pragma unroll
    for (int i = 0; i < 16; i++) {
      float4 t4 = *(const float4*)(qrow + 4 * i);
      if (ccb) {
        float2 c2 = *(const float2*)(ccb + (size_t)m * 32 + 2 * i);
        float2 s2 = *(const float2*)(scb + (size_t)m * 32 + 2 * i);
        float x0 = t4.x * c2.x - t4.y * s2.x;
        float y0 = t4.y * c2.x + t4.x * s2.x;
        float z0 = t4.z * c2.y - t4.w * s2.y;
        float w0 = t4.w * c2.y + t4.z * s2.y;
        t4 = make_float4(x0, y0, z0, w0);
      }
      qreg[4 * i] = t4.x; qreg[4 * i + 1] = t4.y;
      qreg[4 * i + 2] = t4.z; qreg[4 * i + 3] = t4.w;
    }
  }

  float m_run = -INFINITY, l_run = 0.0f;
  float acc[16];
#pragma unroll
  for (int i = 0; i < 16; i++) acc[i] = 0.0f;

  for (int t0 = 0; t0 < M_; t0 += 64) {
    __syncthreads();
#pragma unroll
    for (int i = 0; i < 4; i++) {
      int idx = tid + (i << 8);
      int rr = idx >> 4, dd = (idx & 15) << 2;
      int tok = t0 + rr;
      float4 kv = *(const float4*)(Kp + (size_t)tok * ld + dd);
      if (ccb) {
        float2 c2 = *(const float2*)(ccb + (size_t)tok * 32 + (dd >> 1));
        float2 s2 = *(const float2*)(scb + (size_t)tok * 32 + (dd >> 1));
        float x0 = kv.x * c2.x - kv.y * s2.x;
        float y0 = kv.y * c2.x + kv.x * s2.x;
        float z0 = kv.z * c2.y - kv.w * s2.y;
        float w0 = kv.w * c2.y + kv.z * s2.y;
        kv = make_float4(x0, y0, z0, w0);
      }
      *(float4*)&Ks[rr][dd] = kv;
      *(float4*)&Vs[rr][dd] = *(const float4*)(Vp + (size_t)tok * ld + dd);
    }
    __syncthreads();

    float sv[16];
#pragma unroll
    for (int jj = 0; jj < 16; jj++) {
      int j = cq * 16 + jj;
      const float4* krow = (const float4*)&Ks[j][0];
      float s = 0.0f;
#pragma unroll
      for (int d4 = 0; d4 < 16; d4++) {
        float4 kv = krow[d4];
        s += qreg[4 * d4] * kv.x + qreg[4 * d4 + 1] * kv.y +
             qreg[4 * d4 + 2] * kv.z + qreg[4 * d4 + 3] * kv.w;
      }
      sv[jj] = s * scale;
    }

    float mx = sv[0];
#pragma unroll
    for (int jj = 1; jj < 16; jj++) mx = fmaxf(mx, sv[jj]);
    mx = fmaxf(mx, __shfl_xor(mx, 1));
    mx = fmaxf(mx, __shfl_xor(mx, 2));
    float m_new = fmaxf(m_run, mx);
    float alpha = __expf(m_run - m_new);
    float lsum = 0.0f;
#pragma unroll
    for (int jj = 0; jj < 16; jj++) { sv[jj] = __expf(sv[jj] - m_new); lsum += sv[jj]; }
    lsum += __shfl_xor(lsum, 1);
    lsum += __shfl_xor(lsum, 2);
    l_run = l_run * alpha + lsum;
    m_run = m_new;
#pragma unroll
    for (int jj = 0; jj < 16; jj++) Ps[r][cq * 16 + jj] = sv[jj];
#pragma unroll
    for (int i = 0; i < 16; i++) acc[i] *= alpha;
    __syncthreads();

#pragma unroll 4
    for (int j = 0; j < 64; j++) {
      float p = Ps[r][j];
      const float4* vrow = (const float4*)&Vs[j][cq * 16];
#pragma unroll
      for (int i4 = 0; i4 < 4; i4++) {
        float4 vv = vrow[i4];
        acc[4 * i4]     += p * vv.x;
        acc[4 * i4 + 1] += p * vv.y;
        acc[4 * i4 + 2] += p * vv.z;
        acc[4 * i4 + 3] += p * vv.w;
      }
    }
  }

  float inv = 1.0f / l_run;
  float* Op = O + (tokbase + mBase + r) * C_ + h * 64 + cq * 16;
#pragma unroll
  for (int i = 0; i < 16; i++) Op[i] = acc[i] * inv;
}

// ---------------------------------------------------------------- LayerNorm + GELU
__global__ __launch_bounds__(256) void ln_gelu_kernel(float* __restrict__ h,
                                                      const float* __restrict__ g,
                                                      const float* __restrict__ beta) {
  __shared__ float red[4];
  int t = blockIdx.x, tid = threadIdx.x;
  float* hr = h + (size_t)t * C2_;
  float a = hr[tid], b2 = hr[tid + 256];
  float s = a + b2;
  for (int o = 1; o < 64; o <<= 1) s += __shfl_xor(s, o);
  if ((tid & 63) == 0) red[tid >> 6] = s;
  __syncthreads();
  float mu = (red[0] + red[1] + red[2] + red[3]) * (1.0f / 512.0f);
  __syncthreads();
  float da = a - mu, db = b2 - mu;
  s = da * da + db * db;
  for (int o = 1; o < 64; o <<= 1) s += __shfl_xor(s, o);
  if ((tid & 63) == 0) red[tid >> 6] = s;
  __syncthreads();
  float var = (red[0] + red[1] + red[2] + red[3]) * (1.0f / 512.0f);
  float rs = rsqrtf(var + 1e-5f);
  float xa = da * rs * g[tid] + beta[tid];
  float xb = db * rs * g[tid + 256] + beta[tid + 256];
  hr[tid]       = gelu_tanh(xa);
  hr[tid + 256] = gelu_tanh(xb);
}

// ---------------------------------------------------------------- z = d @ match_w + b, log_sigmoid(+/-)
__global__ __launch_bounds__(256) void z_kernel(const float* __restrict__ d,
                                                const float* __restrict__ mw,
                                                const float* __restrict__ mb,
                                                float* __restrict__ ls,
                                                float* __restrict__ lsn) {
  int row = blockIdx.x * 4 + (threadIdx.x >> 6);
  int lane = threadIdx.x & 63;
  const float4* dr = (const float4*)(d + (size_t)row * C_);
  float4 v = dr[lane];
  float4 w4 = ((const float4*)mw)[lane];
  float s = v.x * w4.x + v.y * w4.y + v.z * w4.z + v.w * w4.w;
  for (int o = 1; o < 64; o <<= 1) s += __shfl_xor(s, o);
  if (lane == 0) {
    float zz = s + mb[0];
    ls[row]  = logsig_f(zz);
    lsn[row] = logsig_f(-zz);
  }
}

// ---------------------------------------------------------------- fused matching-head pass
__global__ __launch_bounds__(256) void head_kernel(const float* __restrict__ A,
                                                   const float* __restrict__ Bm,
                                                   const float* __restrict__ addv,
                                                   const float* __restrict__ rowv,
                                                   float* __restrict__ lse_out,
                                                   float* __restrict__ max_out,
                                                   int* __restrict__ am_out,
                                                   float* __restrict__ scores_out,
                                                   int mode) {
  __shared__ alignas(16) float As[16][68];
  __shared__ alignas(16) float Bs[16][68];
  int tid = threadIdx.x;
  int ty = tid >> 4, tx = tid & 15;
  int mBase = blockIdx.x << 6;
  int b = blockIdx.y;
  const float* Ab = A + (size_t)b * M_ * C_;
  const float* Bb = Bm + (size_t)b * M_ * C_;
  const float* addb = addv ? addv + (size_t)b * M_ : nullptr;
  const float* rowb = rowv ? rowv + (size_t)b * M_ : nullptr;

  float on_m[4], on_l[4], bst[4];
  int bidx[4];
#pragma unroll
  for (int i = 0; i < 4; i++) {
    on_m[i] = -INFINITY; on_l[i] = 0.0f; bst[i] = -INFINITY; bidx[i] = 0x7fffffff;
  }
  float rterm[4];
#pragma unroll
  for (int i = 0; i < 4; i++)
    rterm[i] = rowb ? rowb[mBase + (ty << 2) + i] : 0.0f;

  for (int nTile = 0; nTile < 32; nTile++) {
    int nBase = nTile << 6;
    float acc[4][4] = {};
    for (int k0 = 0; k0 < C_; k0 += 16) {
      __syncthreads();
#pragma unroll
      for (int i = 0; i < 4; i++) {
        int idx = tid + (i << 8);
        int r = idx >> 4, kk = idx & 15;
        As[kk][r] = Ab[(size_t)(mBase + r) * C_ + (k0 + kk)];
        Bs[kk][r] = Bb[(size_t)(nBase + r) * C_ + (k0 + kk)];
      }
      __syncthreads();
#pragma unroll
      for (int kk = 0; kk < 16; kk++) {
        float4 a4 = *(const float4*)&As[kk][ty << 2];
        float4 b4 = *(const float4*)&Bs[kk][tx << 2];
        float a[4] = {a4.x, a4.y, a4.z, a4.w};
        float bb[4] = {b4.x, b4.y, b4.z, b4.w};
#pragma unroll
        for (int i = 0; i < 4; i++)
#pragma unroll
          for (int j = 0; j < 4; j++) acc[i][j] += a[i] * bb[j];
      }
    }
    if (mode == 0) {
#pragma unroll
      for (int i = 0; i < 4; i++)
#pragma unroll
        for (int j = 0; j < 4; j++) {
          float s = acc[i][j];
          if (s > on_m[i]) {
            on_l[i] = on_l[i] * __expf(on_m[i] - s) + 1.0f;
            on_m[i] = s;
          } else {
            on_l[i] += __expf(s - on_m[i]);
          }
        }
    } else {
      float addn[4];
#pragma unroll
      for (int j = 0; j < 4; j++)
        addn[j] = addb ? addb[nBase + (tx << 2) + j] : 0.0f;
#pragma unroll
      for (int i = 0; i < 4; i++)
#pragma unroll
        for (int j = 0; j < 4; j++) {
          float v = 2.0f * acc[i][j] + addn[j];
          int n = nBase + (tx << 2) + j;
          if (v > bst[i]) { bst[i] = v; bidx[i] = n; }
        }
      if (mode == 1) {
#pragma unroll
        for (int i = 0; i < 4; i++) {
          size_t ro = ((size_t)(b * NS_ + mBase + (ty << 2) + i)) * NS_ + nBase + (tx << 2);
#pragma unroll
          for (int j = 0; j < 4; j++)
            scores_out[ro + j] = 2.0f * acc[i][j] + rterm[i] + addn[j];
        }
      }
    }
  }

  if (mode == 0) {
#pragma unroll
    for (int i = 0; i < 4; i++) {
      float Mv = on_m[i], Lv = on_l[i];
      for (int off = 1; off < 16; off <<= 1) {
        float M2 = __shfl_xor(Mv, off);
        float L2 = __shfl_xor(Lv, off);
        float Mn = fmaxf(Mv, M2);
        Lv = Lv * __expf(Mv - Mn) + L2 * __expf(M2 - Mn);
        Mv = Mn;
      }
      if (tx == 0) lse_out[(size_t)b * M_ + mBase + (ty << 2) + i] = Mv + logf(Lv);
    }
  } else {
#pragma unroll
    for (int i = 0; i < 4; i++) {
      float v = bst[i];
      int ix = bidx[i];
      for (int off = 1; off < 16; off <<= 1) {
        float v2 = __shfl_xor(v, off);
        int i2 = __shfl_xor(ix, off);
        if (v2 > v || (v2 == v && i2 < ix)) { v = v2; ix = i2; }
      }
      if (tx == 0) {
        size_t o = (size_t)b * M_ + mBase + (ty << 2) + i;
        am_out[o] = ix;
        if (mode == 1) max_out[o] = v + rterm[i];
      }
    }
  }
}

// ---------------------------------------------------------------- row/col additive terms
__global__ void rcterm_kernel(const float* __restrict__ ls0, const float* __restrict__ lse2,
                              const float* __restrict__ ls1, const float* __restrict__ lse1,
                              float* __restrict__ rt, float* __restrict__ ct) {
  int i = blockIdx.x * blockDim.x + threadIdx.x;
  if (i < B_ * M_) { rt[i] = ls0[i] - lse2[i]; ct[i] = ls1[i] - lse1[i]; }
}

// ---------------------------------------------------------------- scores edges
__global__ void edge_kernel(const float* __restrict__ lsn0, const float* __restrict__ lsn1,
                            float* __restrict__ sco) {
  int i = blockIdx.x * blockDim.x + threadIdx.x;   // B*2048
  if (i >= B_ * M_) return;
  int b = i >> 11, t = i & 2047;
  sco[((size_t)b * NS_ + t) * NS_ + 2048] = lsn0[i];
  sco[((size_t)b * NS_ + 2048) * NS_ + t] = lsn1[i];
  if (t == 0) sco[((size_t)b * NS_ + 2048) * NS_ + 2048] = 0.0f;
}

// ---------------------------------------------------------------- mscores0 / valid0 (workspace)
__global__ void match0ws_kernel(const int* __restrict__ am0, const int* __restrict__ am1,
                                const float* __restrict__ max0, float* __restrict__ ms0f,
                                int* __restrict__ val0) {
  int i = blockIdx.x * blockDim.x + threadIdx.x;
  if (i >= B_ * M_) return;
  int b = i >> 11, m = i & 2047;
  int a0 = am0[i];
  bool mutual = (am1[b * M_ + a0] == m);
  float ms = mutual ? __expf(max0[i]) : 0.0f;
  ms0f[i] = ms;
  val0[i] = (mutual && ms > 0.1f) ? 1 : 0;
}

// ---------------------------------------------------------------- final small outputs
__global__ void finalout_kernel(const int* __restrict__ am0, const int* __restrict__ am1,
                                const float* __restrict__ ms0f, const int* __restrict__ val0,
                                float* __restrict__ out) {
  int i = blockIdx.x * blockDim.x + threadIdx.x;
  if (i >= B_ * M_) return;
  int b = i >> 11, t = i & 2047;
  int a0 = am0[i];
  bool mut0 = (am1[b * M_ + a0] == t);
  float ms0 = ms0f[i];
  bool v0 = mut0 && (ms0 > 0.1f);
  out[i] = v0 ? (float)a0 : -1.0f;                  // m0
  out[2 * B_ * M_ + i] = ms0;                       // mscores0
  int a1 = am1[i];
  bool mut1 = (am0[b * M_ + a1] == t);
  float ms1 = mut1 ? ms0f[b * M_ + a1] : 0.0f;
  bool v1 = mut1 && (val0[b * M_ + a1] != 0);
  out[B_ * M_ + i] = v1 ? (float)a1 : -1.0f;        // m1
  out[3 * B_ * M_ + i] = ms1;                       // mscores1
}

// ================================================================ host
// per-layer transposed-weight element offsets (per plane)
constexpr size_t WOFF_QKV   = 0;                         // 768x256
constexpr size_t WOFF_SAOUT = 196608;                    // 256x256
constexpr size_t WOFF_SAW1  = 262144;                    // 512x512
constexpr size_t WOFF_SAW2  = 524288;                    // 256x512
constexpr size_t WOFF_CAQK  = 655360;                    // 256x256
constexpr size_t WOFF_CAV   = 720896;                    // 256x256
constexpr size_t WOFF_CAOUT = 786432;                    // 256x256
constexpr size_t WOFF_CAW1  = 851968;                    // 512x512
constexpr size_t WOFF_CAW2  = 1114112;                   // 256x512
constexpr size_t WELEMS_    = 1245184;

extern "C" void kernel_launch(void* const* d_in, const int* in_sizes, int n_in,
                              void* d_out, int out_size, void* d_ws, size_t ws_size,
                              hipStream_t stream) {
  const float* kpts0      = (const float*)d_in[0];
  const float* desc0      = (const float*)d_in[1];
  const float* kpts1      = (const float*)d_in[2];
  const float* desc1      = (const float*)d_in[3];
  const float* image_size = (const float*)d_in[4];
  const float* Wr         = (const float*)d_in[5];
  const float* saqkv_W    = (const float*)d_in[6];
  const float* saqkv_b    = (const float*)d_in[7];
  const float* saout_W    = (const float*)d_in[8];
  const float* saout_b    = (const float*)d_in[9];
  const float* saff_W1    = (const float*)d_in[10];
  const float* saff_b1    = (const float*)d_in[11];
  const float* saff_g     = (const float*)d_in[12];
  const float* saff_beta  = (const float*)d_in[13];
  const float* saff_W2    = (const float*)d_in[14];
  const float* saff_b2    = (const float*)d_in[15];
  const float* caqk_W     = (const float*)d_in[16];
  const float* caqk_b     = (const float*)d_in[17];
  const float* cav_W      = (const float*)d_in[18];
  const float* cav_b      = (const float*)d_in[19];
  const float* caout_W    = (const float*)d_in[20];
  const float* caout_b    = (const float*)d_in[21];
  const float* caff_W1    = (const float*)d_in[22];
  const float* caff_b1    = (const float*)d_in[23];
  const float* caff_g     = (const float*)d_in[24];
  const float* caff_beta  = (const float*)d_in[25];
  const float* caff_W2    = (const float*)d_in[26];
  const float* caff_b2    = (const float*)d_in[27];
  const float* fproj_W    = (const float*)d_in[28];
  const float* fproj_b    = (const float*)d_in[29];
  const float* match_w    = (const float*)d_in[30];
  const float* match_b    = (const float*)d_in[31];

  // FP32 output layout: m0@0, m1@8192, mscores0@16384, mscores1@24576, scores@32768
  float* ofp = (float*)d_out;
  float* SCO = ofp + 4 * B_ * M_;

  // ---------------- workspace layout: 7.5N floats ~ 63 MB
  constexpr size_t N = (size_t)TOK_ * C_;           // 2,097,152 floats
  constexpr size_t Qc = (size_t)B_ * M_ * 32;
  float* Wp  = (float*)d_ws;
  float* D0  = Wp;
  float* D1  = D0 + N;
  float* CC0 = D1 + N;
  float* SC0 = CC0 + Qc;
  float* CC1 = SC0 + Qc;
  float* SC1 = CC1 + Qc;
  float* S0  = SC1 + Qc;
  float* S1  = S0 + N;
  float* S2  = S1 + N;
  float* S3  = S2 + N;
  float* S4  = S3 + N;

  // transposed+split weights live in the scores region of d_out (unused until
  // the final head pass, which is enqueued after every consumer of these).
  unsigned short* WTH = (unsigned short*)SCO;
  unsigned short* WTL = WTH + WELEMS_;

  // small final-phase arrays live in S2 (free during final phase)
  float* LS0  = S2;
  float* LSN0 = LS0 + 8192;
  float* LS1  = LSN0 + 8192;
  float* LSN1 = LS1 + 8192;
  float* LSE2 = LSN1 + 8192;
  float* LSE1 = LSE2 + 8192;
  float* RT   = LSE1 + 8192;
  float* CT   = RT + 8192;
  float* MAX0 = CT + 8192;
  float* MS0F = MAX0 + 8192;
  int*   AM0  = (int*)(MS0F + 8192);
  int*   AM1  = AM0 + 8192;
  int*   VAL0 = AM1 + 8192;

  auto wconv = [&](const float* src, size_t off, int kbits, int Ncols) {
    wconv_kernel<<<(Ncols << kbits) >> 8, 256, 0, stream>>>(src, WTH + off, WTL + off, kbits, Ncols);
  };

  auto mgemm = [&](const float* A1, const float* A2, int lda, int kSplit, size_t woff,
                   const float* bias, const float* res, float* out, int K, int Ncols, float osc) {
    mgemm_kernel<<<dim3(Ncols >> 6, TOK_ >> 7), 256, 0, stream>>>(
        A1, A2, lda, kSplit, WTH + woff, WTL + woff, bias, res, out, K, Ncols, osc);
  };

  auto ffn = [&](float* X, const float* msg_tok, size_t offW1, const float* b1,
                 const float* g, const float* be, size_t offW2, const float* b2) {
    mgemm(X, msg_tok, C_, C_, offW1, b1, nullptr, S0, C2_, C2_, 1.0f);
    ln_gelu_kernel<<<TOK_, 256, 0, stream>>>(S0, g, be);
    mgemm(S0, S0, C2_, C2_, offW2, b2, X, X, C2_, C_, 1.0f);
  };

  auto self_block = [&](float* X, const float* cc, const float* sc, int l) {
    const float* bqkv = saqkv_b + (size_t)l * C3_;
    const float* bo   = saout_b + (size_t)l * C_;
    mgemm(X, X, C_, C_, WOFF_QKV, bqkv, nullptr, S0, C_, C3_, 1.0f);   // QKV in S0..S2
    flash_kernel<<<dim3(M_ / 64, B_ * H_), 256, 0, stream>>>(
        S0, S0, S0, C3_, 0, C_, C2_, cc, sc, S3, 0.125f);
    mgemm(S3, S3, C_, C_, WOFF_SAOUT, bo, nullptr, S4, C_, C_, 1.0f);
    ffn(X, S4, WOFF_SAW1, saff_b1 + (size_t)l * C2_,
        saff_g + (size_t)l * C2_, saff_beta + (size_t)l * C2_,
        WOFF_SAW2, saff_b2 + (size_t)l * C_);
  };

  auto cross_block = [&](int l) {
    const float* bqk = caqk_b + (size_t)l * C_;
    const float* bv  = cav_b + (size_t)l * C_;
    const float* bo  = caout_b + (size_t)l * C_;
    const float* b1  = caff_b1 + (size_t)l * C2_;
    const float* g   = caff_g + (size_t)l * C2_;
    const float* be  = caff_beta + (size_t)l * C2_;
    const float* b2  = caff_b2 + (size_t)l * C_;
    mgemm(D0, D0, C_, C_, WOFF_CAQK, bqk, nullptr, S0, C_, C_, 1.0f);
    mgemm(D1, D1, C_, C_, WOFF_CAQK, bqk, nullptr, S1, C_, C_, 1.0f);
    mgemm(D0, D0, C_, C_, WOFF_CAV, bv, nullptr, S2, C_, C_, 1.0f);
    mgemm(D1, D1, C_, C_, WOFF_CAV, bv, nullptr, S3, C_, C_, 1.0f);
    flash_kernel<<<dim3(M_ / 64, B_ * H_), 256, 0, stream>>>(
        S0, S1, S3, C_, 0, 0, 0, nullptr, nullptr, S4, 0.125f);   // m0 -> S4
    flash_kernel<<<dim3(M_ / 64, B_ * H_), 256, 0, stream>>>(
        S1, S0, S2, C_, 0, 0, 0, nullptr, nullptr, S3, 0.125f);   // m1 -> S3
    mgemm(S4, S4, C_, C_, WOFF_CAOUT, bo, nullptr, S2, C_, C_, 1.0f);  // ao0 -> S2
    mgemm(S3, S3, C_, C_, WOFF_CAOUT, bo, nullptr, S4, C_, C_, 1.0f);  // ao1 -> S4
    ffn(D0, S2, WOFF_CAW1, b1, g, be, WOFF_CAW2, b2);
    ffn(D1, S4, WOFF_CAW1, b1, g, be, WOFF_CAW2, b2);
  };

  // ---------------- pipeline
  hipMemcpyAsync(D0, desc0, N * sizeof(float), hipMemcpyDeviceToDevice, stream);
  hipMemcpyAsync(D1, desc1, N * sizeof(float), hipMemcpyDeviceToDevice, stream);
  posenc_kernel<<<(B_ * M_ * 32 + 255) / 256, 256, 0, stream>>>(kpts0, image_size, Wr, CC0, SC0);
  posenc_kernel<<<(B_ * M_ * 32 + 255) / 256, 256, 0, stream>>>(kpts1, image_size, Wr, CC1, SC1);

  for (int l = 0; l < L_; l++) {
    // convert this layer's weights (rotating buffer in SCO region)
    wconv(saqkv_W + (size_t)l * C_ * C3_, WOFF_QKV, 8, C3_);
    wconv(saout_W + (size_t)l * C_ * C_, WOFF_SAOUT, 8, C_);
    wconv(saff_W1 + (size_t)l * C2_ * C2_, WOFF_SAW1, 9, C2_);
    wconv(saff_W2 + (size_t)l * C2_ * C_, WOFF_SAW2, 9, C_);
    wconv(caqk_W + (size_t)l * C_ * C_, WOFF_CAQK, 8, C_);
    wconv(cav_W + (size_t)l * C_ * C_, WOFF_CAV, 8, C_);
    wconv(caout_W + (size_t)l * C_ * C_, WOFF_CAOUT, 8, C_);
    wconv(caff_W1 + (size_t)l * C2_ * C2_, WOFF_CAW1, 9, C2_);
    wconv(caff_W2 + (size_t)l * C2_ * C_, WOFF_CAW2, 9, C_);
    self_block(D0, CC0, SC0, l);
    self_block(D1, CC1, SC1, l);
    cross_block(l);
  }

  // ---------------- final matching head (fp32 sim recomputed per pass)
  wconv(fproj_W, 0, 8, C_);
  mgemm(D0, D0, C_, C_, 0, fproj_b, nullptr, S0, C_, C_, 0.25f);   // md0
  mgemm(D1, D1, C_, C_, 0, fproj_b, nullptr, S1, C_, C_, 0.25f);   // md1
  z_kernel<<<2048, 256, 0, stream>>>(D0, match_w, match_b, LS0, LSN0);
  z_kernel<<<2048, 256, 0, stream>>>(D1, match_w, match_b, LS1, LSN1);
  head_kernel<<<dim3(32, B_), 256, 0, stream>>>(S0, S1, nullptr, nullptr,
                                                LSE2, nullptr, nullptr, nullptr, 0);
  head_kernel<<<dim3(32, B_), 256, 0, stream>>>(S1, S0, nullptr, nullptr,
                                                LSE1, nullptr, nullptr, nullptr, 0);
  rcterm_kernel<<<32, 256, 0, stream>>>(LS0, LSE2, LS1, LSE1, RT, CT);
  head_kernel<<<dim3(32, B_), 256, 0, stream>>>(S0, S1, CT, RT,
                                                nullptr, MAX0, AM0, SCO, 1);
  head_kernel<<<dim3(32, B_), 256, 0, stream>>>(S1, S0, RT, nullptr,
                                                nullptr, nullptr, AM1, nullptr, 2);
  edge_kernel<<<32, 256, 0, stream>>>(LSN0, LSN1, SCO);
  match0ws_kernel<<<32, 256, 0, stream>>>(AM0, AM1, MAX0, MS0F, VAL0);
  finalout_kernel<<<32, 256, 0, stream>>>(AM0, AM1, MS0F, VAL0, ofp);

  (void)in_sizes; (void)n_in; (void)out_size; (void)ws_size;
}

// Round 2
// 12662.224 us; speedup vs baseline: 2.8125x; 2.6348x over previous
//
#include <hip/hip_runtime.h>
#include <hip/hip_bf16.h>
#include <cmath>

#define DEVI __device__ __forceinline__

constexpr int B_   = 4;
constexpr int M_   = 2048;
constexpr int C_   = 256;
constexpr int H_   = 4;
constexpr int HD_  = 64;
constexpr int L_   = 9;
constexpr int TOK_ = B_ * M_;     // 8192
constexpr int C2_  = 2 * C_;      // 512
constexpr int C3_  = 3 * C_;      // 768
constexpr int NS_  = 2049;        // scores dim

typedef __attribute__((ext_vector_type(8))) short s16x8;
typedef __attribute__((ext_vector_type(4))) float f32x4;
typedef __attribute__((ext_vector_type(4))) unsigned short u16x4;

// ---------------------------------------------------------------- helpers
DEVI float logsig_f(float x) {
  if (x >= 0.0f) return -log1pf(__expf(-x));
  return x - log1pf(__expf(x));
}

DEVI float gelu_tanh(float x) {
  float x3 = x * x * x;
  float t = 0.7978845608028654f * (x + 0.044715f * x3);
  // 0.5x(1+tanh(t)) == x / (1 + exp(-2t)) exactly
  return x / (1.0f + __expf(-2.0f * t));
}

DEVI unsigned short f2bf(float x) {            // RNE fp32 -> bf16
  unsigned u = __float_as_uint(x);
  u += 0x7fffu + ((u >> 16) & 1u);
  return (unsigned short)(u >> 16);
}
DEVI float bf2f(unsigned short h) { return __uint_as_float((unsigned)h << 16); }

// ---------------------------------------------------------------- posenc (compact: 32 cos + 32 sin per token)
__global__ void posenc_kernel(const float* __restrict__ kpts, const float* __restrict__ wh,
                              const float* __restrict__ Wr, float* __restrict__ cc,
                              float* __restrict__ sc) {
  int idx = blockIdx.x * blockDim.x + threadIdx.x;   // B*M*32
  if (idx >= B_ * M_ * 32) return;
  int j  = idx & 31;
  int bm = idx >> 5;
  float w = wh[0], h = wh[1];
  float smax = fmaxf(w, h) * 0.5f;
  float kx = (kpts[bm * 2 + 0] - w * 0.5f) / smax;
  float ky = (kpts[bm * 2 + 1] - h * 0.5f) / smax;
  float p = kx * Wr[j] + ky * Wr[32 + j];
  cc[bm * 32 + j] = cosf(p);
  sc[bm * 32 + j] = sinf(p);
}

// ---------------------------------------------------------------- weight transpose + bf16 hi/lo split
__global__ void wconv_kernel(const float* __restrict__ W, unsigned short* __restrict__ Th,
                             unsigned short* __restrict__ Tl, int kbits, int N) {
  int idx = blockIdx.x * 256 + threadIdx.x;
  int k = idx & ((1 << kbits) - 1);
  int n = idx >> kbits;
  float x = W[(size_t)k * N + n];
  unsigned short h = f2bf(x);
  Th[idx] = h;
  Tl[idx] = f2bf(x - bf2f(h));
}

// ---------------------------------------------------------------- split-bf16 MFMA GEMM (fp32-accurate)
__global__ __launch_bounds__(256, 3) void mgemm_kernel(
    const float* __restrict__ A1, const float* __restrict__ A2, int lda, int kSplit,
    const unsigned short* __restrict__ WTh, const unsigned short* __restrict__ WTl,
    const float* __restrict__ bias, const float* res, float* out,
    int K, int N, float oscale) {
  __shared__ alignas(16) unsigned short Ash[128 * 64];
  __shared__ alignas(16) unsigned short Asl[128 * 64];
  __shared__ alignas(16) unsigned short Bsh[64 * 64];
  __shared__ alignas(16) unsigned short Bsl[64 * 64];
  int tid = threadIdx.x;
  int rowBase = blockIdx.y << 7;
  int colBase = blockIdx.x << 6;
  int lr = tid & 15, lg = (tid >> 4) & 3;
  int wid = tid >> 6, wm = wid >> 1, wn = wid & 1;
  int sw = (lr & 7) << 3;
  f32x4 acc[4][2] = {};

  for (int k0 = 0; k0 < K; k0 += 64) {
    const float* Asrc;
    int kloc;
    if (k0 < kSplit) { Asrc = A1; kloc = k0; } else { Asrc = A2; kloc = k0 - kSplit; }
    __syncthreads();
#pragma unroll
    for (int i = 0; i < 8; i++) {
      int idx = tid + (i << 8);
      int r = idx >> 4;
      int kc = (idx & 15) << 2;
      float4 v = *(const float4*)(Asrc + (size_t)(rowBase + r) * lda + kloc + kc);
      unsigned short h0 = f2bf(v.x), h1 = f2bf(v.y), h2 = f2bf(v.z), h3 = f2bf(v.w);
      u16x4 hv = {h0, h1, h2, h3};
      u16x4 lv = {f2bf(v.x - bf2f(h0)), f2bf(v.y - bf2f(h1)),
                  f2bf(v.z - bf2f(h2)), f2bf(v.w - bf2f(h3))};
      int col = kc ^ ((r & 7) << 3);
      *(u16x4*)&Ash[r * 64 + col] = hv;
      *(u16x4*)&Asl[r * 64 + col] = lv;
    }
#pragma unroll
    for (int i = 0; i < 4; i++) {
      int idx = tid + (i << 8);
      int rn = idx >> 4;
      int kc = (idx & 15) << 2;
      size_t g = (size_t)(colBase + rn) * K + k0 + kc;
      u16x4 hv = *(const u16x4*)(WTh + g);
      u16x4 lv = *(const u16x4*)(WTl + g);
      int col = kc ^ ((rn & 7) << 3);
      *(u16x4*)&Bsh[rn * 64 + col] = hv;
      *(u16x4*)&Bsl[rn * 64 + col] = lv;
    }
    __syncthreads();
#pragma unroll
    for (int c = 0; c < 2; c++) {
      int kcol = (c << 5) + (lg << 3);
      s16x8 ah[4], al[4], bh[2], bl[2];
#pragma unroll
      for (int mi = 0; mi < 4; mi++) {
        int off = (wm * 64 + mi * 16 + lr) * 64 + (kcol ^ sw);
        ah[mi] = *(const s16x8*)&Ash[off];
        al[mi] = *(const s16x8*)&Asl[off];
      }
#pragma unroll
      for (int ni = 0; ni < 2; ni++) {
        int off = (wn * 32 + ni * 16 + lr) * 64 + (kcol ^ sw);
        bh[ni] = *(const s16x8*)&Bsh[off];
        bl[ni] = *(const s16x8*)&Bsl[off];
      }
#pragma unroll
      for (int mi = 0; mi < 4; mi++)
#pragma unroll
        for (int ni = 0; ni < 2; ni++) {
          f32x4 t = acc[mi][ni];
          t = __builtin_amdgcn_mfma_f32_16x16x32_bf16(ah[mi], bl[ni], t, 0, 0, 0);
          t = __builtin_amdgcn_mfma_f32_16x16x32_bf16(al[mi], bh[ni], t, 0, 0, 0);
          t = __builtin_amdgcn_mfma_f32_16x16x32_bf16(ah[mi], bh[ni], t, 0, 0, 0);
          acc[mi][ni] = t;
        }
    }
  }
#pragma unroll
  for (int mi = 0; mi < 4; mi++) {
    int row0 = rowBase + wm * 64 + mi * 16 + lg * 4;
#pragma unroll
    for (int ni = 0; ni < 2; ni++) {
      int col = colBase + wn * 32 + ni * 16 + lr;
      float bc = bias[col];
#pragma unroll
      for (int j = 0; j < 4; j++) {
        size_t o = (size_t)(row0 + j) * N + col;
        float v = (acc[mi][ni][j] + bc) * oscale;
        if (res) v += res[o];
        out[o] = v;
      }
    }
  }
}

// ---------------------------------------------------------------- split-bf16 MFMA flash attention
// 64 q-rows/block (4 waves x 16), K-tiles of 64, online softmax.
// Q in registers (RoPE+scale folded); K row-major LDS hi/lo (row-XOR swizzle);
// V transposed LDS Vt[d][key] hi/lo; P round-trips through LDS hi/lo.
__global__ __launch_bounds__(256, 2) void flashm_kernel(
    const float* __restrict__ Qb, const float* __restrict__ Kb,
    const float* __restrict__ Vb,
    int ld, int qcol, int kcol, int vcol,
    const float* __restrict__ cc, const float* __restrict__ sc,
    float* __restrict__ O, float scale) {
  __shared__ alignas(16) unsigned short Ksh[64 * 64];
  __shared__ alignas(16) unsigned short Ksl[64 * 64];
  __shared__ alignas(16) unsigned short Vth[64 * 64];
  __shared__ alignas(16) unsigned short Vtl[64 * 64];
  __shared__ alignas(16) unsigned short Ph[64 * 64];
  __shared__ alignas(16) unsigned short Pl[64 * 64];
  int bh = blockIdx.y;
  int b = bh >> 2, h = bh & 3;
  int mBase = blockIdx.x * 64;
  size_t tokbase = (size_t)b * M_;
  const float* Qp = Qb + tokbase * ld + qcol + h * 64;
  const float* Kp = Kb + tokbase * ld + kcol + h * 64;
  const float* Vp = Vb + tokbase * ld + vcol + h * 64;
  const float* ccb = cc ? cc + tokbase * 32 : nullptr;
  const float* scb = sc ? sc + tokbase * 32 : nullptr;
  int tid = threadIdx.x;
  int lane = tid & 63, w = tid >> 6;
  int lr = lane & 15, lg = lane >> 4;

  // ---- Q fragments in registers (A-operand: row=lr, k-chunk base lg*8), scale folded
  s16x8 qh[2], ql[2];
  {
    int m = mBase + w * 16 + lr;
    const float* qrow = Qp + (size_t)m * ld;
#pragma unroll
    for (int c = 0; c < 2; c++) {
      int d0 = c * 32 + lg * 8;
      float4 a = *(const float4*)(qrow + d0);
      float4 bq = *(const float4*)(qrow + d0 + 4);
      if (ccb) {
        float4 c4 = *(const float4*)(ccb + (size_t)m * 32 + (d0 >> 1));
        float4 s4 = *(const float4*)(scb + (size_t)m * 32 + (d0 >> 1));
        float ax = a.x * c4.x - a.y * s4.x, ay = a.y * c4.x + a.x * s4.x;
        float az = a.z * c4.y - a.w * s4.y, aw = a.w * c4.y + a.z * s4.y;
        float bx = bq.x * c4.z - bq.y * s4.z, by = bq.y * c4.z + bq.x * s4.z;
        float bz = bq.z * c4.w - bq.w * s4.w, bw = bq.w * c4.w + bq.z * s4.w;
        a = make_float4(ax, ay, az, aw); bq = make_float4(bx, by, bz, bw);
      }
      float v8[8] = {a.x, a.y, a.z, a.w, bq.x, bq.y, bq.z, bq.w};
      s16x8 hh, llv;
#pragma unroll
      for (int e = 0; e < 8; e++) {
        float xv = v8[e] * scale;
        unsigned short hb = f2bf(xv);
        hh[e] = (short)hb;
        llv[e] = (short)f2bf(xv - bf2f(hb));
      }
      qh[c] = hh; ql[c] = llv;
    }
  }

  float m_run[4], l_run[4];
  f32x4 oacc[4];
#pragma unroll
  for (int j = 0; j < 4; j++) { m_run[j] = -INFINITY; l_run[j] = 0.0f; }
#pragma unroll
  for (int g = 0; g < 4; g++) oacc[g] = (f32x4){0.f, 0.f, 0.f, 0.f};

  for (int t0 = 0; t0 < M_; t0 += 64) {
    __syncthreads();
    // ---- stage K (RoPE'd, row-major swizzled) and V^T, both split hi/lo
#pragma unroll
    for (int i = 0; i < 4; i++) {
      int idx = tid + (i << 8);
      int key = idx >> 4;
      int d0 = (idx & 15) << 2;
      int tok = t0 + key;
      float4 kv = *(const float4*)(Kp + (size_t)tok * ld + d0);
      if (ccb) {
        float2 c2 = *(const float2*)(ccb + (size_t)tok * 32 + (d0 >> 1));
        float2 s2 = *(const float2*)(scb + (size_t)tok * 32 + (d0 >> 1));
        float x0 = kv.x * c2.x - kv.y * s2.x;
        float y0 = kv.y * c2.x + kv.x * s2.x;
        float z0 = kv.z * c2.y - kv.w * s2.y;
        float w0 = kv.w * c2.y + kv.z * s2.y;
        kv = make_float4(x0, y0, z0, w0);
      }
      {
        unsigned short h0 = f2bf(kv.x), h1 = f2bf(kv.y), h2 = f2bf(kv.z), h3 = f2bf(kv.w);
        u16x4 hv = {h0, h1, h2, h3};
        u16x4 lv = {f2bf(kv.x - bf2f(h0)), f2bf(kv.y - bf2f(h1)),
                    f2bf(kv.z - bf2f(h2)), f2bf(kv.w - bf2f(h3))};
        int cswz = d0 ^ ((key & 7) << 3);
        *(u16x4*)&Ksh[key * 64 + cswz] = hv;
        *(u16x4*)&Ksl[key * 64 + cswz] = lv;
      }
      {
        float4 vv = *(const float4*)(Vp + (size_t)tok * ld + d0);
        float ve[4] = {vv.x, vv.y, vv.z, vv.w};
#pragma unroll
        for (int e = 0; e < 4; e++) {
          int d = d0 + e;
          unsigned short hb = f2bf(ve[e]);
          unsigned short lb = f2bf(ve[e] - bf2f(hb));
          int kk = key ^ (((d ^ (d >> 2)) & 7) << 3);
          Vth[d * 64 + kk] = hb;
          Vtl[d * 64 + kk] = lb;
        }
      }
    }
    __syncthreads();

    // ---- S = Q.K^T  (4 kcol-frags x 2 k-chunks x 3 split terms)
    f32x4 sacc[4];
#pragma unroll
    for (int f = 0; f < 4; f++) sacc[f] = (f32x4){0.f, 0.f, 0.f, 0.f};
#pragma unroll
    for (int f = 0; f < 4; f++) {
#pragma unroll
      for (int c = 0; c < 2; c++) {
        int key = f * 16 + lr;
        int kb = c * 32 + lg * 8;
        int off = key * 64 + (kb ^ ((key & 7) << 3));
        s16x8 kh = *(const s16x8*)&Ksh[off];
        s16x8 kl = *(const s16x8*)&Ksl[off];
        f32x4 t = sacc[f];
        t = __builtin_amdgcn_mfma_f32_16x16x32_bf16(qh[c], kl, t, 0, 0, 0);
        t = __builtin_amdgcn_mfma_f32_16x16x32_bf16(ql[c], kh, t, 0, 0, 0);
        t = __builtin_amdgcn_mfma_f32_16x16x32_bf16(qh[c], kh, t, 0, 0, 0);
        sacc[f] = t;
      }
    }

    // ---- online softmax (rows = lg*4+j, cols across lr and frags)
    float mnew[4], alpha[4], lsum[4];
#pragma unroll
    for (int j = 0; j < 4; j++) {
      float v = fmaxf(fmaxf(sacc[0][j], sacc[1][j]), fmaxf(sacc[2][j], sacc[3][j]));
      v = fmaxf(v, __shfl_xor(v, 1));
      v = fmaxf(v, __shfl_xor(v, 2));
      v = fmaxf(v, __shfl_xor(v, 4));
      v = fmaxf(v, __shfl_xor(v, 8));
      mnew[j] = fmaxf(m_run[j], v);
      alpha[j] = __expf(m_run[j] - mnew[j]);
      lsum[j] = 0.0f;
    }
#pragma unroll
    for (int f = 0; f < 4; f++) {
#pragma unroll
      for (int j = 0; j < 4; j++) {
        float p = __expf(sacc[f][j] - mnew[j]);
        lsum[j] += p;
        int row = w * 16 + lg * 4 + j;
        int col = (f * 16 + lr) ^ ((row & 7) << 3);
        unsigned short hb = f2bf(p);
        Ph[row * 64 + col] = hb;
        Pl[row * 64 + col] = f2bf(p - bf2f(hb));
      }
    }
#pragma unroll
    for (int j = 0; j < 4; j++) {
      float s = lsum[j];
      s += __shfl_xor(s, 1);
      s += __shfl_xor(s, 2);
      s += __shfl_xor(s, 4);
      s += __shfl_xor(s, 8);
      l_run[j] = l_run[j] * alpha[j] + s;
      m_run[j] = mnew[j];
    }
#pragma unroll
    for (int g = 0; g < 4; g++) {
      f32x4 t = oacc[g];
#pragma unroll
      for (int j = 0; j < 4; j++) t[j] *= alpha[j];
      oacc[g] = t;
    }

    // ---- O += P.V  (A = P rows (wave-private), B = Vt)
    s16x8 pah[2], pal[2];
#pragma unroll
    for (int c = 0; c < 2; c++) {
      int row = w * 16 + lr;
      int kb = (c * 32 + lg * 8) ^ ((row & 7) << 3);
      pah[c] = *(const s16x8*)&Ph[row * 64 + kb];
      pal[c] = *(const s16x8*)&Pl[row * 64 + kb];
    }
#pragma unroll
    for (int g = 0; g < 4; g++) {
#pragma unroll
      for (int c = 0; c < 2; c++) {
        int d = g * 16 + lr;
        int kb = (c * 32 + lg * 8) ^ (((d ^ (d >> 2)) & 7) << 3);
        s16x8 vh = *(const s16x8*)&Vth[d * 64 + kb];
        s16x8 vl = *(const s16x8*)&Vtl[d * 64 + kb];
        f32x4 t = oacc[g];
        t = __builtin_amdgcn_mfma_f32_16x16x32_bf16(pah[c], vl, t, 0, 0, 0);
        t = __builtin_amdgcn_mfma_f32_16x16x32_bf16(pal[c], vh, t, 0, 0, 0);
        t = __builtin_amdgcn_mfma_f32_16x16x32_bf16(pah[c], vh, t, 0, 0, 0);
        oacc[g] = t;
      }
    }
  }

  // ---- epilogue
#pragma unroll
  for (int j = 0; j < 4; j++) {
    float inv = 1.0f / l_run[j];
    int q = mBase + w * 16 + lg * 4 + j;
    float* Op = O + (tokbase + q) * C_ + h * 64;
#pragma unroll
    for (int g = 0; g < 4; g++)
      Op[g * 16 + lr] = oacc[g][j] * inv;
  }
}

// ---------------------------------------------------------------- LayerNorm + GELU
__global__ __launch_bounds__(256) void ln_gelu_kernel(float* __restrict__ h,
                                                      const float* __restrict__ g,
                                                      const float* __restrict__ beta) {
  __shared__ float red[4];
  int t = blockIdx.x, tid = threadIdx.x;
  float* hr = h + (size_t)t * C2_;
  float a = hr[tid], b2 = hr[tid + 256];
  float s = a + b2;
  for (int o = 1; o < 64; o <<= 1) s += __shfl_xor(s, o);
  if ((tid & 63) == 0) red[tid >> 6] = s;
  __syncthreads();
  float mu = (red[0] + red[1] + red[2] + red[3]) * (1.0f / 512.0f);
  __syncthreads();
  float da = a - mu, db = b2 - mu;
  s = da * da + db * db;
  for (int o = 1; o < 64; o <<= 1) s += __shfl_xor(s, o);
  if ((tid & 63) == 0) red[tid >> 6] = s;
  __syncthreads();
  float var = (red[0] + red[1] + red[2] + red[3]) * (1.0f / 512.0f);
  float rs = rsqrtf(var + 1e-5f);
  float xa = da * rs * g[tid] + beta[tid];
  float xb = db * rs * g[tid + 256] + beta[tid + 256];
  hr[tid]       = gelu_tanh(xa);
  hr[tid + 256] = gelu_tanh(xb);
}

// ---------------------------------------------------------------- z = d @ match_w + b, log_sigmoid(+/-)
__global__ __launch_bounds__(256) void z_kernel(const float* __restrict__ d,
                                                const float* __restrict__ mw,
                                                const float* __restrict__ mb,
                                                float* __restrict__ ls,
                                                float* __restrict__ lsn) {
  int row = blockIdx.x * 4 + (threadIdx.x >> 6);
  int lane = threadIdx.x & 63;
  const float4* dr = (const float4*)(d + (size_t)row * C_);
  float4 v = dr[lane];
  float4 w4 = ((const float4*)mw)[lane];
  float s = v.x * w4.x + v.y * w4.y + v.z * w4.z + v.w * w4.w;
  for (int o = 1; o < 64; o <<= 1) s += __shfl_xor(s, o);
  if (lane == 0) {
    float zz = s + mb[0];
    ls[row]  = logsig_f(zz);
    lsn[row] = logsig_f(-zz);
  }
}

// ---------------------------------------------------------------- fused matching-head pass
__global__ __launch_bounds__(256) void head_kernel(const float* __restrict__ A,
                                                   const float* __restrict__ Bm,
                                                   const float* __restrict__ addv,
                                                   const float* __restrict__ rowv,
                                                   float* __restrict__ lse_out,
                                                   float* __restrict__ max_out,
                                                   int* __restrict__ am_out,
                                                   float* __restrict__ scores_out,
                                                   int mode) {
  __shared__ alignas(16) float As[16][68];
  __shared__ alignas(16) float Bs[16][68];
  int tid = threadIdx.x;
  int ty = tid >> 4, tx = tid & 15;
  int mBase = blockIdx.x << 6;
  int b = blockIdx.y;
  const float* Ab = A + (size_t)b * M_ * C_;
  const float* Bb = Bm + (size_t)b * M_ * C_;
  const float* addb = addv ? addv + (size_t)b * M_ : nullptr;
  const float* rowb = rowv ? rowv + (size_t)b * M_ : nullptr;

  float on_m[4], on_l[4], bst[4];
  int bidx[4];
#pragma unroll
  for (int i = 0; i < 4; i++) {
    on_m[i] = -INFINITY; on_l[i] = 0.0f; bst[i] = -INFINITY; bidx[i] = 0x7fffffff;
  }
  float rterm[4];
#pragma unroll
  for (int i = 0; i < 4; i++)
    rterm[i] = rowb ? rowb[mBase + (ty << 2) + i] : 0.0f;

  for (int nTile = 0; nTile < 32; nTile++) {
    int nBase = nTile << 6;
    float acc[4][4] = {};
    for (int k0 = 0; k0 < C_; k0 += 16) {
      __syncthreads();
#pragma unroll
      for (int i = 0; i < 4; i++) {
        int idx = tid + (i << 8);
        int r = idx >> 4, kk = idx & 15;
        As[kk][r] = Ab[(size_t)(mBase + r) * C_ + (k0 + kk)];
        Bs[kk][r] = Bb[(size_t)(nBase + r) * C_ + (k0 + kk)];
      }
      __syncthreads();
#pragma unroll
      for (int kk = 0; kk < 16; kk++) {
        float4 a4 = *(const float4*)&As[kk][ty << 2];
        float4 b4 = *(const float4*)&Bs[kk][tx << 2];
        float a[4] = {a4.x, a4.y, a4.z, a4.w};
        float bb[4] = {b4.x, b4.y, b4.z, b4.w};
#pragma unroll
        for (int i = 0; i < 4; i++)
#pragma unroll
          for (int j = 0; j < 4; j++) acc[i][j] += a[i] * bb[j];
      }
    }
    if (mode == 0) {
#pragma unroll
      for (int i = 0; i < 4; i++)
#pragma unroll
        for (int j = 0; j < 4; j++) {
          float s = acc[i][j];
          if (s > on_m[i]) {
            on_l[i] = on_l[i] * __expf(on_m[i] - s) + 1.0f;
            on_m[i] = s;
          } else {
            on_l[i] += __expf(s - on_m[i]);
          }
        }
    } else {
      float addn[4];
#pragma unroll
      for (int j = 0; j < 4; j++)
        addn[j] = addb ? addb[nBase + (tx << 2) + j] : 0.0f;
#pragma unroll
      for (int i = 0; i < 4; i++)
#pragma unroll
        for (int j = 0; j < 4; j++) {
          float v = 2.0f * acc[i][j] + addn[j];
          int n = nBase + (tx << 2) + j;
          if (v > bst[i]) { bst[i] = v; bidx[i] = n; }
        }
      if (mode == 1) {
#pragma unroll
        for (int i = 0; i < 4; i++) {
          size_t ro = ((size_t)(b * NS_ + mBase + (ty << 2) + i)) * NS_ + nBase + (tx << 2);
#pragma unroll
          for (int j = 0; j < 4; j++)
            scores_out[ro + j] = 2.0f * acc[i][j] + rterm[i] + addn[j];
        }
      }
    }
  }

  if (mode == 0) {
#pragma unroll
    for (int i = 0; i < 4; i++) {
      float Mv = on_m[i], Lv = on_l[i];
      for (int off = 1; off < 16; off <<= 1) {
        float M2 = __shfl_xor(Mv, off);
        float L2 = __shfl_xor(Lv, off);
        float Mn = fmaxf(Mv, M2);
        Lv = Lv * __expf(Mv - Mn) + L2 * __expf(M2 - Mn);
        Mv = Mn;
      }
      if (tx == 0) lse_out[(size_t)b * M_ + mBase + (ty << 2) + i] = Mv + logf(Lv);
    }
  } else {
#pragma unroll
    for (int i = 0; i < 4; i++) {
      float v = bst[i];
      int ix = bidx[i];
      for (int off = 1; off < 16; off <<= 1) {
        float v2 = __shfl_xor(v, off);
        int i2 = __shfl_xor(ix, off);
        if (v2 > v || (v2 == v && i2 < ix)) { v = v2; ix = i2; }
      }
      if (tx == 0) {
        size_t o = (size_t)b * M_ + mBase + (ty << 2) + i;
        am_out[o] = ix;
        if (mode == 1) max_out[o] = v + rterm[i];
      }
    }
  }
}

// ---------------------------------------------------------------- row/col additive terms
__global__ void rcterm_kernel(const float* __restrict__ ls0, const float* __restrict__ lse2,
                              const float* __restrict__ ls1, const float* __restrict__ lse1,
                              float* __restrict__ rt, float* __restrict__ ct) {
  int i = blockIdx.x * blockDim.x + threadIdx.x;
  if (i < B_ * M_) { rt[i] = ls0[i] - lse2[i]; ct[i] = ls1[i] - lse1[i]; }
}

// ---------------------------------------------------------------- scores edges
__global__ void edge_kernel(const float* __restrict__ lsn0, const float* __restrict__ lsn1,
                            float* __restrict__ sco) {
  int i = blockIdx.x * blockDim.x + threadIdx.x;   // B*2048
  if (i >= B_ * M_) return;
  int b = i >> 11, t = i & 2047;
  sco[((size_t)b * NS_ + t) * NS_ + 2048] = lsn0[i];
  sco[((size_t)b * NS_ + 2048) * NS_ + t] = lsn1[i];
  if (t == 0) sco[((size_t)b * NS_ + 2048) * NS_ + 2048] = 0.0f;
}

// ---------------------------------------------------------------- mscores0 / valid0 (workspace)
__global__ void match0ws_kernel(const int* __restrict__ am0, const int* __restrict__ am1,
                                const float* __restrict__ max0, float* __restrict__ ms0f,
                                int* __restrict__ val0) {
  int i = blockIdx.x * blockDim.x + threadIdx.x;
  if (i >= B_ * M_) return;
  int b = i >> 11, m = i & 2047;
  int a0 = am0[i];
  bool mutual = (am1[b * M_ + a0] == m);
  float ms = mutual ? __expf(max0[i]) : 0.0f;
  ms0f[i] = ms;
  val0[i] = (mutual && ms > 0.1f) ? 1 : 0;
}

// ---------------------------------------------------------------- final small outputs
__global__ void finalout_kernel(const int* __restrict__ am0, const int* __restrict__ am1,
                                const float* __restrict__ ms0f, const int* __restrict__ val0,
                                float* __restrict__ out) {
  int i = blockIdx.x * blockDim.x + threadIdx.x;
  if (i >= B_ * M_) return;
  int b = i >> 11, t = i & 2047;
  int a0 = am0[i];
  bool mut0 = (am1[b * M_ + a0] == t);
  float ms0 = ms0f[i];
  bool v0 = mut0 && (ms0 > 0.1f);
  out[i] = v0 ? (float)a0 : -1.0f;                  // m0
  out[2 * B_ * M_ + i] = ms0;                       // mscores0
  int a1 = am1[i];
  bool mut1 = (am0[b * M_ + a1] == t);
  float ms1 = mut1 ? ms0f[b * M_ + a1] : 0.0f;
  bool v1 = mut1 && (val0[b * M_ + a1] != 0);
  out[B_ * M_ + i] = v1 ? (float)a1 : -1.0f;        // m1
  out[3 * B_ * M_ + i] = ms1;                       // mscores1
}

// ================================================================ host
constexpr size_t WOFF_QKV   = 0;                         // 768x256
constexpr size_t WOFF_SAOUT = 196608;                    // 256x256
constexpr size_t WOFF_SAW1  = 262144;                    // 512x512
constexpr size_t WOFF_SAW2  = 524288;                    // 256x512
constexpr size_t WOFF_CAQK  = 655360;                    // 256x256
constexpr size_t WOFF_CAV   = 720896;                    // 256x256
constexpr size_t WOFF_CAOUT = 786432;                    // 256x256
constexpr size_t WOFF_CAW1  = 851968;                    // 512x512
constexpr size_t WOFF_CAW2  = 1114112;                   // 256x512
constexpr size_t WELEMS_    = 1245184;

extern "C" void kernel_launch(void* const* d_in, const int* in_sizes, int n_in,
                              void* d_out, int out_size, void* d_ws, size_t ws_size,
                              hipStream_t stream) {
  const float* kpts0      = (const float*)d_in[0];
  const float* desc0      = (const float*)d_in[1];
  const float* kpts1      = (const float*)d_in[2];
  const float* desc1      = (const float*)d_in[3];
  const float* image_size = (const float*)d_in[4];
  const float* Wr         = (const float*)d_in[5];
  const float* saqkv_W    = (const float*)d_in[6];
  const float* saqkv_b    = (const float*)d_in[7];
  const float* saout_W    = (const float*)d_in[8];
  const float* saout_b    = (const float*)d_in[9];
  const float* saff_W1    = (const float*)d_in[10];
  const float* saff_b1    = (const float*)d_in[11];
  const float* saff_g     = (const float*)d_in[12];
  const float* saff_beta  = (const float*)d_in[13];
  const float* saff_W2    = (const float*)d_in[14];
  const float* saff_b2    = (const float*)d_in[15];
  const float* caqk_W     = (const float*)d_in[16];
  const float* caqk_b     = (const float*)d_in[17];
  const float* cav_W      = (const float*)d_in[18];
  const float* cav_b      = (const float*)d_in[19];
  const float* caout_W    = (const float*)d_in[20];
  const float* caout_b    = (const float*)d_in[21];
  const float* caff_W1    = (const float*)d_in[22];
  const float* caff_b1    = (const float*)d_in[23];
  const float* caff_g     = (const float*)d_in[24];
  const float* caff_beta  = (const float*)d_in[25];
  const float* caff_W2    = (const float*)d_in[26];
  const float* caff_b2    = (const float*)d_in[27];
  const float* fproj_W    = (const float*)d_in[28];
  const float* fproj_b    = (const float*)d_in[29];
  const float* match_w    = (const float*)d_in[30];
  const float* match_b    = (const float*)d_in[31];

  // FP32 output layout: m0@0, m1@8192, mscores0@16384, mscores1@24576, scores@32768
  float* ofp = (float*)d_out;
  float* SCO = ofp + 4 * B_ * M_;

  constexpr size_t N = (size_t)TOK_ * C_;           // 2,097,152 floats
  constexpr size_t Qc = (size_t)B_ * M_ * 32;
  float* Wp  = (float*)d_ws;
  float* D0  = Wp;
  float* D1  = D0 + N;
  float* CC0 = D1 + N;
  float* SC0 = CC0 + Qc;
  float* CC1 = SC0 + Qc;
  float* SC1 = CC1 + Qc;
  float* S0  = SC1 + Qc;
  float* S1  = S0 + N;
  float* S2  = S1 + N;
  float* S3  = S2 + N;
  float* S4  = S3 + N;

  unsigned short* WTH = (unsigned short*)SCO;
  unsigned short* WTL = WTH + WELEMS_;

  float* LS0  = S2;
  float* LSN0 = LS0 + 8192;
  float* LS1  = LSN0 + 8192;
  float* LSN1 = LS1 + 8192;
  float* LSE2 = LSN1 + 8192;
  float* LSE1 = LSE2 + 8192;
  float* RT   = LSE1 + 8192;
  float* CT   = RT + 8192;
  float* MAX0 = CT + 8192;
  float* MS0F = MAX0 + 8192;
  int*   AM0  = (int*)(MS0F + 8192);
  int*   AM1  = AM0 + 8192;
  int*   VAL0 = AM1 + 8192;

  auto wconv = [&](const float* src, size_t off, int kbits, int Ncols) {
    wconv_kernel<<<(Ncols << kbits) >> 8, 256, 0, stream>>>(src, WTH + off, WTL + off, kbits, Ncols);
  };

  auto mgemm = [&](const float* A1, const float* A2, int lda, int kSplit, size_t woff,
                   const float* bias, const float* res, float* out, int K, int Ncols, float osc) {
    mgemm_kernel<<<dim3(Ncols >> 6, TOK_ >> 7), 256, 0, stream>>>(
        A1, A2, lda, kSplit, WTH + woff, WTL + woff, bias, res, out, K, Ncols, osc);
  };

  auto ffn = [&](float* X, const float* msg_tok, size_t offW1, const float* b1,
                 const float* g, const float* be, size_t offW2, const float* b2) {
    mgemm(X, msg_tok, C_, C_, offW1, b1, nullptr, S0, C2_, C2_, 1.0f);
    ln_gelu_kernel<<<TOK_, 256, 0, stream>>>(S0, g, be);
    mgemm(S0, S0, C2_, C2_, offW2, b2, X, X, C2_, C_, 1.0f);
  };

  auto self_block = [&](float* X, const float* cc, const float* sc, int l) {
    const float* bqkv = saqkv_b + (size_t)l * C3_;
    const float* bo   = saout_b + (size_t)l * C_;
    mgemm(X, X, C_, C_, WOFF_QKV, bqkv, nullptr, S0, C_, C3_, 1.0f);   // QKV in S0..S2
    flashm_kernel<<<dim3(M_ / 64, B_ * H_), 256, 0, stream>>>(
        S0, S0, S0, C3_, 0, C_, C2_, cc, sc, S3, 0.125f);
    mgemm(S3, S3, C_, C_, WOFF_SAOUT, bo, nullptr, S4, C_, C_, 1.0f);
    ffn(X, S4, WOFF_SAW1, saff_b1 + (size_t)l * C2_,
        saff_g + (size_t)l * C2_, saff_beta + (size_t)l * C2_,
        WOFF_SAW2, saff_b2 + (size_t)l * C_);
  };

  auto cross_block = [&](int l) {
    const float* bqk = caqk_b + (size_t)l * C_;
    const float* bv  = cav_b + (size_t)l * C_;
    const float* bo  = caout_b + (size_t)l * C_;
    const float* b1  = caff_b1 + (size_t)l * C2_;
    const float* g   = caff_g + (size_t)l * C2_;
    const float* be  = caff_beta + (size_t)l * C2_;
    const float* b2  = caff_b2 + (size_t)l * C_;
    mgemm(D0, D0, C_, C_, WOFF_CAQK, bqk, nullptr, S0, C_, C_, 1.0f);
    mgemm(D1, D1, C_, C_, WOFF_CAQK, bqk, nullptr, S1, C_, C_, 1.0f);
    mgemm(D0, D0, C_, C_, WOFF_CAV, bv, nullptr, S2, C_, C_, 1.0f);
    mgemm(D1, D1, C_, C_, WOFF_CAV, bv, nullptr, S3, C_, C_, 1.0f);
    flashm_kernel<<<dim3(M_ / 64, B_ * H_), 256, 0, stream>>>(
        S0, S1, S3, C_, 0, 0, 0, nullptr, nullptr, S4, 0.125f);   // m0 -> S4
    flashm_kernel<<<dim3(M_ / 64, B_ * H_), 256, 0, stream>>>(
        S1, S0, S2, C_, 0, 0, 0, nullptr, nullptr, S3, 0.125f);   // m1 -> S3
    mgemm(S4, S4, C_, C_, WOFF_CAOUT, bo, nullptr, S2, C_, C_, 1.0f);  // ao0 -> S2
    mgemm(S3, S3, C_, C_, WOFF_CAOUT, bo, nullptr, S4, C_, C_, 1.0f);  // ao1 -> S4
    ffn(D0, S2, WOFF_CAW1, b1, g, be, WOFF_CAW2, b2);
    ffn(D1, S4, WOFF_CAW1, b1, g, be, WOFF_CAW2, b2);
  };

  // ---------------- pipeline
  hipMemcpyAsync(D0, desc0, N * sizeof(float), hipMemcpyDeviceToDevice, stream);
  hipMemcpyAsync(D1, desc1, N * sizeof(float), hipMemcpyDeviceToDevice, stream);
  posenc_kernel<<<(B_ * M_ * 32 + 255) / 256, 256, 0, stream>>>(kpts0, image_size, Wr, CC0, SC0);
  posenc_kernel<<<(B_ * M_ * 32 + 255) / 256, 256, 0, stream>>>(kpts1, image_size, Wr, CC1, SC1);

  for (int l = 0; l < L_; l++) {
    wconv(saqkv_W + (size_t)l * C_ * C3_, WOFF_QKV, 8, C3_);
    wconv(saout_W + (size_t)l * C_ * C_, WOFF_SAOUT, 8, C_);
    wconv(saff_W1 + (size_t)l * C2_ * C2_, WOFF_SAW1, 9, C2_);
    wconv(saff_W2 + (size_t)l * C2_ * C_, WOFF_SAW2, 9, C_);
    wconv(caqk_W + (size_t)l * C_ * C_, WOFF_CAQK, 8, C_);
    wconv(cav_W + (size_t)l * C_ * C_, WOFF_CAV, 8, C_);
    wconv(caout_W + (size_t)l * C_ * C_, WOFF_CAOUT, 8, C_);
    wconv(caff_W1 + (size_t)l * C2_ * C2_, WOFF_CAW1, 9, C2_);
    wconv(caff_W2 + (size_t)l * C2_ * C_, WOFF_CAW2, 9, C_);
    self_block(D0, CC0, SC0, l);
    self_block(D1, CC1, SC1, l);
    cross_block(l);
  }

  // ---------------- final matching head (fp32 sim recomputed per pass)
  wconv(fproj_W, 0, 8, C_);
  mgemm(D0, D0, C_, C_, 0, fproj_b, nullptr, S0, C_, C_, 0.25f);   // md0
  mgemm(D1, D1, C_, C_, 0, fproj_b, nullptr, S1, C_, C_, 0.25f);   // md1
  z_kernel<<<2048, 256, 0, stream>>>(D0, match_w, match_b, LS0, LSN0);
  z_kernel<<<2048, 256, 0, stream>>>(D1, match_w, match_b, LS1, LSN1);
  head_kernel<<<dim3(32, B_), 256, 0, stream>>>(S0, S1, nullptr, nullptr,
                                                LSE2, nullptr, nullptr, nullptr, 0);
  head_kernel<<<dim3(32, B_), 256, 0, stream>>>(S1, S0, nullptr, nullptr,
                                                LSE1, nullptr, nullptr, nullptr, 0);
  rcterm_kernel<<<32, 256, 0, stream>>>(LS0, LSE2, LS1, LSE1, RT, CT);
  head_kernel<<<dim3(32, B_), 256, 0, stream>>>(S0, S1, CT, RT,
                                                nullptr, MAX0, AM0, SCO, 1);
  head_kernel<<<dim3(32, B_), 256, 0, stream>>>(S1, S0, RT, nullptr,
                                                nullptr, nullptr, AM1, nullptr, 2);
  edge_kernel<<<32, 256, 0, stream>>>(LSN0, LSN1, SCO);
  match0ws_kernel<<<32, 256, 0, stream>>>(AM0, AM1, MAX0, MS0F, VAL0);
  finalout_kernel<<<32, 256, 0, stream>>>(AM0, AM1, MS0F, VAL0, ofp);

  (void)in_sizes; (void)n_in; (void)out_size; (void)ws_size;
}

// Round 3
// 9575.748 us; speedup vs baseline: 3.7190x; 1.3223x over previous
//
#include <hip/hip_runtime.h>
#include <hip/hip_bf16.h>
#include <cmath>

#define DEVI __device__ __forceinline__

constexpr int B_   = 4;
constexpr int M_   = 2048;
constexpr int C_   = 256;
constexpr int H_   = 4;
constexpr int HD_  = 64;
constexpr int L_   = 9;
constexpr int TOK_ = B_ * M_;     // 8192
constexpr int C2_  = 2 * C_;      // 512
constexpr int C3_  = 3 * C_;      // 768
constexpr int NS_  = 2049;        // scores dim

typedef __attribute__((ext_vector_type(8))) short s16x8;
typedef __attribute__((ext_vector_type(4))) float f32x4;
typedef __attribute__((ext_vector_type(4))) unsigned short u16x4;

// ---------------------------------------------------------------- helpers
DEVI float logsig_f(float x) {
  if (x >= 0.0f) return -log1pf(__expf(-x));
  return x - log1pf(__expf(x));
}

DEVI float gelu_tanh(float x) {
  float x3 = x * x * x;
  float t = 0.7978845608028654f * (x + 0.044715f * x3);
  return x / (1.0f + __expf(-2.0f * t));     // == 0.5x(1+tanh(t))
}

DEVI unsigned short f2bf(float x) {            // RNE fp32 -> bf16
  unsigned u = __float_as_uint(x);
  u += 0x7fffu + ((u >> 16) & 1u);
  return (unsigned short)(u >> 16);
}
DEVI float bf2f(unsigned short h) { return __uint_as_float((unsigned)h << 16); }

// ---------------------------------------------------------------- posenc
__global__ void posenc_kernel(const float* __restrict__ kpts, const float* __restrict__ wh,
                              const float* __restrict__ Wr, float* __restrict__ cc,
                              float* __restrict__ sc) {
  int idx = blockIdx.x * blockDim.x + threadIdx.x;   // B*M*32
  if (idx >= B_ * M_ * 32) return;
  int j  = idx & 31;
  int bm = idx >> 5;
  float w = wh[0], h = wh[1];
  float smax = fmaxf(w, h) * 0.5f;
  float kx = (kpts[bm * 2 + 0] - w * 0.5f) / smax;
  float ky = (kpts[bm * 2 + 1] - h * 0.5f) / smax;
  float p = kx * Wr[j] + ky * Wr[32 + j];
  cc[bm * 32 + j] = cosf(p);
  sc[bm * 32 + j] = sinf(p);
}

// ---------------------------------------------------------------- weight transpose + split (single matrix)
__global__ void wconv_kernel(const float* __restrict__ W, unsigned short* __restrict__ Th,
                             unsigned short* __restrict__ Tl, int kbits, int N) {
  int idx = blockIdx.x * 256 + threadIdx.x;
  int k = idx & ((1 << kbits) - 1);
  int n = idx >> kbits;
  float x = W[(size_t)k * N + n];
  unsigned short h = f2bf(x);
  Th[idx] = h;
  Tl[idx] = f2bf(x - bf2f(h));
}

// ---------------------------------------------------------------- all 9 per-layer weights in one launch
__global__ void wconv_layer_kernel(const float* __restrict__ qkv, const float* __restrict__ saout,
                                   const float* __restrict__ sw1, const float* __restrict__ sw2,
                                   const float* __restrict__ cqk, const float* __restrict__ cv,
                                   const float* __restrict__ cout_, const float* __restrict__ cw1,
                                   const float* __restrict__ cw2,
                                   unsigned short* __restrict__ Th, unsigned short* __restrict__ Tl) {
  int idx = blockIdx.x * 256 + threadIdx.x;   // < 1245184
  const float* src; int kbits, N, rel;
  if      (idx <  196608) { src = qkv;   kbits = 8; N = 768; rel = idx; }
  else if (idx <  262144) { src = saout; kbits = 8; N = 256; rel = idx -  196608; }
  else if (idx <  524288) { src = sw1;   kbits = 9; N = 512; rel = idx -  262144; }
  else if (idx <  655360) { src = sw2;   kbits = 9; N = 256; rel = idx -  524288; }
  else if (idx <  720896) { src = cqk;   kbits = 8; N = 256; rel = idx -  655360; }
  else if (idx <  786432) { src = cv;    kbits = 8; N = 256; rel = idx -  720896; }
  else if (idx <  851968) { src = cout_; kbits = 8; N = 256; rel = idx -  786432; }
  else if (idx < 1114112) { src = cw1;   kbits = 9; N = 512; rel = idx -  851968; }
  else                    { src = cw2;   kbits = 9; N = 256; rel = idx - 1114112; }
  int k = rel & ((1 << kbits) - 1), n = rel >> kbits;
  float x = src[(size_t)k * N + n];
  unsigned short h = f2bf(x);
  Th[idx] = h;
  Tl[idx] = f2bf(x - bf2f(h));
}

// ---------------------------------------------------------------- fp32 -> hi/lo planes (elementwise)
__global__ void split_kernel(const float* __restrict__ src, unsigned short* __restrict__ h,
                             unsigned short* __restrict__ l) {
  int idx = blockIdx.x * 256 + threadIdx.x;
  float x = src[idx];
  unsigned short hb = f2bf(x);
  h[idx] = hb;
  l[idx] = f2bf(x - bf2f(hb));
}

// ---------------------------------------------------------------- self-attn prep: RoPE + split Q,K (packed per bh)
__global__ __launch_bounds__(256) void prep_ropeqk_kernel(
    const float* __restrict__ S, const float* __restrict__ cc, const float* __restrict__ sc,
    unsigned short* __restrict__ Qh, unsigned short* __restrict__ Ql,
    unsigned short* __restrict__ Kh, unsigned short* __restrict__ Kl) {
  int idx = blockIdx.x * 256 + threadIdx.x;   // B*M*H*32
  int j = idx & 31;
  int h = (idx >> 5) & 3;
  int tok = idx >> 7;                          // 0..8191
  int m = tok & 2047, b = tok >> 11;
  const float* row = S + (size_t)tok * 768 + h * 64 + 2 * j;
  float c = cc[(size_t)tok * 32 + j];
  float s = sc[(size_t)tok * 32 + j];
  float2 q = *(const float2*)row;
  float2 k = *(const float2*)(row + 256);
  float qx = q.x * c - q.y * s, qy = q.y * c + q.x * s;
  float kx = k.x * c - k.y * s, ky = k.y * c + k.x * s;
  size_t o = ((size_t)(b * 4 + h) * 2048 + m) * 64 + 2 * j;
  unsigned short q0 = f2bf(qx), q1 = f2bf(qy);
  ushort2 t;
  t.x = q0; t.y = q1;                       *(ushort2*)&Qh[o] = t;
  t.x = f2bf(qx - bf2f(q0)); t.y = f2bf(qy - bf2f(q1)); *(ushort2*)&Ql[o] = t;
  unsigned short k0 = f2bf(kx), k1 = f2bf(ky);
  t.x = k0; t.y = k1;                       *(ushort2*)&Kh[o] = t;
  t.x = f2bf(kx - bf2f(k0)); t.y = f2bf(ky - bf2f(k1)); *(ushort2*)&Kl[o] = t;
}

// ---------------------------------------------------------------- self-attn prep: V transpose + split (packed per bh)
__global__ __launch_bounds__(256) void prep_vt_kernel(
    const float* __restrict__ S, int ld, int vcol,
    unsigned short* __restrict__ Vth, unsigned short* __restrict__ Vtl) {
  int idx = blockIdx.x * 256 + threadIdx.x;    // bh*64*512
  int mq = idx & 511; int m0 = mq << 2;
  int d = (idx >> 9) & 63;
  int bh = idx >> 15;
  int b = bh >> 2, h = bh & 3;
  const float* base = S + ((size_t)(b * 2048) + m0) * ld + vcol + h * 64 + d;
  u16x4 hv, lv;
#pragma unroll
  for (int i = 0; i < 4; i++) {
    float x = base[(size_t)i * ld];
    unsigned short hb = f2bf(x);
    hv[i] = hb;
    lv[i] = f2bf(x - bf2f(hb));
  }
  size_t o = ((size_t)bh * 64 + d) * 2048 + m0;
  *(u16x4*)&Vth[o] = hv;
  *(u16x4*)&Vtl[o] = lv;
}

// ---------------------------------------------------------------- split-bf16 MFMA GEMM, pre-split A
// A: hi/lo planes [row][lda] (A1 for k<kSplit else A2). W pre-split [N][K].
// Outputs (each optional): outf fp32 [row][N] (+res); outh/outl split planes;
// tvh/tvl transposed-split per-(b,h) packed [bh][64][2048] (for Wv).
__global__ __launch_bounds__(256, 3) void mgemm_kernel(
    const unsigned short* __restrict__ A1h, const unsigned short* __restrict__ A1l,
    const unsigned short* __restrict__ A2h, const unsigned short* __restrict__ A2l,
    int lda, int kSplit,
    const unsigned short* __restrict__ WTh, const unsigned short* __restrict__ WTl,
    const float* __restrict__ bias, const float* __restrict__ res, float* __restrict__ outf,
    unsigned short* __restrict__ outh, unsigned short* __restrict__ outl,
    unsigned short* __restrict__ tvh, unsigned short* __restrict__ tvl,
    int K, int N, float oscale) {
  __shared__ alignas(16) unsigned short Ash[128 * 64];
  __shared__ alignas(16) unsigned short Asl[128 * 64];
  __shared__ alignas(16) unsigned short Bsh[64 * 64];
  __shared__ alignas(16) unsigned short Bsl[64 * 64];
  int tid = threadIdx.x;
  int rowBase = blockIdx.y << 7;
  int colBase = blockIdx.x << 6;
  int lr = tid & 15, lg = (tid >> 4) & 3;
  int wid = tid >> 6, wm = wid >> 1, wn = wid & 1;
  int sw = (lr & 7) << 3;
  f32x4 acc[4][2] = {};

  for (int k0 = 0; k0 < K; k0 += 64) {
    const unsigned short *Ah, *Al;
    int kloc;
    if (k0 < kSplit) { Ah = A1h; Al = A1l; kloc = k0; }
    else             { Ah = A2h; Al = A2l; kloc = k0 - kSplit; }
    __syncthreads();
#pragma unroll
    for (int i = 0; i < 8; i++) {
      int idx = tid + (i << 8);
      int r = idx >> 4;
      int kc = (idx & 15) << 2;
      size_t g = (size_t)(rowBase + r) * lda + kloc + kc;
      u16x4 hv = *(const u16x4*)&Ah[g];
      u16x4 lv = *(const u16x4*)&Al[g];
      int col = kc ^ ((r & 7) << 3);
      *(u16x4*)&Ash[r * 64 + col] = hv;
      *(u16x4*)&Asl[r * 64 + col] = lv;
    }
#pragma unroll
    for (int i = 0; i < 4; i++) {
      int idx = tid + (i << 8);
      int rn = idx >> 4;
      int kc = (idx & 15) << 2;
      size_t g = (size_t)(colBase + rn) * K + k0 + kc;
      u16x4 hv = *(const u16x4*)&WTh[g];
      u16x4 lv = *(const u16x4*)&WTl[g];
      int col = kc ^ ((rn & 7) << 3);
      *(u16x4*)&Bsh[rn * 64 + col] = hv;
      *(u16x4*)&Bsl[rn * 64 + col] = lv;
    }
    __syncthreads();
#pragma unroll
    for (int c = 0; c < 2; c++) {
      int kcol = (c << 5) + (lg << 3);
      s16x8 ah[4], al[4], bh[2], bl[2];
#pragma unroll
      for (int mi = 0; mi < 4; mi++) {
        int off = (wm * 64 + mi * 16 + lr) * 64 + (kcol ^ sw);
        ah[mi] = *(const s16x8*)&Ash[off];
        al[mi] = *(const s16x8*)&Asl[off];
      }
#pragma unroll
      for (int ni = 0; ni < 2; ni++) {
        int off = (wn * 32 + ni * 16 + lr) * 64 + (kcol ^ sw);
        bh[ni] = *(const s16x8*)&Bsh[off];
        bl[ni] = *(const s16x8*)&Bsl[off];
      }
#pragma unroll
      for (int mi = 0; mi < 4; mi++)
#pragma unroll
        for (int ni = 0; ni < 2; ni++) {
          f32x4 t = acc[mi][ni];
          t = __builtin_amdgcn_mfma_f32_16x16x32_bf16(ah[mi], bl[ni], t, 0, 0, 0);
          t = __builtin_amdgcn_mfma_f32_16x16x32_bf16(al[mi], bh[ni], t, 0, 0, 0);
          t = __builtin_amdgcn_mfma_f32_16x16x32_bf16(ah[mi], bh[ni], t, 0, 0, 0);
          acc[mi][ni] = t;
        }
    }
  }
  // epilogue: C/D layout col = lane&15, row = (lane>>4)*4 + j
#pragma unroll
  for (int mi = 0; mi < 4; mi++) {
    int row0 = rowBase + wm * 64 + mi * 16 + lg * 4;
#pragma unroll
    for (int ni = 0; ni < 2; ni++) {
      int col = colBase + wn * 32 + ni * 16 + lr;
      float bc = bias[col];
      float vj[4];
      size_t o0 = (size_t)row0 * N + col;
#pragma unroll
      for (int j = 0; j < 4; j++) {
        float v = (acc[mi][ni][j] + bc) * oscale;
        if (res) v += res[o0 + (size_t)j * N];
        vj[j] = v;
      }
      if (outf) {
#pragma unroll
        for (int j = 0; j < 4; j++) outf[o0 + (size_t)j * N] = vj[j];
      }
      if (outh) {
#pragma unroll
        for (int j = 0; j < 4; j++) {
          unsigned short hb = f2bf(vj[j]);
          outh[o0 + (size_t)j * N] = hb;
          outl[o0 + (size_t)j * N] = f2bf(vj[j] - bf2f(hb));
        }
      }
      if (tvh) {
        int hh = col >> 6, d = col & 63;
        int bb = row0 >> 11, m0 = row0 & 2047;
        u16x4 hv, lv;
#pragma unroll
        for (int j = 0; j < 4; j++) {
          unsigned short hb = f2bf(vj[j]);
          hv[j] = hb;
          lv[j] = f2bf(vj[j] - bf2f(hb));
        }
        size_t tvo = ((size_t)(bb * 4 + hh) * 64 + d) * 2048 + m0;
        *(u16x4*)&tvh[tvo] = hv;
        *(u16x4*)&tvl[tvo] = lv;
      }
    }
  }
}

// ---------------------------------------------------------------- MFMA flash attention, fully pre-split inputs
// Q/K: hi/lo planes addressed base + b*(M*C) + h*hstr + tok*ld + d.
// V: transposed packed [bh][64][2048] hi/lo. Scale applied to S post-MFMA.
// Out: split planes, plain [8192][256] at col h*64.
__global__ __launch_bounds__(256, 2) void flashm2_kernel(
    const unsigned short* __restrict__ Qh, const unsigned short* __restrict__ Ql, int ldq, int hq,
    const unsigned short* __restrict__ Kh, const unsigned short* __restrict__ Kl, int ldk, int hk,
    const unsigned short* __restrict__ Vth, const unsigned short* __restrict__ Vtl,
    unsigned short* __restrict__ Oh, unsigned short* __restrict__ Ol, float scale) {
  __shared__ alignas(16) unsigned short Ksh[64 * 64];
  __shared__ alignas(16) unsigned short Ksl[64 * 64];
  __shared__ alignas(16) unsigned short Vsh[64 * 64];
  __shared__ alignas(16) unsigned short Vsl[64 * 64];
  __shared__ alignas(16) unsigned short Ph[64 * 64];
  __shared__ alignas(16) unsigned short Pl[64 * 64];
  int bh = blockIdx.y;
  int b = bh >> 2, h = bh & 3;
  int mBase = blockIdx.x * 64;
  size_t qbase = (size_t)b * (M_ * C_) + (size_t)h * hq;
  size_t kbase = (size_t)b * (M_ * C_) + (size_t)h * hk;
  size_t vbase = (size_t)bh * (64 * 2048);
  int tid = threadIdx.x;
  int lane = tid & 63, w = tid >> 6;
  int lr = lane & 15, lg = lane >> 4;

  // Q fragments (pure loads)
  s16x8 qh[2], ql[2];
  {
    int m = mBase + w * 16 + lr;
#pragma unroll
    for (int c = 0; c < 2; c++) {
      size_t g = qbase + (size_t)m * ldq + c * 32 + lg * 8;
      qh[c] = *(const s16x8*)&Qh[g];
      ql[c] = *(const s16x8*)&Ql[g];
    }
  }

  float m_run[4], l_run[4];
  f32x4 oacc[4];
#pragma unroll
  for (int j = 0; j < 4; j++) { m_run[j] = -INFINITY; l_run[j] = 0.0f; }
#pragma unroll
  for (int g = 0; g < 4; g++) oacc[g] = (f32x4){0.f, 0.f, 0.f, 0.f};

  for (int t0 = 0; t0 < M_; t0 += 64) {
    __syncthreads();
    // stage K rows (swizzled) and Vt rows (swizzled) — pure u16x4 copies
#pragma unroll
    for (int i = 0; i < 4; i++) {
      int idx = tid + (i << 8);
      int key = idx >> 4;
      int d0 = (idx & 15) << 2;
      size_t g = kbase + (size_t)(t0 + key) * ldk + d0;
      int cswz = d0 ^ ((key & 7) << 3);
      *(u16x4*)&Ksh[key * 64 + cswz] = *(const u16x4*)&Kh[g];
      *(u16x4*)&Ksl[key * 64 + cswz] = *(const u16x4*)&Kl[g];
      // V: row d, keys kc..kc+3
      int d = idx >> 4;
      int kc = (idx & 15) << 2;
      size_t gv = vbase + (size_t)d * 2048 + t0 + kc;
      int kk = kc ^ (((d ^ (d >> 2)) & 7) << 3);
      *(u16x4*)&Vsh[d * 64 + kk] = *(const u16x4*)&Vth[gv];
      *(u16x4*)&Vsl[d * 64 + kk] = *(const u16x4*)&Vtl[gv];
    }
    __syncthreads();

    // S = Q.K^T
    f32x4 sacc[4];
#pragma unroll
    for (int f = 0; f < 4; f++) sacc[f] = (f32x4){0.f, 0.f, 0.f, 0.f};
#pragma unroll
    for (int f = 0; f < 4; f++) {
#pragma unroll
      for (int c = 0; c < 2; c++) {
        int key = f * 16 + lr;
        int kb = c * 32 + lg * 8;
        int off = key * 64 + (kb ^ ((key & 7) << 3));
        s16x8 kh = *(const s16x8*)&Ksh[off];
        s16x8 kl = *(const s16x8*)&Ksl[off];
        f32x4 t = sacc[f];
        t = __builtin_amdgcn_mfma_f32_16x16x32_bf16(qh[c], kl, t, 0, 0, 0);
        t = __builtin_amdgcn_mfma_f32_16x16x32_bf16(ql[c], kh, t, 0, 0, 0);
        t = __builtin_amdgcn_mfma_f32_16x16x32_bf16(qh[c], kh, t, 0, 0, 0);
        sacc[f] = t;
      }
    }
#pragma unroll
    for (int f = 0; f < 4; f++)
#pragma unroll
      for (int j = 0; j < 4; j++) sacc[f][j] *= scale;

    // online softmax (rows = lg*4+j)
    float mnew[4], alpha[4], lsum[4];
#pragma unroll
    for (int j = 0; j < 4; j++) {
      float v = fmaxf(fmaxf(sacc[0][j], sacc[1][j]), fmaxf(sacc[2][j], sacc[3][j]));
      v = fmaxf(v, __shfl_xor(v, 1));
      v = fmaxf(v, __shfl_xor(v, 2));
      v = fmaxf(v, __shfl_xor(v, 4));
      v = fmaxf(v, __shfl_xor(v, 8));
      mnew[j] = fmaxf(m_run[j], v);
      alpha[j] = __expf(m_run[j] - mnew[j]);
      lsum[j] = 0.0f;
    }
#pragma unroll
    for (int f = 0; f < 4; f++) {
#pragma unroll
      for (int j = 0; j < 4; j++) {
        float p = __expf(sacc[f][j] - mnew[j]);
        lsum[j] += p;
        int row = w * 16 + lg * 4 + j;
        int col = (f * 16 + lr) ^ ((row & 7) << 3);
        unsigned short hb = f2bf(p);
        Ph[row * 64 + col] = hb;
        Pl[row * 64 + col] = f2bf(p - bf2f(hb));
      }
    }
#pragma unroll
    for (int j = 0; j < 4; j++) {
      float s = lsum[j];
      s += __shfl_xor(s, 1);
      s += __shfl_xor(s, 2);
      s += __shfl_xor(s, 4);
      s += __shfl_xor(s, 8);
      l_run[j] = l_run[j] * alpha[j] + s;
      m_run[j] = mnew[j];
    }
#pragma unroll
    for (int g = 0; g < 4; g++) {
      f32x4 t = oacc[g];
#pragma unroll
      for (int j = 0; j < 4; j++) t[j] *= alpha[j];
      oacc[g] = t;
    }

    // O += P.V
    s16x8 pah[2], pal[2];
#pragma unroll
    for (int c = 0; c < 2; c++) {
      int row = w * 16 + lr;
      int kb = (c * 32 + lg * 8) ^ ((row & 7) << 3);
      pah[c] = *(const s16x8*)&Ph[row * 64 + kb];
      pal[c] = *(const s16x8*)&Pl[row * 64 + kb];
    }
#pragma unroll
    for (int g = 0; g < 4; g++) {
#pragma unroll
      for (int c = 0; c < 2; c++) {
        int d = g * 16 + lr;
        int kb = (c * 32 + lg * 8) ^ (((d ^ (d >> 2)) & 7) << 3);
        s16x8 vh = *(const s16x8*)&Vsh[d * 64 + kb];
        s16x8 vl = *(const s16x8*)&Vsl[d * 64 + kb];
        f32x4 t = oacc[g];
        t = __builtin_amdgcn_mfma_f32_16x16x32_bf16(pah[c], vl, t, 0, 0, 0);
        t = __builtin_amdgcn_mfma_f32_16x16x32_bf16(pal[c], vh, t, 0, 0, 0);
        t = __builtin_amdgcn_mfma_f32_16x16x32_bf16(pah[c], vh, t, 0, 0, 0);
        oacc[g] = t;
      }
    }
  }

  // epilogue: split O directly
#pragma unroll
  for (int j = 0; j < 4; j++) {
    float inv = 1.0f / l_run[j];
    int q = mBase + w * 16 + lg * 4 + j;
    size_t ob = ((size_t)b * M_ + q) * C_ + h * 64;
#pragma unroll
    for (int g = 0; g < 4; g++) {
      float v = oacc[g][j] * inv;
      unsigned short hb = f2bf(v);
      Oh[ob + g * 16 + lr] = hb;
      Ol[ob + g * 16 + lr] = f2bf(v - bf2f(hb));
    }
  }
}

// ---------------------------------------------------------------- LayerNorm + GELU (+ split out)
__global__ __launch_bounds__(256) void ln_gelu_kernel(float* __restrict__ h,
                                                      const float* __restrict__ g,
                                                      const float* __restrict__ beta,
                                                      unsigned short* __restrict__ Hh,
                                                      unsigned short* __restrict__ Hl) {
  __shared__ float red[4];
  int t = blockIdx.x, tid = threadIdx.x;
  float* hr = h + (size_t)t * C2_;
  float a = hr[tid], b2 = hr[tid + 256];
  float s = a + b2;
  for (int o = 1; o < 64; o <<= 1) s += __shfl_xor(s, o);
  if ((tid & 63) == 0) red[tid >> 6] = s;
  __syncthreads();
  float mu = (red[0] + red[1] + red[2] + red[3]) * (1.0f / 512.0f);
  __syncthreads();
  float da = a - mu, db = b2 - mu;
  s = da * da + db * db;
  for (int o = 1; o < 64; o <<= 1) s += __shfl_xor(s, o);
  if ((tid & 63) == 0) red[tid >> 6] = s;
  __syncthreads();
  float var = (red[0] + red[1] + red[2] + red[3]) * (1.0f / 512.0f);
  float rs = rsqrtf(var + 1e-5f);
  float xa = gelu_tanh(da * rs * g[tid] + beta[tid]);
  float xb = gelu_tanh(db * rs * g[tid + 256] + beta[tid + 256]);
  hr[tid]       = xa;
  hr[tid + 256] = xb;
  size_t o = (size_t)t * C2_;
  unsigned short ha = f2bf(xa), hb2 = f2bf(xb);
  Hh[o + tid]       = ha;
  Hl[o + tid]       = f2bf(xa - bf2f(ha));
  Hh[o + tid + 256] = hb2;
  Hl[o + tid + 256] = f2bf(xb - bf2f(hb2));
}

// ---------------------------------------------------------------- z = d @ match_w + b, log_sigmoid(+/-)
__global__ __launch_bounds__(256) void z_kernel(const float* __restrict__ d,
                                                const float* __restrict__ mw,
                                                const float* __restrict__ mb,
                                                float* __restrict__ ls,
                                                float* __restrict__ lsn) {
  int row = blockIdx.x * 4 + (threadIdx.x >> 6);
  int lane = threadIdx.x & 63;
  const float4* dr = (const float4*)(d + (size_t)row * C_);
  float4 v = dr[lane];
  float4 w4 = ((const float4*)mw)[lane];
  float s = v.x * w4.x + v.y * w4.y + v.z * w4.z + v.w * w4.w;
  for (int o = 1; o < 64; o <<= 1) s += __shfl_xor(s, o);
  if (lane == 0) {
    float zz = s + mb[0];
    ls[row]  = logsig_f(zz);
    lsn[row] = logsig_f(-zz);
  }
}

// ---------------------------------------------------------------- fused matching-head pass (fp32 scalar)
__global__ __launch_bounds__(256) void head_kernel(const float* __restrict__ A,
                                                   const float* __restrict__ Bm,
                                                   const float* __restrict__ addv,
                                                   const float* __restrict__ rowv,
                                                   float* __restrict__ lse_out,
                                                   float* __restrict__ max_out,
                                                   int* __restrict__ am_out,
                                                   float* __restrict__ scores_out,
                                                   int mode) {
  __shared__ alignas(16) float As[16][68];
  __shared__ alignas(16) float Bs[16][68];
  int tid = threadIdx.x;
  int ty = tid >> 4, tx = tid & 15;
  int mBase = blockIdx.x << 6;
  int b = blockIdx.y;
  const float* Ab = A + (size_t)b * M_ * C_;
  const float* Bb = Bm + (size_t)b * M_ * C_;
  const float* addb = addv ? addv + (size_t)b * M_ : nullptr;
  const float* rowb = rowv ? rowv + (size_t)b * M_ : nullptr;

  float on_m[4], on_l[4], bst[4];
  int bidx[4];
#pragma unroll
  for (int i = 0; i < 4; i++) {
    on_m[i] = -INFINITY; on_l[i] = 0.0f; bst[i] = -INFINITY; bidx[i] = 0x7fffffff;
  }
  float rterm[4];
#pragma unroll
  for (int i = 0; i < 4; i++)
    rterm[i] = rowb ? rowb[mBase + (ty << 2) + i] : 0.0f;

  for (int nTile = 0; nTile < 32; nTile++) {
    int nBase = nTile << 6;
    float acc[4][4] = {};
    for (int k0 = 0; k0 < C_; k0 += 16) {
      __syncthreads();
#pragma unroll
      for (int i = 0; i < 4; i++) {
        int idx = tid + (i << 8);
        int r = idx >> 4, kk = idx & 15;
        As[kk][r] = Ab[(size_t)(mBase + r) * C_ + (k0 + kk)];
        Bs[kk][r] = Bb[(size_t)(nBase + r) * C_ + (k0 + kk)];
      }
      __syncthreads();
#pragma unroll
      for (int kk = 0; kk < 16; kk++) {
        float4 a4 = *(const float4*)&As[kk][ty << 2];
        float4 b4 = *(const float4*)&Bs[kk][tx << 2];
        float a[4] = {a4.x, a4.y, a4.z, a4.w};
        float bb[4] = {b4.x, b4.y, b4.z, b4.w};
#pragma unroll
        for (int i = 0; i < 4; i++)
#pragma unroll
          for (int j = 0; j < 4; j++) acc[i][j] += a[i] * bb[j];
      }
    }
    if (mode == 0) {
#pragma unroll
      for (int i = 0; i < 4; i++)
#pragma unroll
        for (int j = 0; j < 4; j++) {
          float s = acc[i][j];
          if (s > on_m[i]) {
            on_l[i] = on_l[i] * __expf(on_m[i] - s) + 1.0f;
            on_m[i] = s;
          } else {
            on_l[i] += __expf(s - on_m[i]);
          }
        }
    } else {
      float addn[4];
#pragma unroll
      for (int j = 0; j < 4; j++)
        addn[j] = addb ? addb[nBase + (tx << 2) + j] : 0.0f;
#pragma unroll
      for (int i = 0; i < 4; i++)
#pragma unroll
        for (int j = 0; j < 4; j++) {
          float v = 2.0f * acc[i][j] + addn[j];
          int n = nBase + (tx << 2) + j;
          if (v > bst[i]) { bst[i] = v; bidx[i] = n; }
        }
      if (mode == 1) {
#pragma unroll
        for (int i = 0; i < 4; i++) {
          size_t ro = ((size_t)(b * NS_ + mBase + (ty << 2) + i)) * NS_ + nBase + (tx << 2);
#pragma unroll
          for (int j = 0; j < 4; j++)
            scores_out[ro + j] = 2.0f * acc[i][j] + rterm[i] + addn[j];
        }
      }
    }
  }

  if (mode == 0) {
#pragma unroll
    for (int i = 0; i < 4; i++) {
      float Mv = on_m[i], Lv = on_l[i];
      for (int off = 1; off < 16; off <<= 1) {
        float M2 = __shfl_xor(Mv, off);
        float L2 = __shfl_xor(Lv, off);
        float Mn = fmaxf(Mv, M2);
        Lv = Lv * __expf(Mv - Mn) + L2 * __expf(M2 - Mn);
        Mv = Mn;
      }
      if (tx == 0) lse_out[(size_t)b * M_ + mBase + (ty << 2) + i] = Mv + logf(Lv);
    }
  } else {
#pragma unroll
    for (int i = 0; i < 4; i++) {
      float v = bst[i];
      int ix = bidx[i];
      for (int off = 1; off < 16; off <<= 1) {
        float v2 = __shfl_xor(v, off);
        int i2 = __shfl_xor(ix, off);
        if (v2 > v || (v2 == v && i2 < ix)) { v = v2; ix = i2; }
      }
      if (tx == 0) {
        size_t o = (size_t)b * M_ + mBase + (ty << 2) + i;
        am_out[o] = ix;
        if (mode == 1) max_out[o] = v + rterm[i];
      }
    }
  }
}

// ---------------------------------------------------------------- row/col additive terms
__global__ void rcterm_kernel(const float* __restrict__ ls0, const float* __restrict__ lse2,
                              const float* __restrict__ ls1, const float* __restrict__ lse1,
                              float* __restrict__ rt, float* __restrict__ ct) {
  int i = blockIdx.x * blockDim.x + threadIdx.x;
  if (i < B_ * M_) { rt[i] = ls0[i] - lse2[i]; ct[i] = ls1[i] - lse1[i]; }
}

// ---------------------------------------------------------------- scores edges
__global__ void edge_kernel(const float* __restrict__ lsn0, const float* __restrict__ lsn1,
                            float* __restrict__ sco) {
  int i = blockIdx.x * blockDim.x + threadIdx.x;   // B*2048
  if (i >= B_ * M_) return;
  int b = i >> 11, t = i & 2047;
  sco[((size_t)b * NS_ + t) * NS_ + 2048] = lsn0[i];
  sco[((size_t)b * NS_ + 2048) * NS_ + t] = lsn1[i];
  if (t == 0) sco[((size_t)b * NS_ + 2048) * NS_ + 2048] = 0.0f;
}

// ---------------------------------------------------------------- mscores0 / valid0
__global__ void match0ws_kernel(const int* __restrict__ am0, const int* __restrict__ am1,
                                const float* __restrict__ max0, float* __restrict__ ms0f,
                                int* __restrict__ val0) {
  int i = blockIdx.x * blockDim.x + threadIdx.x;
  if (i >= B_ * M_) return;
  int b = i >> 11, m = i & 2047;
  int a0 = am0[i];
  bool mutual = (am1[b * M_ + a0] == m);
  float ms = mutual ? __expf(max0[i]) : 0.0f;
  ms0f[i] = ms;
  val0[i] = (mutual && ms > 0.1f) ? 1 : 0;
}

// ---------------------------------------------------------------- final small outputs
__global__ void finalout_kernel(const int* __restrict__ am0, const int* __restrict__ am1,
                                const float* __restrict__ ms0f, const int* __restrict__ val0,
                                float* __restrict__ out) {
  int i = blockIdx.x * blockDim.x + threadIdx.x;
  if (i >= B_ * M_) return;
  int b = i >> 11, t = i & 2047;
  int a0 = am0[i];
  bool mut0 = (am1[b * M_ + a0] == t);
  float ms0 = ms0f[i];
  bool v0 = mut0 && (ms0 > 0.1f);
  out[i] = v0 ? (float)a0 : -1.0f;                  // m0
  out[2 * B_ * M_ + i] = ms0;                       // mscores0
  int a1 = am1[i];
  bool mut1 = (am0[b * M_ + a1] == t);
  float ms1 = mut1 ? ms0f[b * M_ + a1] : 0.0f;
  bool v1 = mut1 && (val0[b * M_ + a1] != 0);
  out[B_ * M_ + i] = v1 ? (float)a1 : -1.0f;        // m1
  out[3 * B_ * M_ + i] = ms1;                       // mscores1
}

// ================================================================ host
// weight plane offsets (ushort elems)
constexpr size_t WOFF_QKV   = 0;
constexpr size_t WOFF_SAOUT = 196608;
constexpr size_t WOFF_SAW1  = 262144;
constexpr size_t WOFF_SAW2  = 524288;
constexpr size_t WOFF_CAQK  = 655360;
constexpr size_t WOFF_CAV   = 720896;
constexpr size_t WOFF_CAOUT = 786432;
constexpr size_t WOFF_CAW1  = 851968;
constexpr size_t WOFF_CAW2  = 1114112;
constexpr size_t WELEMS_    = 1245184;

// activation split-plane layout in the SCO region (ushort elems)
constexpr size_t PLN   = (size_t)TOK_ * C_;          // 2,097,152 elems per plane
constexpr size_t OXS0  = 2 * WELEMS_;                //  2,490,368  (h, l=+PLN)
constexpr size_t OXS1  = OXS0 + 2 * PLN;             //  6,684,672
constexpr size_t OBA   = OXS1 + 2 * PLN;             // 10,878,976
constexpr size_t OBB   = OBA + 2 * PLN;              // 15,073,280
constexpr size_t OBC   = OBB + 2 * PLN;              // 19,267,584
constexpr size_t OBD   = OBC + 2 * PLN;              // 23,461,888
constexpr size_t OBE   = OBD + 2 * PLN;              // 27,656,192; end 31,850,496 < 33,587,208

extern "C" void kernel_launch(void* const* d_in, const int* in_sizes, int n_in,
                              void* d_out, int out_size, void* d_ws, size_t ws_size,
                              hipStream_t stream) {
  const float* kpts0      = (const float*)d_in[0];
  const float* desc0      = (const float*)d_in[1];
  const float* kpts1      = (const float*)d_in[2];
  const float* desc1      = (const float*)d_in[3];
  const float* image_size = (const float*)d_in[4];
  const float* Wr         = (const float*)d_in[5];
  const float* saqkv_W    = (const float*)d_in[6];
  const float* saqkv_b    = (const float*)d_in[7];
  const float* saout_W    = (const float*)d_in[8];
  const float* saout_b    = (const float*)d_in[9];
  const float* saff_W1    = (const float*)d_in[10];
  const float* saff_b1    = (const float*)d_in[11];
  const float* saff_g     = (const float*)d_in[12];
  const float* saff_beta  = (const float*)d_in[13];
  const float* saff_W2    = (const float*)d_in[14];
  const float* saff_b2    = (const float*)d_in[15];
  const float* caqk_W     = (const float*)d_in[16];
  const float* caqk_b     = (const float*)d_in[17];
  const float* cav_W      = (const float*)d_in[18];
  const float* cav_b      = (const float*)d_in[19];
  const float* caout_W    = (const float*)d_in[20];
  const float* caout_b    = (const float*)d_in[21];
  const float* caff_W1    = (const float*)d_in[22];
  const float* caff_b1    = (const float*)d_in[23];
  const float* caff_g     = (const float*)d_in[24];
  const float* caff_beta  = (const float*)d_in[25];
  const float* caff_W2    = (const float*)d_in[26];
  const float* caff_b2    = (const float*)d_in[27];
  const float* fproj_W    = (const float*)d_in[28];
  const float* fproj_b    = (const float*)d_in[29];
  const float* match_w    = (const float*)d_in[30];
  const float* match_b    = (const float*)d_in[31];

  // FP32 output layout: m0@0, m1@8192, mscores0@16384, mscores1@24576, scores@32768
  float* ofp = (float*)d_out;
  float* SCO = ofp + 4 * B_ * M_;
  unsigned short* SCu = (unsigned short*)SCO;

  constexpr size_t N = (size_t)TOK_ * C_;
  constexpr size_t Qc = (size_t)B_ * M_ * 32;
  float* Wp  = (float*)d_ws;
  float* D0  = Wp;
  float* D1  = D0 + N;
  float* CC0 = D1 + N;
  float* SC0 = CC0 + Qc;
  float* CC1 = SC0 + Qc;
  float* SC1 = CC1 + Qc;
  float* S0  = SC1 + Qc;
  float* S1  = S0 + N;
  float* S2  = S1 + N;
  float* S3  = S2 + N;
  float* S4  = S3 + N;

  unsigned short* WTH = SCu;
  unsigned short* WTL = SCu + WELEMS_;

  float* LS0  = S2;
  float* LSN0 = LS0 + 8192;
  float* LS1  = LSN0 + 8192;
  float* LSN1 = LS1 + 8192;
  float* LSE2 = LSN1 + 8192;
  float* LSE1 = LSE2 + 8192;
  float* RT   = LSE1 + 8192;
  float* CT   = RT + 8192;
  float* MAX0 = CT + 8192;
  float* MS0F = MAX0 + 8192;
  int*   AM0  = (int*)(MS0F + 8192);
  int*   AM1  = AM0 + 8192;
  int*   VAL0 = AM1 + 8192;

  auto Hp = [&](size_t off) { return SCu + off; };          // hi plane
  auto Lp = [&](size_t off) { return SCu + off + PLN; };    // lo plane

  auto mgemm = [&](const unsigned short* a1h, const unsigned short* a1l,
                   const unsigned short* a2h, const unsigned short* a2l,
                   int lda, int kSplit, size_t woff,
                   const float* bias, const float* res, float* outf,
                   unsigned short* outh, unsigned short* outl,
                   unsigned short* tvh, unsigned short* tvl,
                   int K, int Ncols, float osc) {
    mgemm_kernel<<<dim3(Ncols >> 6, TOK_ >> 7), 256, 0, stream>>>(
        a1h, a1l, a2h, a2l, lda, kSplit, WTH + woff, WTL + woff,
        bias, res, outf, outh, outl, tvh, tvl, K, Ncols, osc);
  };

  auto ffn = [&](float* X, unsigned short* xsh, unsigned short* xsl,
                 unsigned short* msgh, unsigned short* msgl,
                 size_t offW1, const float* b1, const float* g, const float* be,
                 size_t offW2, const float* b2) {
    mgemm(xsh, xsl, msgh, msgl, C_, C_, offW1, b1, nullptr, S0,
          nullptr, nullptr, nullptr, nullptr, C2_, C2_, 1.0f);
    ln_gelu_kernel<<<TOK_, 256, 0, stream>>>(S0, g, be, Hp(OBC), Hp(OBD));
    mgemm(Hp(OBC), Hp(OBD), Hp(OBC), Hp(OBD), C2_, C2_, offW2, b2, X, X,
          xsh, xsl, nullptr, nullptr, C2_, C_, 1.0f);
  };

  auto self_block = [&](float* X, unsigned short* xsh, unsigned short* xsl,
                        const float* cc, const float* sc, int l) {
    const float* bqkv = saqkv_b + (size_t)l * C3_;
    const float* bo   = saout_b + (size_t)l * C_;
    // QKV -> S0 fp32
    mgemm(xsh, xsl, xsh, xsl, C_, C_, WOFF_QKV, bqkv, nullptr, S0,
          nullptr, nullptr, nullptr, nullptr, C_, C3_, 1.0f);
    // prep: RoPE+split Q,K packed; transpose+split V packed
    prep_ropeqk_kernel<<<4096, 256, 0, stream>>>(S0, cc, sc, Hp(OBA), Lp(OBA), Hp(OBB), Lp(OBB));
    prep_vt_kernel<<<2048, 256, 0, stream>>>(S0, C3_, C2_, Hp(OBC), Lp(OBC));
    flashm2_kernel<<<dim3(M_ / 64, B_ * H_), 256, 0, stream>>>(
        Hp(OBA), Lp(OBA), 64, 2048 * 64, Hp(OBB), Lp(OBB), 64, 2048 * 64,
        Hp(OBC), Lp(OBC), Hp(OBE), Lp(OBE), 0.125f);
    // Wo: A = flash-out split -> msg split (BUF_A)
    mgemm(Hp(OBE), Lp(OBE), Hp(OBE), Lp(OBE), C_, C_, WOFF_SAOUT, bo, nullptr, nullptr,
          Hp(OBA), Lp(OBA), nullptr, nullptr, C_, C_, 1.0f);
    ffn(X, xsh, xsl, Hp(OBA), Lp(OBA),
        WOFF_SAW1, saff_b1 + (size_t)l * C2_,
        saff_g + (size_t)l * C2_, saff_beta + (size_t)l * C2_,
        WOFF_SAW2, saff_b2 + (size_t)l * C_);
  };

  auto cross_block = [&](int l) {
    const float* bqk = caqk_b + (size_t)l * C_;
    const float* bv  = cav_b + (size_t)l * C_;
    const float* bo  = caout_b + (size_t)l * C_;
    const float* b1  = caff_b1 + (size_t)l * C2_;
    const float* g   = caff_g + (size_t)l * C2_;
    const float* be  = caff_beta + (size_t)l * C2_;
    const float* b2  = caff_b2 + (size_t)l * C_;
    // qk0 -> BUF_A, qk1 -> BUF_B (plain split, no fp32)
    mgemm(Hp(OXS0), Lp(OXS0), Hp(OXS0), Lp(OXS0), C_, C_, WOFF_CAQK, bqk, nullptr, nullptr,
          Hp(OBA), Lp(OBA), nullptr, nullptr, C_, C_, 1.0f);
    mgemm(Hp(OXS1), Lp(OXS1), Hp(OXS1), Lp(OXS1), C_, C_, WOFF_CAQK, bqk, nullptr, nullptr,
          Hp(OBB), Lp(OBB), nullptr, nullptr, C_, C_, 1.0f);
    // v0 -> Vt BUF_C, v1 -> Vt BUF_D (transposed split)
    mgemm(Hp(OXS0), Lp(OXS0), Hp(OXS0), Lp(OXS0), C_, C_, WOFF_CAV, bv, nullptr, nullptr,
          nullptr, nullptr, Hp(OBC), Lp(OBC), C_, C_, 1.0f);
    mgemm(Hp(OXS1), Lp(OXS1), Hp(OXS1), Lp(OXS1), C_, C_, WOFF_CAV, bv, nullptr, nullptr,
          nullptr, nullptr, Hp(OBD), Lp(OBD), C_, C_, 1.0f);
    // m0: Q=qk0,K=qk1,V=v1 -> BUF_E ; m1: Q=qk1,K=qk0,V=v0 -> BUF_D (Vt3 dead)
    flashm2_kernel<<<dim3(M_ / 64, B_ * H_), 256, 0, stream>>>(
        Hp(OBA), Lp(OBA), C_, 64, Hp(OBB), Lp(OBB), C_, 64,
        Hp(OBD), Lp(OBD), Hp(OBE), Lp(OBE), 0.125f);
    flashm2_kernel<<<dim3(M_ / 64, B_ * H_), 256, 0, stream>>>(
        Hp(OBB), Lp(OBB), C_, 64, Hp(OBA), Lp(OBA), C_, 64,
        Hp(OBC), Lp(OBC), Hp(OBD), Lp(OBD), 0.125f);
    // Wo: ao0 (A=BUF_E) -> msg0 BUF_A ; ao1 (A=BUF_D) -> msg1 BUF_B
    mgemm(Hp(OBE), Lp(OBE), Hp(OBE), Lp(OBE), C_, C_, WOFF_CAOUT, bo, nullptr, nullptr,
          Hp(OBA), Lp(OBA), nullptr, nullptr, C_, C_, 1.0f);
    mgemm(Hp(OBD), Lp(OBD), Hp(OBD), Lp(OBD), C_, C_, WOFF_CAOUT, bo, nullptr, nullptr,
          Hp(OBB), Lp(OBB), nullptr, nullptr, C_, C_, 1.0f);
    ffn(D0, Hp(OXS0), Lp(OXS0), Hp(OBA), Lp(OBA), WOFF_CAW1, b1, g, be, WOFF_CAW2, b2);
    ffn(D1, Hp(OXS1), Lp(OXS1), Hp(OBB), Lp(OBB), WOFF_CAW1, b1, g, be, WOFF_CAW2, b2);
  };

  // ---------------- pipeline
  hipMemcpyAsync(D0, desc0, N * sizeof(float), hipMemcpyDeviceToDevice, stream);
  hipMemcpyAsync(D1, desc1, N * sizeof(float), hipMemcpyDeviceToDevice, stream);
  split_kernel<<<PLN / 256, 256, 0, stream>>>(desc0, Hp(OXS0), Lp(OXS0));
  split_kernel<<<PLN / 256, 256, 0, stream>>>(desc1, Hp(OXS1), Lp(OXS1));
  posenc_kernel<<<(B_ * M_ * 32 + 255) / 256, 256, 0, stream>>>(kpts0, image_size, Wr, CC0, SC0);
  posenc_kernel<<<(B_ * M_ * 32 + 255) / 256, 256, 0, stream>>>(kpts1, image_size, Wr, CC1, SC1);

  for (int l = 0; l < L_; l++) {
    wconv_layer_kernel<<<WELEMS_ / 256, 256, 0, stream>>>(
        saqkv_W + (size_t)l * C_ * C3_, saout_W + (size_t)l * C_ * C_,
        saff_W1 + (size_t)l * C2_ * C2_, saff_W2 + (size_t)l * C2_ * C_,
        caqk_W + (size_t)l * C_ * C_, cav_W + (size_t)l * C_ * C_,
        caout_W + (size_t)l * C_ * C_, caff_W1 + (size_t)l * C2_ * C2_,
        caff_W2 + (size_t)l * C2_ * C_, WTH, WTL);
    self_block(D0, Hp(OXS0), Lp(OXS0), CC0, SC0, l);
    self_block(D1, Hp(OXS1), Lp(OXS1), CC1, SC1, l);
    cross_block(l);
  }

  // ---------------- final matching head
  wconv_kernel<<<(C_ << 8) >> 8, 256, 0, stream>>>(fproj_W, WTH, WTL, 8, C_);
  mgemm(Hp(OXS0), Lp(OXS0), Hp(OXS0), Lp(OXS0), C_, C_, 0, fproj_b, nullptr, S0,
        nullptr, nullptr, nullptr, nullptr, C_, C_, 0.25f);
  mgemm(Hp(OXS1), Lp(OXS1), Hp(OXS1), Lp(OXS1), C_, C_, 0, fproj_b, nullptr, S1,
        nullptr, nullptr, nullptr, nullptr, C_, C_, 0.25f);
  z_kernel<<<2048, 256, 0, stream>>>(D0, match_w, match_b, LS0, LSN0);
  z_kernel<<<2048, 256, 0, stream>>>(D1, match_w, match_b, LS1, LSN1);
  head_kernel<<<dim3(32, B_), 256, 0, stream>>>(S0, S1, nullptr, nullptr,
                                                LSE2, nullptr, nullptr, nullptr, 0);
  head_kernel<<<dim3(32, B_), 256, 0, stream>>>(S1, S0, nullptr, nullptr,
                                                LSE1, nullptr, nullptr, nullptr, 0);
  rcterm_kernel<<<32, 256, 0, stream>>>(LS0, LSE2, LS1, LSE1, RT, CT);
  head_kernel<<<dim3(32, B_), 256, 0, stream>>>(S0, S1, CT, RT,
                                                nullptr, MAX0, AM0, SCO, 1);
  head_kernel<<<dim3(32, B_), 256, 0, stream>>>(S1, S0, RT, nullptr,
                                                nullptr, nullptr, AM1, nullptr, 2);
  edge_kernel<<<32, 256, 0, stream>>>(LSN0, LSN1, SCO);
  match0ws_kernel<<<32, 256, 0, stream>>>(AM0, AM1, MAX0, MS0F, VAL0);
  finalout_kernel<<<32, 256, 0, stream>>>(AM0, AM1, MS0F, VAL0, ofp);

  (void)in_sizes; (void)n_in; (void)out_size; (void)ws_size;
}

// Round 4
// 7933.482 us; speedup vs baseline: 4.4888x; 1.2070x over previous
//
#include <hip/hip_runtime.h>
#include <hip/hip_bf16.h>
#include <cmath>

#define DEVI __device__ __forceinline__

constexpr int B_   = 4;
constexpr int M_   = 2048;
constexpr int C_   = 256;
constexpr int H_   = 4;
constexpr int HD_  = 64;
constexpr int L_   = 9;
constexpr int TOK_ = B_ * M_;     // 8192
constexpr int C2_  = 2 * C_;      // 512
constexpr int C3_  = 3 * C_;      // 768
constexpr int NS_  = 2049;        // scores dim

typedef __attribute__((ext_vector_type(8))) short s16x8;
typedef __attribute__((ext_vector_type(4))) float f32x4;
typedef __attribute__((ext_vector_type(4))) unsigned short u16x4;

// ---------------------------------------------------------------- helpers
DEVI float logsig_f(float x) {
  if (x >= 0.0f) return -log1pf(__expf(-x));
  return x - log1pf(__expf(x));
}

DEVI float gelu_tanh(float x) {
  float x3 = x * x * x;
  float t = 0.7978845608028654f * (x + 0.044715f * x3);
  return x / (1.0f + __expf(-2.0f * t));     // == 0.5x(1+tanh(t))
}

DEVI unsigned short f2bf(float x) {            // RNE fp32 -> bf16
  unsigned u = __float_as_uint(x);
  u += 0x7fffu + ((u >> 16) & 1u);
  return (unsigned short)(u >> 16);
}
DEVI float bf2f(unsigned short h) { return __uint_as_float((unsigned)h << 16); }

// ---------------------------------------------------------------- posenc
__global__ void posenc_kernel(const float* __restrict__ kpts, const float* __restrict__ wh,
                              const float* __restrict__ Wr, float* __restrict__ cc,
                              float* __restrict__ sc) {
  int idx = blockIdx.x * blockDim.x + threadIdx.x;   // B*M*32
  if (idx >= B_ * M_ * 32) return;
  int j  = idx & 31;
  int bm = idx >> 5;
  float w = wh[0], h = wh[1];
  float smax = fmaxf(w, h) * 0.5f;
  float kx = (kpts[bm * 2 + 0] - w * 0.5f) / smax;
  float ky = (kpts[bm * 2 + 1] - h * 0.5f) / smax;
  float p = kx * Wr[j] + ky * Wr[32 + j];
  cc[bm * 32 + j] = cosf(p);
  sc[bm * 32 + j] = sinf(p);
}

// ---------------------------------------------------------------- weight transpose + split (single matrix)
__global__ void wconv_kernel(const float* __restrict__ W, unsigned short* __restrict__ Th,
                             unsigned short* __restrict__ Tl, int kbits, int N) {
  int idx = blockIdx.x * 256 + threadIdx.x;
  int k = idx & ((1 << kbits) - 1);
  int n = idx >> kbits;
  float x = W[(size_t)k * N + n];
  unsigned short h = f2bf(x);
  Th[idx] = h;
  Tl[idx] = f2bf(x - bf2f(h));
}

// ---------------------------------------------------------------- all 9 per-layer weights in one launch
__global__ void wconv_layer_kernel(const float* __restrict__ qkv, const float* __restrict__ saout,
                                   const float* __restrict__ sw1, const float* __restrict__ sw2,
                                   const float* __restrict__ cqk, const float* __restrict__ cv,
                                   const float* __restrict__ cout_, const float* __restrict__ cw1,
                                   const float* __restrict__ cw2,
                                   unsigned short* __restrict__ Th, unsigned short* __restrict__ Tl) {
  int idx = blockIdx.x * 256 + threadIdx.x;   // < 1245184
  const float* src; int kbits, N, rel;
  if      (idx <  196608) { src = qkv;   kbits = 8; N = 768; rel = idx; }
  else if (idx <  262144) { src = saout; kbits = 8; N = 256; rel = idx -  196608; }
  else if (idx <  524288) { src = sw1;   kbits = 9; N = 512; rel = idx -  262144; }
  else if (idx <  655360) { src = sw2;   kbits = 9; N = 256; rel = idx -  524288; }
  else if (idx <  720896) { src = cqk;   kbits = 8; N = 256; rel = idx -  655360; }
  else if (idx <  786432) { src = cv;    kbits = 8; N = 256; rel = idx -  720896; }
  else if (idx <  851968) { src = cout_; kbits = 8; N = 256; rel = idx -  786432; }
  else if (idx < 1114112) { src = cw1;   kbits = 9; N = 512; rel = idx -  851968; }
  else                    { src = cw2;   kbits = 9; N = 256; rel = idx - 1114112; }
  int k = rel & ((1 << kbits) - 1), n = rel >> kbits;
  float x = src[(size_t)k * N + n];
  unsigned short h = f2bf(x);
  Th[idx] = h;
  Tl[idx] = f2bf(x - bf2f(h));
}

// ---------------------------------------------------------------- fp32 -> hi/lo planes (elementwise)
__global__ void split_kernel(const float* __restrict__ src, unsigned short* __restrict__ h,
                             unsigned short* __restrict__ l) {
  int idx = blockIdx.x * 256 + threadIdx.x;
  float x = src[idx];
  unsigned short hb = f2bf(x);
  h[idx] = hb;
  l[idx] = f2bf(x - bf2f(hb));
}

// ---------------------------------------------------------------- self-attn prep: RoPE + split Q,K (packed per bh)
__global__ __launch_bounds__(256) void prep_ropeqk_kernel(
    const float* __restrict__ S, const float* __restrict__ cc, const float* __restrict__ sc,
    unsigned short* __restrict__ Qh, unsigned short* __restrict__ Ql,
    unsigned short* __restrict__ Kh, unsigned short* __restrict__ Kl) {
  int idx = blockIdx.x * 256 + threadIdx.x;   // B*M*H*32
  int j = idx & 31;
  int h = (idx >> 5) & 3;
  int tok = idx >> 7;                          // 0..8191
  int m = tok & 2047, b = tok >> 11;
  const float* row = S + (size_t)tok * 768 + h * 64 + 2 * j;
  float c = cc[(size_t)tok * 32 + j];
  float s = sc[(size_t)tok * 32 + j];
  float2 q = *(const float2*)row;
  float2 k = *(const float2*)(row + 256);
  float qx = q.x * c - q.y * s, qy = q.y * c + q.x * s;
  float kx = k.x * c - k.y * s, ky = k.y * c + k.x * s;
  size_t o = ((size_t)(b * 4 + h) * 2048 + m) * 64 + 2 * j;
  unsigned short q0 = f2bf(qx), q1 = f2bf(qy);
  ushort2 t;
  t.x = q0; t.y = q1;                       *(ushort2*)&Qh[o] = t;
  t.x = f2bf(qx - bf2f(q0)); t.y = f2bf(qy - bf2f(q1)); *(ushort2*)&Ql[o] = t;
  unsigned short k0 = f2bf(kx), k1 = f2bf(ky);
  t.x = k0; t.y = k1;                       *(ushort2*)&Kh[o] = t;
  t.x = f2bf(kx - bf2f(k0)); t.y = f2bf(ky - bf2f(k1)); *(ushort2*)&Kl[o] = t;
}

// ---------------------------------------------------------------- self-attn prep: V transpose + split (packed per bh)
__global__ __launch_bounds__(256) void prep_vt_kernel(
    const float* __restrict__ S, int ld, int vcol,
    unsigned short* __restrict__ Vth, unsigned short* __restrict__ Vtl) {
  int idx = blockIdx.x * 256 + threadIdx.x;    // bh*64*512
  int mq = idx & 511; int m0 = mq << 2;
  int d = (idx >> 9) & 63;
  int bh = idx >> 15;
  int b = bh >> 2, h = bh & 3;
  const float* base = S + ((size_t)(b * 2048) + m0) * ld + vcol + h * 64 + d;
  u16x4 hv, lv;
#pragma unroll
  for (int i = 0; i < 4; i++) {
    float x = base[(size_t)i * ld];
    unsigned short hb = f2bf(x);
    hv[i] = hb;
    lv[i] = f2bf(x - bf2f(hb));
  }
  size_t o = ((size_t)bh * 64 + d) * 2048 + m0;
  *(u16x4*)&Vth[o] = hv;
  *(u16x4*)&Vtl[o] = lv;
}

// ---------------------------------------------------------------- split-bf16 MFMA GEMM, pre-split A
// out[m][n] = (sum_k A[m][k]*WT[n][k] + bias[n]) * oscale (+res)
// Outputs optional: outf fp32 stride ldo; split planes (stride 256) for col<nsplit;
// tvh/tvl transposed-packed [bh][64][2048] for col>=nsplit (or all cols if outh null).
__global__ __launch_bounds__(256, 3) void mgemm_kernel(
    const unsigned short* __restrict__ A1h, const unsigned short* __restrict__ A1l,
    const unsigned short* __restrict__ A2h, const unsigned short* __restrict__ A2l,
    int lda, int kSplit,
    const unsigned short* __restrict__ WTh, const unsigned short* __restrict__ WTl,
    const float* __restrict__ bias, const float* __restrict__ res,
    float* __restrict__ outf, int ldo,
    unsigned short* __restrict__ outh, unsigned short* __restrict__ outl, int nsplit,
    unsigned short* __restrict__ tvh, unsigned short* __restrict__ tvl,
    int K, float oscale) {
  __shared__ alignas(16) unsigned short Ash[128 * 64];
  __shared__ alignas(16) unsigned short Asl[128 * 64];
  __shared__ alignas(16) unsigned short Bsh[64 * 64];
  __shared__ alignas(16) unsigned short Bsl[64 * 64];
  int tid = threadIdx.x;
  int rowBase = blockIdx.y << 7;
  int colBase = blockIdx.x << 6;
  int lr = tid & 15, lg = (tid >> 4) & 3;
  int wid = tid >> 6, wm = wid >> 1, wn = wid & 1;
  int sw = (lr & 7) << 3;
  f32x4 acc[4][2] = {};

  for (int k0 = 0; k0 < K; k0 += 64) {
    const unsigned short *Ah, *Al;
    int kloc;
    if (k0 < kSplit) { Ah = A1h; Al = A1l; kloc = k0; }
    else             { Ah = A2h; Al = A2l; kloc = k0 - kSplit; }
    __syncthreads();
#pragma unroll
    for (int i = 0; i < 8; i++) {
      int idx = tid + (i << 8);
      int r = idx >> 4;
      int kc = (idx & 15) << 2;
      size_t g = (size_t)(rowBase + r) * lda + kloc + kc;
      u16x4 hv = *(const u16x4*)&Ah[g];
      u16x4 lv = *(const u16x4*)&Al[g];
      int col = kc ^ ((r & 7) << 3);
      *(u16x4*)&Ash[r * 64 + col] = hv;
      *(u16x4*)&Asl[r * 64 + col] = lv;
    }
#pragma unroll
    for (int i = 0; i < 4; i++) {
      int idx = tid + (i << 8);
      int rn = idx >> 4;
      int kc = (idx & 15) << 2;
      size_t g = (size_t)(colBase + rn) * K + k0 + kc;
      u16x4 hv = *(const u16x4*)&WTh[g];
      u16x4 lv = *(const u16x4*)&WTl[g];
      int col = kc ^ ((rn & 7) << 3);
      *(u16x4*)&Bsh[rn * 64 + col] = hv;
      *(u16x4*)&Bsl[rn * 64 + col] = lv;
    }
    __syncthreads();
#pragma unroll
    for (int c = 0; c < 2; c++) {
      int kcol = (c << 5) + (lg << 3);
      s16x8 ah[4], al[4], bh[2], bl[2];
#pragma unroll
      for (int mi = 0; mi < 4; mi++) {
        int off = (wm * 64 + mi * 16 + lr) * 64 + (kcol ^ sw);
        ah[mi] = *(const s16x8*)&Ash[off];
        al[mi] = *(const s16x8*)&Asl[off];
      }
#pragma unroll
      for (int ni = 0; ni < 2; ni++) {
        int off = (wn * 32 + ni * 16 + lr) * 64 + (kcol ^ sw);
        bh[ni] = *(const s16x8*)&Bsh[off];
        bl[ni] = *(const s16x8*)&Bsl[off];
      }
#pragma unroll
      for (int mi = 0; mi < 4; mi++)
#pragma unroll
        for (int ni = 0; ni < 2; ni++) {
          f32x4 t = acc[mi][ni];
          t = __builtin_amdgcn_mfma_f32_16x16x32_bf16(ah[mi], bl[ni], t, 0, 0, 0);
          t = __builtin_amdgcn_mfma_f32_16x16x32_bf16(al[mi], bh[ni], t, 0, 0, 0);
          t = __builtin_amdgcn_mfma_f32_16x16x32_bf16(ah[mi], bh[ni], t, 0, 0, 0);
          acc[mi][ni] = t;
        }
    }
  }
  // epilogue: C/D layout col = lane&15, row = (lane>>4)*4 + j
#pragma unroll
  for (int mi = 0; mi < 4; mi++) {
    int row0 = rowBase + wm * 64 + mi * 16 + lg * 4;
#pragma unroll
    for (int ni = 0; ni < 2; ni++) {
      int col = colBase + wn * 32 + ni * 16 + lr;
      float bc = bias ? bias[col] : 0.0f;
      float vj[4];
      size_t of0 = (size_t)row0 * ldo + col;
#pragma unroll
      for (int j = 0; j < 4; j++) {
        float v = (acc[mi][ni][j] + bc) * oscale;
        if (res) v += res[of0 + (size_t)j * ldo];
        vj[j] = v;
      }
      if (outf) {
#pragma unroll
        for (int j = 0; j < 4; j++) outf[of0 + (size_t)j * ldo] = vj[j];
      }
      bool plain = outh && (col < nsplit);
      if (plain) {
        size_t o0 = (size_t)row0 * 256 + col;
#pragma unroll
        for (int j = 0; j < 4; j++) {
          unsigned short hb = f2bf(vj[j]);
          outh[o0 + (size_t)j * 256] = hb;
          outl[o0 + (size_t)j * 256] = f2bf(vj[j] - bf2f(hb));
        }
      } else if (tvh) {
        int cc2 = outh ? (col - nsplit) : col;
        int hh = cc2 >> 6, d = cc2 & 63;
        int bb = row0 >> 11, m0 = row0 & 2047;
        u16x4 hv, lv;
#pragma unroll
        for (int j = 0; j < 4; j++) {
          unsigned short hb = f2bf(vj[j]);
          hv[j] = hb;
          lv[j] = f2bf(vj[j] - bf2f(hb));
        }
        size_t tvo = ((size_t)(bb * 4 + hh) * 64 + d) * 2048 + m0;
        *(u16x4*)&tvh[tvo] = hv;
        *(u16x4*)&tvl[tvo] = lv;
      }
    }
  }
}

// ---------------------------------------------------------------- MFMA flash attention, fully pre-split inputs
__global__ __launch_bounds__(256, 2) void flashm2_kernel(
    const unsigned short* __restrict__ Qh, const unsigned short* __restrict__ Ql, int ldq, int hq,
    const unsigned short* __restrict__ Kh, const unsigned short* __restrict__ Kl, int ldk, int hk,
    const unsigned short* __restrict__ Vth, const unsigned short* __restrict__ Vtl,
    unsigned short* __restrict__ Oh, unsigned short* __restrict__ Ol, float scale) {
  __shared__ alignas(16) unsigned short Ksh[64 * 64];
  __shared__ alignas(16) unsigned short Ksl[64 * 64];
  __shared__ alignas(16) unsigned short Vsh[64 * 64];
  __shared__ alignas(16) unsigned short Vsl[64 * 64];
  __shared__ alignas(16) unsigned short Ph[64 * 64];
  __shared__ alignas(16) unsigned short Pl[64 * 64];
  int bh = blockIdx.y;
  int b = bh >> 2, h = bh & 3;
  int mBase = blockIdx.x * 64;
  size_t qbase = (size_t)b * (M_ * C_) + (size_t)h * hq;
  size_t kbase = (size_t)b * (M_ * C_) + (size_t)h * hk;
  size_t vbase = (size_t)bh * (64 * 2048);
  int tid = threadIdx.x;
  int lane = tid & 63, w = tid >> 6;
  int lr = lane & 15, lg = lane >> 4;

  s16x8 qh[2], ql[2];
  {
    int m = mBase + w * 16 + lr;
#pragma unroll
    for (int c = 0; c < 2; c++) {
      size_t g = qbase + (size_t)m * ldq + c * 32 + lg * 8;
      qh[c] = *(const s16x8*)&Qh[g];
      ql[c] = *(const s16x8*)&Ql[g];
    }
  }

  float m_run[4], l_run[4];
  f32x4 oacc[4];
#pragma unroll
  for (int j = 0; j < 4; j++) { m_run[j] = -INFINITY; l_run[j] = 0.0f; }
#pragma unroll
  for (int g = 0; g < 4; g++) oacc[g] = (f32x4){0.f, 0.f, 0.f, 0.f};

  for (int t0 = 0; t0 < M_; t0 += 64) {
    __syncthreads();
#pragma unroll
    for (int i = 0; i < 4; i++) {
      int idx = tid + (i << 8);
      int key = idx >> 4;
      int d0 = (idx & 15) << 2;
      size_t g = kbase + (size_t)(t0 + key) * ldk + d0;
      int cswz = d0 ^ ((key & 7) << 3);
      *(u16x4*)&Ksh[key * 64 + cswz] = *(const u16x4*)&Kh[g];
      *(u16x4*)&Ksl[key * 64 + cswz] = *(const u16x4*)&Kl[g];
      int d = idx >> 4;
      int kc = (idx & 15) << 2;
      size_t gv = vbase + (size_t)d * 2048 + t0 + kc;
      int kk = kc ^ (((d ^ (d >> 2)) & 7) << 3);
      *(u16x4*)&Vsh[d * 64 + kk] = *(const u16x4*)&Vth[gv];
      *(u16x4*)&Vsl[d * 64 + kk] = *(const u16x4*)&Vtl[gv];
    }
    __syncthreads();

    f32x4 sacc[4];
#pragma unroll
    for (int f = 0; f < 4; f++) sacc[f] = (f32x4){0.f, 0.f, 0.f, 0.f};
#pragma unroll
    for (int f = 0; f < 4; f++) {
#pragma unroll
      for (int c = 0; c < 2; c++) {
        int key = f * 16 + lr;
        int kb = c * 32 + lg * 8;
        int off = key * 64 + (kb ^ ((key & 7) << 3));
        s16x8 kh = *(const s16x8*)&Ksh[off];
        s16x8 kl = *(const s16x8*)&Ksl[off];
        f32x4 t = sacc[f];
        t = __builtin_amdgcn_mfma_f32_16x16x32_bf16(qh[c], kl, t, 0, 0, 0);
        t = __builtin_amdgcn_mfma_f32_16x16x32_bf16(ql[c], kh, t, 0, 0, 0);
        t = __builtin_amdgcn_mfma_f32_16x16x32_bf16(qh[c], kh, t, 0, 0, 0);
        sacc[f] = t;
      }
    }
#pragma unroll
    for (int f = 0; f < 4; f++)
#pragma unroll
      for (int j = 0; j < 4; j++) sacc[f][j] *= scale;

    float mnew[4], alpha[4], lsum[4];
#pragma unroll
    for (int j = 0; j < 4; j++) {
      float v = fmaxf(fmaxf(sacc[0][j], sacc[1][j]), fmaxf(sacc[2][j], sacc[3][j]));
      v = fmaxf(v, __shfl_xor(v, 1));
      v = fmaxf(v, __shfl_xor(v, 2));
      v = fmaxf(v, __shfl_xor(v, 4));
      v = fmaxf(v, __shfl_xor(v, 8));
      mnew[j] = fmaxf(m_run[j], v);
      alpha[j] = __expf(m_run[j] - mnew[j]);
      lsum[j] = 0.0f;
    }
#pragma unroll
    for (int f = 0; f < 4; f++) {
#pragma unroll
      for (int j = 0; j < 4; j++) {
        float p = __expf(sacc[f][j] - mnew[j]);
        lsum[j] += p;
        int row = w * 16 + lg * 4 + j;
        int col = (f * 16 + lr) ^ ((row & 7) << 3);
        unsigned short hb = f2bf(p);
        Ph[row * 64 + col] = hb;
        Pl[row * 64 + col] = f2bf(p - bf2f(hb));
      }
    }
#pragma unroll
    for (int j = 0; j < 4; j++) {
      float s = lsum[j];
      s += __shfl_xor(s, 1);
      s += __shfl_xor(s, 2);
      s += __shfl_xor(s, 4);
      s += __shfl_xor(s, 8);
      l_run[j] = l_run[j] * alpha[j] + s;
      m_run[j] = mnew[j];
    }
#pragma unroll
    for (int g = 0; g < 4; g++) {
      f32x4 t = oacc[g];
#pragma unroll
      for (int j = 0; j < 4; j++) t[j] *= alpha[j];
      oacc[g] = t;
    }

    s16x8 pah[2], pal[2];
#pragma unroll
    for (int c = 0; c < 2; c++) {
      int row = w * 16 + lr;
      int kb = (c * 32 + lg * 8) ^ ((row & 7) << 3);
      pah[c] = *(const s16x8*)&Ph[row * 64 + kb];
      pal[c] = *(const s16x8*)&Pl[row * 64 + kb];
    }
#pragma unroll
    for (int g = 0; g < 4; g++) {
#pragma unroll
      for (int c = 0; c < 2; c++) {
        int d = g * 16 + lr;
        int kb = (c * 32 + lg * 8) ^ (((d ^ (d >> 2)) & 7) << 3);
        s16x8 vh = *(const s16x8*)&Vsh[d * 64 + kb];
        s16x8 vl = *(const s16x8*)&Vsl[d * 64 + kb];
        f32x4 t = oacc[g];
        t = __builtin_amdgcn_mfma_f32_16x16x32_bf16(pah[c], vl, t, 0, 0, 0);
        t = __builtin_amdgcn_mfma_f32_16x16x32_bf16(pal[c], vh, t, 0, 0, 0);
        t = __builtin_amdgcn_mfma_f32_16x16x32_bf16(pah[c], vh, t, 0, 0, 0);
        oacc[g] = t;
      }
    }
  }

#pragma unroll
  for (int j = 0; j < 4; j++) {
    float inv = 1.0f / l_run[j];
    int q = mBase + w * 16 + lg * 4 + j;
    size_t ob = ((size_t)b * M_ + q) * C_ + h * 64;
#pragma unroll
    for (int g = 0; g < 4; g++) {
      float v = oacc[g][j] * inv;
      unsigned short hb = f2bf(v);
      Oh[ob + g * 16 + lr] = hb;
      Ol[ob + g * 16 + lr] = f2bf(v - bf2f(hb));
    }
  }
}

// ---------------------------------------------------------------- LayerNorm + GELU -> split planes only
__global__ __launch_bounds__(256) void ln_gelu_kernel(const float* __restrict__ h,
                                                      const float* __restrict__ g,
                                                      const float* __restrict__ beta,
                                                      unsigned short* __restrict__ Hh,
                                                      unsigned short* __restrict__ Hl) {
  __shared__ float red[4];
  int t = blockIdx.x, tid = threadIdx.x;
  const float* hr = h + (size_t)t * C2_;
  float a = hr[tid], b2 = hr[tid + 256];
  float s = a + b2;
  for (int o = 1; o < 64; o <<= 1) s += __shfl_xor(s, o);
  if ((tid & 63) == 0) red[tid >> 6] = s;
  __syncthreads();
  float mu = (red[0] + red[1] + red[2] + red[3]) * (1.0f / 512.0f);
  __syncthreads();
  float da = a - mu, db = b2 - mu;
  s = da * da + db * db;
  for (int o = 1; o < 64; o <<= 1) s += __shfl_xor(s, o);
  if ((tid & 63) == 0) red[tid >> 6] = s;
  __syncthreads();
  float var = (red[0] + red[1] + red[2] + red[3]) * (1.0f / 512.0f);
  float rs = rsqrtf(var + 1e-5f);
  float xa = gelu_tanh(da * rs * g[tid] + beta[tid]);
  float xb = gelu_tanh(db * rs * g[tid + 256] + beta[tid + 256]);
  size_t o = (size_t)t * C2_;
  unsigned short ha = f2bf(xa), hb2 = f2bf(xb);
  Hh[o + tid]       = ha;
  Hl[o + tid]       = f2bf(xa - bf2f(ha));
  Hh[o + tid + 256] = hb2;
  Hl[o + tid + 256] = f2bf(xb - bf2f(hb2));
}

// ---------------------------------------------------------------- z = d @ match_w + b, log_sigmoid(+/-)
__global__ __launch_bounds__(256) void z_kernel(const float* __restrict__ d,
                                                const float* __restrict__ mw,
                                                const float* __restrict__ mb,
                                                float* __restrict__ ls,
                                                float* __restrict__ lsn) {
  int row = blockIdx.x * 4 + (threadIdx.x >> 6);
  int lane = threadIdx.x & 63;
  const float4* dr = (const float4*)(d + (size_t)row * C_);
  float4 v = dr[lane];
  float4 w4 = ((const float4*)mw)[lane];
  float s = v.x * w4.x + v.y * w4.y + v.z * w4.z + v.w * w4.w;
  for (int o = 1; o < 64; o <<= 1) s += __shfl_xor(s, o);
  if (lane == 0) {
    float zz = s + mb[0];
    ls[row]  = logsig_f(zz);
    lsn[row] = logsig_f(-zz);
  }
}

// ---------------------------------------------------------------- scores passes
// row-lse over 0.5*scores row -> RT = ls0 - lse  (one wave per row)
__global__ __launch_bounds__(256) void lse_row_kernel(const float* __restrict__ sco,
                                                      const float* __restrict__ ls0,
                                                      float* __restrict__ rt) {
  int row = blockIdx.x * 4 + (threadIdx.x >> 6);   // 0..8191
  int lane = threadIdx.x & 63;
  int b = row >> 11, m = row & 2047;
  const float* rp = sco + ((size_t)b * NS_ + m) * NS_;
  float v[32];
  float mx = -INFINITY;
#pragma unroll
  for (int i = 0; i < 32; i++) {
    v[i] = 0.5f * rp[i * 64 + lane];
    mx = fmaxf(mx, v[i]);
  }
  for (int o = 1; o < 64; o <<= 1) mx = fmaxf(mx, __shfl_xor(mx, o));
  float s = 0.0f;
#pragma unroll
  for (int i = 0; i < 32; i++) s += __expf(v[i] - mx);
  for (int o = 1; o < 64; o <<= 1) s += __shfl_xor(s, o);
  if (lane == 0) rt[row] = ls0[row] - (mx + logf(s));
}

// col-lse stage 1: partial (m,l) per col per 256-row chunk
__global__ void colred1_kernel(const float* __restrict__ sco, float* __restrict__ pm,
                               float* __restrict__ pl) {
  int col = blockIdx.x * 256 + threadIdx.x;
  int rc = blockIdx.y, b = blockIdx.z;
  const float* base = sco + (size_t)b * NS_ * NS_ + col;
  float mr = -INFINITY, lr_ = 0.0f;
  for (int r = rc * 256; r < rc * 256 + 256; r++) {
    float v = 0.5f * base[(size_t)r * NS_];
    float mn = fmaxf(mr, v);
    lr_ = lr_ * __expf(mr - mn) + __expf(v - mn);
    mr = mn;
  }
  size_t o = ((size_t)b * 8 + rc) * 2048 + col;
  pm[o] = mr; pl[o] = lr_;
}

// col-lse stage 2 -> CT = ls1 - lse
__global__ void colred2_kernel(const float* __restrict__ pm, const float* __restrict__ pl,
                               const float* __restrict__ ls1, float* __restrict__ ct) {
  int i = blockIdx.x * 256 + threadIdx.x;  // b*2048+col
  int b = i >> 11, col = i & 2047;
  float m = -INFINITY, l = 0.0f;
  for (int rc = 0; rc < 8; rc++) {
    size_t o = ((size_t)b * 8 + rc) * 2048 + col;
    float m2 = pm[o], l2 = pl[o];
    float mn = fmaxf(m, m2);
    l = l * __expf(m - mn) + l2 * __expf(m2 - mn);
    m = mn;
  }
  ct[i] = ls1[i] - (m + logf(l));
}

// finalize scores in place + row argmax/max (one wave per row)
__global__ __launch_bounds__(256) void upd_rowargmax_kernel(const float* __restrict__ rt,
                                                            const float* __restrict__ ct,
                                                            float* __restrict__ sco,
                                                            float* __restrict__ max_out,
                                                            int* __restrict__ am_out) {
  int row = blockIdx.x * 4 + (threadIdx.x >> 6);
  int lane = threadIdx.x & 63;
  int b = row >> 11, m = row & 2047;
  float* rp = sco + ((size_t)b * NS_ + m) * NS_;
  float rterm = rt[row];
  const float* ctb = ct + b * 2048;
  float best = -INFINITY; int bi = 0x7fffffff;
#pragma unroll
  for (int i = 0; i < 32; i++) {
    int c = i * 64 + lane;
    float v = rp[c] + rterm + ctb[c];
    rp[c] = v;
    if (v > best) { best = v; bi = c; }
  }
  for (int o = 1; o < 64; o <<= 1) {
    float v2 = __shfl_xor(best, o);
    int i2 = __shfl_xor(bi, o);
    if (v2 > best || (v2 == best && i2 < bi)) { best = v2; bi = i2; }
  }
  if (lane == 0) { max_out[row] = best; am_out[row] = bi; }
}

// col argmax stage 1 (on final scores)
__global__ void colamax1_kernel(const float* __restrict__ sco, float* __restrict__ pv,
                                int* __restrict__ pi) {
  int col = blockIdx.x * 256 + threadIdx.x;
  int rc = blockIdx.y, b = blockIdx.z;
  const float* base = sco + (size_t)b * NS_ * NS_ + col;
  float best = -INFINITY; int bi = 0;
  for (int r = rc * 256; r < rc * 256 + 256; r++) {
    float v = base[(size_t)r * NS_];
    if (v > best) { best = v; bi = r; }
  }
  size_t o = ((size_t)b * 8 + rc) * 2048 + col;
  pv[o] = best; pi[o] = bi;
}

// col argmax stage 2
__global__ void colamax2_kernel(const float* __restrict__ pv, const int* __restrict__ pi,
                                int* __restrict__ am1) {
  int i = blockIdx.x * 256 + threadIdx.x;
  int b = i >> 11, col = i & 2047;
  float best = -INFINITY; int bi = 0;
  for (int rc = 0; rc < 8; rc++) {
    size_t o = ((size_t)b * 8 + rc) * 2048 + col;
    float v = pv[o];
    if (v > best) { best = v; bi = pi[o]; }
  }
  am1[i] = bi;
}

// ---------------------------------------------------------------- scores edges
__global__ void edge_kernel(const float* __restrict__ lsn0, const float* __restrict__ lsn1,
                            float* __restrict__ sco) {
  int i = blockIdx.x * blockDim.x + threadIdx.x;   // B*2048
  if (i >= B_ * M_) return;
  int b = i >> 11, t = i & 2047;
  sco[((size_t)b * NS_ + t) * NS_ + 2048] = lsn0[i];
  sco[((size_t)b * NS_ + 2048) * NS_ + t] = lsn1[i];
  if (t == 0) sco[((size_t)b * NS_ + 2048) * NS_ + 2048] = 0.0f;
}

// ---------------------------------------------------------------- mscores0 / valid0
__global__ void match0ws_kernel(const int* __restrict__ am0, const int* __restrict__ am1,
                                const float* __restrict__ max0, float* __restrict__ ms0f,
                                int* __restrict__ val0) {
  int i = blockIdx.x * blockDim.x + threadIdx.x;
  if (i >= B_ * M_) return;
  int b = i >> 11, m = i & 2047;
  int a0 = am0[i];
  bool mutual = (am1[b * M_ + a0] == m);
  float ms = mutual ? __expf(max0[i]) : 0.0f;
  ms0f[i] = ms;
  val0[i] = (mutual && ms > 0.1f) ? 1 : 0;
}

// ---------------------------------------------------------------- final small outputs
__global__ void finalout_kernel(const int* __restrict__ am0, const int* __restrict__ am1,
                                const float* __restrict__ ms0f, const int* __restrict__ val0,
                                float* __restrict__ out) {
  int i = blockIdx.x * blockDim.x + threadIdx.x;
  if (i >= B_ * M_) return;
  int b = i >> 11, t = i & 2047;
  int a0 = am0[i];
  bool mut0 = (am1[b * M_ + a0] == t);
  float ms0 = ms0f[i];
  bool v0 = mut0 && (ms0 > 0.1f);
  out[i] = v0 ? (float)a0 : -1.0f;                  // m0
  out[2 * B_ * M_ + i] = ms0;                       // mscores0
  int a1 = am1[i];
  bool mut1 = (am0[b * M_ + a1] == t);
  float ms1 = mut1 ? ms0f[b * M_ + a1] : 0.0f;
  bool v1 = mut1 && (val0[b * M_ + a1] != 0);
  out[B_ * M_ + i] = v1 ? (float)a1 : -1.0f;        // m1
  out[3 * B_ * M_ + i] = ms1;                       // mscores1
}

// ================================================================ host
constexpr size_t WOFF_QKV   = 0;
constexpr size_t WOFF_SAOUT = 196608;
constexpr size_t WOFF_SAW1  = 262144;
constexpr size_t WOFF_SAW2  = 524288;
constexpr size_t WOFF_CAQK  = 655360;   // CAQK(256)+CAV(256) contiguous -> merged N=512
constexpr size_t WOFF_CAOUT = 786432;
constexpr size_t WOFF_CAW1  = 851968;
constexpr size_t WOFF_CAW2  = 1114112;
constexpr size_t WELEMS_    = 1245184;

constexpr size_t PLN   = (size_t)TOK_ * C_;          // 2,097,152 elems per plane
constexpr size_t OXS0  = 2 * WELEMS_;
constexpr size_t OXS1  = OXS0 + 2 * PLN;
constexpr size_t OBA   = OXS1 + 2 * PLN;
constexpr size_t OBB   = OBA + 2 * PLN;
constexpr size_t OBC   = OBB + 2 * PLN;
constexpr size_t OBD   = OBC + 2 * PLN;
constexpr size_t OBE   = OBD + 2 * PLN;

extern "C" void kernel_launch(void* const* d_in, const int* in_sizes, int n_in,
                              void* d_out, int out_size, void* d_ws, size_t ws_size,
                              hipStream_t stream) {
  const float* kpts0      = (const float*)d_in[0];
  const float* desc0      = (const float*)d_in[1];
  const float* kpts1      = (const float*)d_in[2];
  const float* desc1      = (const float*)d_in[3];
  const float* image_size = (const float*)d_in[4];
  const float* Wr         = (const float*)d_in[5];
  const float* saqkv_W    = (const float*)d_in[6];
  const float* saqkv_b    = (const float*)d_in[7];
  const float* saout_W    = (const float*)d_in[8];
  const float* saout_b    = (const float*)d_in[9];
  const float* saff_W1    = (const float*)d_in[10];
  const float* saff_b1    = (const float*)d_in[11];
  const float* saff_g     = (const float*)d_in[12];
  const float* saff_beta  = (const float*)d_in[13];
  const float* saff_W2    = (const float*)d_in[14];
  const float* saff_b2    = (const float*)d_in[15];
  const float* caqk_W     = (const float*)d_in[16];
  const float* caqk_b     = (const float*)d_in[17];
  const float* cav_W      = (const float*)d_in[18];
  const float* cav_b      = (const float*)d_in[19];
  const float* caout_W    = (const float*)d_in[20];
  const float* caout_b    = (const float*)d_in[21];
  const float* caff_W1    = (const float*)d_in[22];
  const float* caff_b1    = (const float*)d_in[23];
  const float* caff_g     = (const float*)d_in[24];
  const float* caff_beta  = (const float*)d_in[25];
  const float* caff_W2    = (const float*)d_in[26];
  const float* caff_b2    = (const float*)d_in[27];
  const float* fproj_W    = (const float*)d_in[28];
  const float* fproj_b    = (const float*)d_in[29];
  const float* match_w    = (const float*)d_in[30];
  const float* match_b    = (const float*)d_in[31];

  // FP32 output layout: m0@0, m1@8192, mscores0@16384, mscores1@24576, scores@32768
  float* ofp = (float*)d_out;
  float* SCO = ofp + 4 * B_ * M_;
  unsigned short* SCu = (unsigned short*)SCO;

  constexpr size_t N = (size_t)TOK_ * C_;
  constexpr size_t Qc = (size_t)B_ * M_ * 32;
  float* Wp  = (float*)d_ws;
  float* D0  = Wp;
  float* D1  = D0 + N;
  float* CC0 = D1 + N;
  float* SC0 = CC0 + Qc;
  float* CC1 = SC0 + Qc;
  float* SC1 = CC1 + Qc;
  float* S0  = SC1 + Qc;
  float* S1  = S0 + N;
  float* S2  = S1 + N;
  float* S3  = S2 + N;
  float* S4  = S3 + N;
  (void)S4;

  unsigned short* WTH = SCu;
  unsigned short* WTL = SCu + WELEMS_;

  // small final-phase arrays in S2 (free during final phase)
  float* LS0  = S2;
  float* LSN0 = LS0 + 8192;
  float* LS1  = LSN0 + 8192;
  float* LSN1 = LS1 + 8192;
  float* RT   = LSN1 + 8192;
  float* CT   = RT + 8192;
  float* MAX0 = CT + 8192;
  float* MS0F = MAX0 + 8192;
  int*   AM0  = (int*)(MS0F + 8192);
  int*   AM1  = AM0 + 8192;
  int*   VAL0 = AM1 + 8192;
  float* CB   = (float*)(VAL0 + 8192);     // 512-concat bias for merged cross proj
  // partials in S3
  float* PM = S3;
  float* PL = PM + 65536;
  float* PV = PL + 65536;
  int*   PI = (int*)(PV + 65536);
  // md split planes in ws (S0/S1) for final phase
  unsigned short* MD0u = (unsigned short*)S0;
  unsigned short* MD1u = (unsigned short*)S1;

  auto Hp = [&](size_t off) { return SCu + off; };
  auto Lp = [&](size_t off) { return SCu + off + PLN; };

  auto mgemm = [&](const unsigned short* a1h, const unsigned short* a1l,
                   const unsigned short* a2h, const unsigned short* a2l,
                   int lda, int kSplit, const unsigned short* wth, const unsigned short* wtl,
                   const float* bias, const float* res, float* outf, int ldo,
                   unsigned short* outh, unsigned short* outl, int nsplit,
                   unsigned short* tvh, unsigned short* tvl,
                   int K, int Ncols, int Mrows, float osc) {
    mgemm_kernel<<<dim3(Ncols >> 6, Mrows >> 7), 256, 0, stream>>>(
        a1h, a1l, a2h, a2l, lda, kSplit, wth, wtl,
        bias, res, outf, ldo, outh, outl, nsplit, tvh, tvl, K, osc);
  };

  auto ffn = [&](float* X, unsigned short* xsh, unsigned short* xsl,
                 unsigned short* msgh, unsigned short* msgl,
                 size_t offW1, const float* b1, const float* g, const float* be,
                 size_t offW2, const float* b2) {
    mgemm(xsh, xsl, msgh, msgl, C_, C_, WTH + offW1, WTL + offW1,
          b1, nullptr, S0, C2_, nullptr, nullptr, 0, nullptr, nullptr, C2_, C2_, TOK_, 1.0f);
    ln_gelu_kernel<<<TOK_, 256, 0, stream>>>(S0, g, be, Hp(OBC), Hp(OBD));
    mgemm(Hp(OBC), Hp(OBD), Hp(OBC), Hp(OBD), C2_, C2_, WTH + offW2, WTL + offW2,
          b2, X, X, C_, xsh, xsl, C_, nullptr, nullptr, C2_, C_, TOK_, 1.0f);
  };

  auto self_block = [&](float* X, unsigned short* xsh, unsigned short* xsl,
                        const float* cc, const float* sc, int l) {
    const float* bqkv = saqkv_b + (size_t)l * C3_;
    const float* bo   = saout_b + (size_t)l * C_;
    mgemm(xsh, xsl, xsh, xsl, C_, C_, WTH + WOFF_QKV, WTL + WOFF_QKV,
          bqkv, nullptr, S0, C3_, nullptr, nullptr, 0, nullptr, nullptr, C_, C3_, TOK_, 1.0f);
    prep_ropeqk_kernel<<<4096, 256, 0, stream>>>(S0, cc, sc, Hp(OBA), Lp(OBA), Hp(OBB), Lp(OBB));
    prep_vt_kernel<<<2048, 256, 0, stream>>>(S0, C3_, C2_, Hp(OBC), Lp(OBC));
    flashm2_kernel<<<dim3(M_ / 64, B_ * H_), 256, 0, stream>>>(
        Hp(OBA), Lp(OBA), 64, 2048 * 64, Hp(OBB), Lp(OBB), 64, 2048 * 64,
        Hp(OBC), Lp(OBC), Hp(OBE), Lp(OBE), 0.125f);
    mgemm(Hp(OBE), Lp(OBE), Hp(OBE), Lp(OBE), C_, C_, WTH + WOFF_SAOUT, WTL + WOFF_SAOUT,
          bo, nullptr, nullptr, C_, Hp(OBA), Lp(OBA), C_, nullptr, nullptr, C_, C_, TOK_, 1.0f);
    ffn(X, xsh, xsl, Hp(OBA), Lp(OBA),
        WOFF_SAW1, saff_b1 + (size_t)l * C2_,
        saff_g + (size_t)l * C2_, saff_beta + (size_t)l * C2_,
        WOFF_SAW2, saff_b2 + (size_t)l * C_);
  };

  auto cross_block = [&](int l) {
    const float* bo  = caout_b + (size_t)l * C_;
    const float* b1  = caff_b1 + (size_t)l * C2_;
    const float* g   = caff_g + (size_t)l * C2_;
    const float* be  = caff_beta + (size_t)l * C2_;
    const float* b2  = caff_b2 + (size_t)l * C_;
    // concat bias [bqk | bv]
    hipMemcpyAsync(CB, caqk_b + (size_t)l * C_, C_ * sizeof(float),
                   hipMemcpyDeviceToDevice, stream);
    hipMemcpyAsync(CB + C_, cav_b + (size_t)l * C_, C_ * sizeof(float),
                   hipMemcpyDeviceToDevice, stream);
    // merged qk+v projection: image0 -> qk in OBA (plain) + v in OBC (tv);
    //                         image1 -> qk in OBB + v in OBD
    mgemm(Hp(OXS0), Lp(OXS0), Hp(OXS0), Lp(OXS0), C_, C_, WTH + WOFF_CAQK, WTL + WOFF_CAQK,
          CB, nullptr, nullptr, C_, Hp(OBA), Lp(OBA), C_, Hp(OBC), Lp(OBC), C_, C2_, TOK_, 1.0f);
    mgemm(Hp(OXS1), Lp(OXS1), Hp(OXS1), Lp(OXS1), C_, C_, WTH + WOFF_CAQK, WTL + WOFF_CAQK,
          CB, nullptr, nullptr, C_, Hp(OBB), Lp(OBB), C_, Hp(OBD), Lp(OBD), C_, C2_, TOK_, 1.0f);
    // m0: Q=qk0,K=qk1,V=v1 -> OBE ; m1: Q=qk1,K=qk0,V=v0 -> OBD
    flashm2_kernel<<<dim3(M_ / 64, B_ * H_), 256, 0, stream>>>(
        Hp(OBA), Lp(OBA), C_, 64, Hp(OBB), Lp(OBB), C_, 64,
        Hp(OBD), Lp(OBD), Hp(OBE), Lp(OBE), 0.125f);
    flashm2_kernel<<<dim3(M_ / 64, B_ * H_), 256, 0, stream>>>(
        Hp(OBB), Lp(OBB), C_, 64, Hp(OBA), Lp(OBA), C_, 64,
        Hp(OBC), Lp(OBC), Hp(OBD), Lp(OBD), 0.125f);
    mgemm(Hp(OBE), Lp(OBE), Hp(OBE), Lp(OBE), C_, C_, WTH + WOFF_CAOUT, WTL + WOFF_CAOUT,
          bo, nullptr, nullptr, C_, Hp(OBA), Lp(OBA), C_, nullptr, nullptr, C_, C_, TOK_, 1.0f);
    mgemm(Hp(OBD), Lp(OBD), Hp(OBD), Lp(OBD), C_, C_, WTH + WOFF_CAOUT, WTL + WOFF_CAOUT,
          bo, nullptr, nullptr, C_, Hp(OBB), Lp(OBB), C_, nullptr, nullptr, C_, C_, TOK_, 1.0f);
    ffn(D0, Hp(OXS0), Lp(OXS0), Hp(OBA), Lp(OBA), WOFF_CAW1, b1, g, be, WOFF_CAW2, b2);
    ffn(D1, Hp(OXS1), Lp(OXS1), Hp(OBB), Lp(OBB), WOFF_CAW1, b1, g, be, WOFF_CAW2, b2);
  };

  // ---------------- pipeline
  hipMemcpyAsync(D0, desc0, N * sizeof(float), hipMemcpyDeviceToDevice, stream);
  hipMemcpyAsync(D1, desc1, N * sizeof(float), hipMemcpyDeviceToDevice, stream);
  split_kernel<<<PLN / 256, 256, 0, stream>>>(desc0, Hp(OXS0), Lp(OXS0));
  split_kernel<<<PLN / 256, 256, 0, stream>>>(desc1, Hp(OXS1), Lp(OXS1));
  posenc_kernel<<<(B_ * M_ * 32 + 255) / 256, 256, 0, stream>>>(kpts0, image_size, Wr, CC0, SC0);
  posenc_kernel<<<(B_ * M_ * 32 + 255) / 256, 256, 0, stream>>>(kpts1, image_size, Wr, CC1, SC1);

  for (int l = 0; l < L_; l++) {
    wconv_layer_kernel<<<WELEMS_ / 256, 256, 0, stream>>>(
        saqkv_W + (size_t)l * C_ * C3_, saout_W + (size_t)l * C_ * C_,
        saff_W1 + (size_t)l * C2_ * C2_, saff_W2 + (size_t)l * C2_ * C_,
        caqk_W + (size_t)l * C_ * C_, cav_W + (size_t)l * C_ * C_,
        caout_W + (size_t)l * C_ * C_, caff_W1 + (size_t)l * C2_ * C2_,
        caff_W2 + (size_t)l * C2_ * C_, WTH, WTL);
    self_block(D0, Hp(OXS0), Lp(OXS0), CC0, SC0, l);
    self_block(D1, Hp(OXS1), Lp(OXS1), CC1, SC1, l);
    cross_block(l);
  }

  // ---------------- final matching head (MFMA sim + streaming passes)
  wconv_kernel<<<(C_ << 8) >> 8, 256, 0, stream>>>(fproj_W, WTH, WTL, 8, C_);
  // md0 -> split planes in S0, md1 -> S1 (oscale = 1/C^0.25 = 0.25)
  mgemm(Hp(OXS0), Lp(OXS0), Hp(OXS0), Lp(OXS0), C_, C_, WTH, WTL,
        fproj_b, nullptr, nullptr, C_, MD0u, MD0u + PLN, C_, nullptr, nullptr,
        C_, C_, TOK_, 0.25f);
  mgemm(Hp(OXS1), Lp(OXS1), Hp(OXS1), Lp(OXS1), C_, C_, WTH, WTL,
        fproj_b, nullptr, nullptr, C_, MD1u, MD1u + PLN, C_, nullptr, nullptr,
        C_, C_, TOK_, 0.25f);
  z_kernel<<<2048, 256, 0, stream>>>(D0, match_w, match_b, LS0, LSN0);
  z_kernel<<<2048, 256, 0, stream>>>(D1, match_w, match_b, LS1, LSN1);
  // scores inner = 2*sim via MFMA, per batch (B operand = md1 rows = [N][K])
  for (int b = 0; b < B_; b++) {
    size_t ao = (size_t)b * M_ * C_;
    mgemm(MD0u + ao, MD0u + PLN + ao, MD0u + ao, MD0u + PLN + ao, C_, C_,
          MD1u + ao, MD1u + PLN + ao, nullptr, nullptr,
          SCO + (size_t)b * NS_ * NS_, NS_, nullptr, nullptr, 0, nullptr, nullptr,
          C_, M_, M_, 2.0f);
  }
  edge_kernel<<<32, 256, 0, stream>>>(LSN0, LSN1, SCO);
  lse_row_kernel<<<2048, 256, 0, stream>>>(SCO, LS0, RT);
  colred1_kernel<<<dim3(8, 8, 4), 256, 0, stream>>>(SCO, PM, PL);
  colred2_kernel<<<32, 256, 0, stream>>>(PM, PL, LS1, CT);
  upd_rowargmax_kernel<<<2048, 256, 0, stream>>>(RT, CT, SCO, MAX0, AM0);
  colamax1_kernel<<<dim3(8, 8, 4), 256, 0, stream>>>(SCO, PV, PI);
  colamax2_kernel<<<32, 256, 0, stream>>>(PV, PI, AM1);
  match0ws_kernel<<<32, 256, 0, stream>>>(AM0, AM1, MAX0, MS0F, VAL0);
  finalout_kernel<<<32, 256, 0, stream>>>(AM0, AM1, MS0F, VAL0, ofp);

  (void)in_sizes; (void)n_in; (void)out_size; (void)ws_size;
}

// Round 5
// 7158.040 us; speedup vs baseline: 4.9751x; 1.1083x over previous
//
#include <hip/hip_runtime.h>
#include <hip/hip_bf16.h>
#include <cmath>

#define DEVI __device__ __forceinline__

constexpr int B_   = 4;
constexpr int M_   = 2048;
constexpr int C_   = 256;
constexpr int H_   = 4;
constexpr int HD_  = 64;
constexpr int L_   = 9;
constexpr int TOK_ = B_ * M_;     // 8192
constexpr int C2_  = 2 * C_;      // 512
constexpr int C3_  = 3 * C_;      // 768
constexpr int NS_  = 2049;        // scores dim

typedef __attribute__((ext_vector_type(8))) short s16x8;
typedef __attribute__((ext_vector_type(4))) float f32x4;
typedef __attribute__((ext_vector_type(4))) unsigned short u16x4;

// ---------------------------------------------------------------- helpers
DEVI float logsig_f(float x) {
  if (x >= 0.0f) return -log1pf(__expf(-x));
  return x - log1pf(__expf(x));
}

DEVI float gelu_tanh(float x) {
  float x3 = x * x * x;
  float t = 0.7978845608028654f * (x + 0.044715f * x3);
  return x / (1.0f + __expf(-2.0f * t));     // == 0.5x(1+tanh(t))
}

DEVI unsigned short f2bf(float x) {            // RNE fp32 -> bf16
  unsigned u = __float_as_uint(x);
  u += 0x7fffu + ((u >> 16) & 1u);
  return (unsigned short)(u >> 16);
}
DEVI float bf2f(unsigned short h) { return __uint_as_float((unsigned)h << 16); }

// ---------------------------------------------------------------- posenc
__global__ void posenc_kernel(const float* __restrict__ kpts, const float* __restrict__ wh,
                              const float* __restrict__ Wr, float* __restrict__ cc,
                              float* __restrict__ sc) {
  int idx = blockIdx.x * blockDim.x + threadIdx.x;   // B*M*32
  if (idx >= B_ * M_ * 32) return;
  int j  = idx & 31;
  int bm = idx >> 5;
  float w = wh[0], h = wh[1];
  float smax = fmaxf(w, h) * 0.5f;
  float kx = (kpts[bm * 2 + 0] - w * 0.5f) / smax;
  float ky = (kpts[bm * 2 + 1] - h * 0.5f) / smax;
  float p = kx * Wr[j] + ky * Wr[32 + j];
  cc[bm * 32 + j] = cosf(p);
  sc[bm * 32 + j] = sinf(p);
}

// ---------------------------------------------------------------- weight transpose + split (single matrix)
__global__ void wconv_kernel(const float* __restrict__ W, unsigned short* __restrict__ Th,
                             unsigned short* __restrict__ Tl, int kbits, int N) {
  int idx = blockIdx.x * 256 + threadIdx.x;
  int k = idx & ((1 << kbits) - 1);
  int n = idx >> kbits;
  float x = W[(size_t)k * N + n];
  unsigned short h = f2bf(x);
  Th[idx] = h;
  Tl[idx] = f2bf(x - bf2f(h));
}

// ---------------------------------------------------------------- all 9 per-layer weights in one launch
__global__ void wconv_layer_kernel(const float* __restrict__ qkv, const float* __restrict__ saout,
                                   const float* __restrict__ sw1, const float* __restrict__ sw2,
                                   const float* __restrict__ cqk, const float* __restrict__ cv,
                                   const float* __restrict__ cout_, const float* __restrict__ cw1,
                                   const float* __restrict__ cw2,
                                   unsigned short* __restrict__ Th, unsigned short* __restrict__ Tl) {
  int idx = blockIdx.x * 256 + threadIdx.x;   // < 1245184
  const float* src; int kbits, N, rel;
  if      (idx <  196608) { src = qkv;   kbits = 8; N = 768; rel = idx; }
  else if (idx <  262144) { src = saout; kbits = 8; N = 256; rel = idx -  196608; }
  else if (idx <  524288) { src = sw1;   kbits = 9; N = 512; rel = idx -  262144; }
  else if (idx <  655360) { src = sw2;   kbits = 9; N = 256; rel = idx -  524288; }
  else if (idx <  720896) { src = cqk;   kbits = 8; N = 256; rel = idx -  655360; }
  else if (idx <  786432) { src = cv;    kbits = 8; N = 256; rel = idx -  720896; }
  else if (idx <  851968) { src = cout_; kbits = 8; N = 256; rel = idx -  786432; }
  else if (idx < 1114112) { src = cw1;   kbits = 9; N = 512; rel = idx -  851968; }
  else                    { src = cw2;   kbits = 9; N = 256; rel = idx - 1114112; }
  int k = rel & ((1 << kbits) - 1), n = rel >> kbits;
  float x = src[(size_t)k * N + n];
  unsigned short h = f2bf(x);
  Th[idx] = h;
  Tl[idx] = f2bf(x - bf2f(h));
}

// ---------------------------------------------------------------- concat cross bias for all layers
__global__ void cbias_kernel(const float* __restrict__ qkb, const float* __restrict__ vb,
                             float* __restrict__ cb) {
  int i = blockIdx.x * 256 + threadIdx.x;    // L*512
  if (i >= L_ * 512) return;
  int l = i >> 9, c = i & 511;
  cb[i] = (c < 256) ? qkb[l * 256 + c] : vb[l * 256 + (c - 256)];
}

// ---------------------------------------------------------------- fp32 -> hi/lo planes (elementwise)
__global__ void split_kernel(const float* __restrict__ src, unsigned short* __restrict__ h,
                             unsigned short* __restrict__ l) {
  int idx = blockIdx.x * 256 + threadIdx.x;
  float x = src[idx];
  unsigned short hb = f2bf(x);
  h[idx] = hb;
  l[idx] = f2bf(x - bf2f(hb));
}

// ---------------------------------------------------------------- split-bf16 MFMA GEMM, pre-split A
// out = (A@W^T + bias)*oscale (+res). Epilogue modes:
//   outf: fp32 stride ldo
//   outh/outl: split planes stride 256 (col<nsplit)
//   tvh/tvl: transposed-packed [bb*4+h][64][2048] (col>=nsplit)
//   ccp!=null: QKV-fused — col<512: RoPE+split packed Q/K; col>=512: V->tv
__global__ __launch_bounds__(256, 3) void mgemm_kernel(
    const unsigned short* __restrict__ A1h, const unsigned short* __restrict__ A1l,
    const unsigned short* __restrict__ A2h, const unsigned short* __restrict__ A2l,
    int lda, int kSplit,
    const unsigned short* __restrict__ WTh, const unsigned short* __restrict__ WTl,
    const float* __restrict__ bias, const float* __restrict__ res,
    float* __restrict__ outf, int ldo,
    unsigned short* __restrict__ outh, unsigned short* __restrict__ outl, int nsplit,
    unsigned short* __restrict__ tvh, unsigned short* __restrict__ tvl,
    const float* __restrict__ ccp, const float* __restrict__ scp,
    unsigned short* __restrict__ qph, unsigned short* __restrict__ qpl,
    unsigned short* __restrict__ kph, unsigned short* __restrict__ kpl,
    int K, float oscale) {
  __shared__ alignas(16) unsigned short Ash[128 * 64];
  __shared__ alignas(16) unsigned short Asl[128 * 64];
  __shared__ alignas(16) unsigned short Bsh[64 * 64];
  __shared__ alignas(16) unsigned short Bsl[64 * 64];
  int tid = threadIdx.x;
  int rowBase = blockIdx.y << 7;
  int colBase = blockIdx.x << 6;
  int lr = tid & 15, lg = (tid >> 4) & 3;
  int wid = tid >> 6, wm = wid >> 1, wn = wid & 1;
  int sw = (lr & 7) << 3;
  f32x4 acc[4][2] = {};

  for (int k0 = 0; k0 < K; k0 += 64) {
    const unsigned short *Ah, *Al;
    int kloc;
    if (k0 < kSplit) { Ah = A1h; Al = A1l; kloc = k0; }
    else             { Ah = A2h; Al = A2l; kloc = k0 - kSplit; }
    __syncthreads();
#pragma unroll
    for (int i = 0; i < 8; i++) {
      int idx = tid + (i << 8);
      int r = idx >> 4;
      int kc = (idx & 15) << 2;
      size_t g = (size_t)(rowBase + r) * lda + kloc + kc;
      u16x4 hv = *(const u16x4*)&Ah[g];
      u16x4 lv = *(const u16x4*)&Al[g];
      int col = kc ^ ((r & 7) << 3);
      *(u16x4*)&Ash[r * 64 + col] = hv;
      *(u16x4*)&Asl[r * 64 + col] = lv;
    }
#pragma unroll
    for (int i = 0; i < 4; i++) {
      int idx = tid + (i << 8);
      int rn = idx >> 4;
      int kc = (idx & 15) << 2;
      size_t g = (size_t)(colBase + rn) * K + k0 + kc;
      u16x4 hv = *(const u16x4*)&WTh[g];
      u16x4 lv = *(const u16x4*)&WTl[g];
      int col = kc ^ ((rn & 7) << 3);
      *(u16x4*)&Bsh[rn * 64 + col] = hv;
      *(u16x4*)&Bsl[rn * 64 + col] = lv;
    }
    __syncthreads();
#pragma unroll
    for (int c = 0; c < 2; c++) {
      int kcol = (c << 5) + (lg << 3);
      s16x8 ah[4], al[4], bh[2], bl[2];
#pragma unroll
      for (int mi = 0; mi < 4; mi++) {
        int off = (wm * 64 + mi * 16 + lr) * 64 + (kcol ^ sw);
        ah[mi] = *(const s16x8*)&Ash[off];
        al[mi] = *(const s16x8*)&Asl[off];
      }
#pragma unroll
      for (int ni = 0; ni < 2; ni++) {
        int off = (wn * 32 + ni * 16 + lr) * 64 + (kcol ^ sw);
        bh[ni] = *(const s16x8*)&Bsh[off];
        bl[ni] = *(const s16x8*)&Bsl[off];
      }
#pragma unroll
      for (int mi = 0; mi < 4; mi++)
#pragma unroll
        for (int ni = 0; ni < 2; ni++) {
          f32x4 t = acc[mi][ni];
          t = __builtin_amdgcn_mfma_f32_16x16x32_bf16(ah[mi], bl[ni], t, 0, 0, 0);
          t = __builtin_amdgcn_mfma_f32_16x16x32_bf16(al[mi], bh[ni], t, 0, 0, 0);
          t = __builtin_amdgcn_mfma_f32_16x16x32_bf16(ah[mi], bh[ni], t, 0, 0, 0);
          acc[mi][ni] = t;
        }
    }
  }
  // epilogue: C/D layout col = lane&15, row = (lane>>4)*4 + j
#pragma unroll
  for (int mi = 0; mi < 4; mi++) {
    int row0 = rowBase + wm * 64 + mi * 16 + lg * 4;
#pragma unroll
    for (int ni = 0; ni < 2; ni++) {
      int col = colBase + wn * 32 + ni * 16 + lr;
      float bc = bias ? bias[col] : 0.0f;
      float vj[4];
      size_t of0 = (size_t)row0 * ldo + col;
#pragma unroll
      for (int j = 0; j < 4; j++) {
        float v = (acc[mi][ni][j] + bc) * oscale;
        if (res) v += res[of0 + (size_t)j * ldo];
        vj[j] = v;
      }
      if (ccp) {
        // wave-uniform branch: col block of 16 is entirely <512 or >=512
        if (col < 512) {
          float pv[4];
#pragma unroll
          for (int j = 0; j < 4; j++) pv[j] = __shfl_xor(vj[j], 1);
          int d = col & 63;
          int hh = (col >> 6) & 3;
          int ji = (d >> 1) & 31;
          bool isK = col >= 256;
          unsigned short* dh = isK ? kph : qph;
          unsigned short* dl = isK ? kpl : qpl;
          int bb = row0 >> 11;
#pragma unroll
          for (int j = 0; j < 4; j++) {
            int tok = row0 + j;
            float c = ccp[(size_t)tok * 32 + ji];
            float s = scp[(size_t)tok * 32 + ji];
            float r = (col & 1) ? (vj[j] * c + pv[j] * s)
                                : (vj[j] * c - pv[j] * s);
            size_t o = ((size_t)(bb * 4 + hh) * 2048 + (tok & 2047)) * 64 + d;
            unsigned short hb = f2bf(r);
            dh[o] = hb;
            dl[o] = f2bf(r - bf2f(hb));
          }
        } else {
          int cc2 = col - 512;
          int hh = cc2 >> 6, d = cc2 & 63;
          int bb = row0 >> 11, mv = row0 & 2047;
          u16x4 hv, lv;
#pragma unroll
          for (int j = 0; j < 4; j++) {
            unsigned short hb = f2bf(vj[j]);
            hv[j] = hb; lv[j] = f2bf(vj[j] - bf2f(hb));
          }
          size_t tvo = ((size_t)(bb * 4 + hh) * 64 + d) * 2048 + mv;
          *(u16x4*)&tvh[tvo] = hv;
          *(u16x4*)&tvl[tvo] = lv;
        }
      } else {
        if (outf) {
#pragma unroll
          for (int j = 0; j < 4; j++) outf[of0 + (size_t)j * ldo] = vj[j];
        }
        bool plain = outh && (col < nsplit);
        if (plain) {
          size_t o0 = (size_t)row0 * 256 + col;
#pragma unroll
          for (int j = 0; j < 4; j++) {
            unsigned short hb = f2bf(vj[j]);
            outh[o0 + (size_t)j * 256] = hb;
            outl[o0 + (size_t)j * 256] = f2bf(vj[j] - bf2f(hb));
          }
        } else if (tvh) {
          int cc2 = outh ? (col - nsplit) : col;
          int hh = cc2 >> 6, d = cc2 & 63;
          int bb = row0 >> 11, mv = row0 & 2047;
          u16x4 hv, lv;
#pragma unroll
          for (int j = 0; j < 4; j++) {
            unsigned short hb = f2bf(vj[j]);
            hv[j] = hb;
            lv[j] = f2bf(vj[j] - bf2f(hb));
          }
          size_t tvo = ((size_t)(bb * 4 + hh) * 64 + d) * 2048 + mv;
          *(u16x4*)&tvh[tvo] = hv;
          *(u16x4*)&tvl[tvo] = lv;
        }
      }
    }
  }
}

// ---------------------------------------------------------------- MFMA flash attention, fully pre-split inputs
__global__ __launch_bounds__(256, 2) void flashm2_kernel(
    const unsigned short* __restrict__ Qh, const unsigned short* __restrict__ Ql, int ldq, int hq,
    const unsigned short* __restrict__ Kh, const unsigned short* __restrict__ Kl, int ldk, int hk,
    const unsigned short* __restrict__ Vth, const unsigned short* __restrict__ Vtl, int voff,
    unsigned short* __restrict__ Oh, unsigned short* __restrict__ Ol, float scale) {
  __shared__ alignas(16) unsigned short Ksh[64 * 64];
  __shared__ alignas(16) unsigned short Ksl[64 * 64];
  __shared__ alignas(16) unsigned short Vsh[64 * 64];
  __shared__ alignas(16) unsigned short Vsl[64 * 64];
  __shared__ alignas(16) unsigned short Ph[64 * 64];
  __shared__ alignas(16) unsigned short Pl[64 * 64];
  int bh = blockIdx.y;
  int b = bh >> 2, h = bh & 3;
  int mBase = blockIdx.x * 64;
  size_t qbase = (size_t)b * (M_ * C_) + (size_t)h * hq;
  size_t kbase = (size_t)b * (M_ * C_) + (size_t)h * hk;
  size_t vbase = (size_t)(voff + bh) * (64 * 2048);
  int tid = threadIdx.x;
  int lane = tid & 63, w = tid >> 6;
  int lr = lane & 15, lg = lane >> 4;

  s16x8 qh[2], ql[2];
  {
    int m = mBase + w * 16 + lr;
#pragma unroll
    for (int c = 0; c < 2; c++) {
      size_t g = qbase + (size_t)m * ldq + c * 32 + lg * 8;
      qh[c] = *(const s16x8*)&Qh[g];
      ql[c] = *(const s16x8*)&Ql[g];
    }
  }

  float m_run[4], l_run[4];
  f32x4 oacc[4];
#pragma unroll
  for (int j = 0; j < 4; j++) { m_run[j] = -INFINITY; l_run[j] = 0.0f; }
#pragma unroll
  for (int g = 0; g < 4; g++) oacc[g] = (f32x4){0.f, 0.f, 0.f, 0.f};

  for (int t0 = 0; t0 < M_; t0 += 64) {
    __syncthreads();
#pragma unroll
    for (int i = 0; i < 4; i++) {
      int idx = tid + (i << 8);
      int key = idx >> 4;
      int d0 = (idx & 15) << 2;
      size_t g = kbase + (size_t)(t0 + key) * ldk + d0;
      int cswz = d0 ^ ((key & 7) << 3);
      *(u16x4*)&Ksh[key * 64 + cswz] = *(const u16x4*)&Kh[g];
      *(u16x4*)&Ksl[key * 64 + cswz] = *(const u16x4*)&Kl[g];
      int d = idx >> 4;
      int kc = (idx & 15) << 2;
      size_t gv = vbase + (size_t)d * 2048 + t0 + kc;
      int kk = kc ^ (((d ^ (d >> 2)) & 7) << 3);
      *(u16x4*)&Vsh[d * 64 + kk] = *(const u16x4*)&Vth[gv];
      *(u16x4*)&Vsl[d * 64 + kk] = *(const u16x4*)&Vtl[gv];
    }
    __syncthreads();

    f32x4 sacc[4];
#pragma unroll
    for (int f = 0; f < 4; f++) sacc[f] = (f32x4){0.f, 0.f, 0.f, 0.f};
#pragma unroll
    for (int f = 0; f < 4; f++) {
#pragma unroll
      for (int c = 0; c < 2; c++) {
        int key = f * 16 + lr;
        int kb = c * 32 + lg * 8;
        int off = key * 64 + (kb ^ ((key & 7) << 3));
        s16x8 kh = *(const s16x8*)&Ksh[off];
        s16x8 kl = *(const s16x8*)&Ksl[off];
        f32x4 t = sacc[f];
        t = __builtin_amdgcn_mfma_f32_16x16x32_bf16(qh[c], kl, t, 0, 0, 0);
        t = __builtin_amdgcn_mfma_f32_16x16x32_bf16(ql[c], kh, t, 0, 0, 0);
        t = __builtin_amdgcn_mfma_f32_16x16x32_bf16(qh[c], kh, t, 0, 0, 0);
        sacc[f] = t;
      }
    }
#pragma unroll
    for (int f = 0; f < 4; f++)
#pragma unroll
      for (int j = 0; j < 4; j++) sacc[f][j] *= scale;

    float mnew[4], alpha[4], lsum[4];
#pragma unroll
    for (int j = 0; j < 4; j++) {
      float v = fmaxf(fmaxf(sacc[0][j], sacc[1][j]), fmaxf(sacc[2][j], sacc[3][j]));
      v = fmaxf(v, __shfl_xor(v, 1));
      v = fmaxf(v, __shfl_xor(v, 2));
      v = fmaxf(v, __shfl_xor(v, 4));
      v = fmaxf(v, __shfl_xor(v, 8));
      mnew[j] = fmaxf(m_run[j], v);
      alpha[j] = __expf(m_run[j] - mnew[j]);
      lsum[j] = 0.0f;
    }
#pragma unroll
    for (int f = 0; f < 4; f++) {
#pragma unroll
      for (int j = 0; j < 4; j++) {
        float p = __expf(sacc[f][j] - mnew[j]);
        lsum[j] += p;
        int row = w * 16 + lg * 4 + j;
        int col = (f * 16 + lr) ^ ((row & 7) << 3);
        unsigned short hb = f2bf(p);
        Ph[row * 64 + col] = hb;
        Pl[row * 64 + col] = f2bf(p - bf2f(hb));
      }
    }
#pragma unroll
    for (int j = 0; j < 4; j++) {
      float s = lsum[j];
      s += __shfl_xor(s, 1);
      s += __shfl_xor(s, 2);
      s += __shfl_xor(s, 4);
      s += __shfl_xor(s, 8);
      l_run[j] = l_run[j] * alpha[j] + s;
      m_run[j] = mnew[j];
    }
#pragma unroll
    for (int g = 0; g < 4; g++) {
      f32x4 t = oacc[g];
#pragma unroll
      for (int j = 0; j < 4; j++) t[j] *= alpha[j];
      oacc[g] = t;
    }

    s16x8 pah[2], pal[2];
#pragma unroll
    for (int c = 0; c < 2; c++) {
      int row = w * 16 + lr;
      int kb = (c * 32 + lg * 8) ^ ((row & 7) << 3);
      pah[c] = *(const s16x8*)&Ph[row * 64 + kb];
      pal[c] = *(const s16x8*)&Pl[row * 64 + kb];
    }
#pragma unroll
    for (int g = 0; g < 4; g++) {
#pragma unroll
      for (int c = 0; c < 2; c++) {
        int d = g * 16 + lr;
        int kb = (c * 32 + lg * 8) ^ (((d ^ (d >> 2)) & 7) << 3);
        s16x8 vh = *(const s16x8*)&Vsh[d * 64 + kb];
        s16x8 vl = *(const s16x8*)&Vsl[d * 64 + kb];
        f32x4 t = oacc[g];
        t = __builtin_amdgcn_mfma_f32_16x16x32_bf16(pah[c], vl, t, 0, 0, 0);
        t = __builtin_amdgcn_mfma_f32_16x16x32_bf16(pal[c], vh, t, 0, 0, 0);
        t = __builtin_amdgcn_mfma_f32_16x16x32_bf16(pah[c], vh, t, 0, 0, 0);
        oacc[g] = t;
      }
    }
  }

#pragma unroll
  for (int j = 0; j < 4; j++) {
    float inv = 1.0f / l_run[j];
    int q = mBase + w * 16 + lg * 4 + j;
    size_t ob = ((size_t)b * M_ + q) * C_ + h * 64;
#pragma unroll
    for (int g = 0; g < 4; g++) {
      float v = oacc[g][j] * inv;
      unsigned short hb = f2bf(v);
      Oh[ob + g * 16 + lr] = hb;
      Ol[ob + g * 16 + lr] = f2bf(v - bf2f(hb));
    }
  }
}

// ---------------------------------------------------------------- LayerNorm + GELU -> split planes only
__global__ __launch_bounds__(256) void ln_gelu_kernel(const float* __restrict__ h,
                                                      const float* __restrict__ g,
                                                      const float* __restrict__ beta,
                                                      unsigned short* __restrict__ Hh,
                                                      unsigned short* __restrict__ Hl) {
  __shared__ float red[4];
  int t = blockIdx.x, tid = threadIdx.x;
  const float* hr = h + (size_t)t * C2_;
  float a = hr[tid], b2 = hr[tid + 256];
  float s = a + b2;
  for (int o = 1; o < 64; o <<= 1) s += __shfl_xor(s, o);
  if ((tid & 63) == 0) red[tid >> 6] = s;
  __syncthreads();
  float mu = (red[0] + red[1] + red[2] + red[3]) * (1.0f / 512.0f);
  __syncthreads();
  float da = a - mu, db = b2 - mu;
  s = da * da + db * db;
  for (int o = 1; o < 64; o <<= 1) s += __shfl_xor(s, o);
  if ((tid & 63) == 0) red[tid >> 6] = s;
  __syncthreads();
  float var = (red[0] + red[1] + red[2] + red[3]) * (1.0f / 512.0f);
  float rs = rsqrtf(var + 1e-5f);
  float xa = gelu_tanh(da * rs * g[tid] + beta[tid]);
  float xb = gelu_tanh(db * rs * g[tid + 256] + beta[tid + 256]);
  size_t o = (size_t)t * C2_;
  unsigned short ha = f2bf(xa), hb2 = f2bf(xb);
  Hh[o + tid]       = ha;
  Hl[o + tid]       = f2bf(xa - bf2f(ha));
  Hh[o + tid + 256] = hb2;
  Hl[o + tid + 256] = f2bf(xb - bf2f(hb2));
}

// ---------------------------------------------------------------- z = d @ match_w + b, log_sigmoid(+/-)
__global__ __launch_bounds__(256) void z_kernel(const float* __restrict__ d,
                                                const float* __restrict__ mw,
                                                const float* __restrict__ mb,
                                                float* __restrict__ ls,
                                                float* __restrict__ lsn) {
  int row = blockIdx.x * 4 + (threadIdx.x >> 6);
  int lane = threadIdx.x & 63;
  const float4* dr = (const float4*)(d + (size_t)row * C_);
  float4 v = dr[lane];
  float4 w4 = ((const float4*)mw)[lane];
  float s = v.x * w4.x + v.y * w4.y + v.z * w4.z + v.w * w4.w;
  for (int o = 1; o < 64; o <<= 1) s += __shfl_xor(s, o);
  if (lane == 0) {
    float zz = s + mb[0];
    ls[row]  = logsig_f(zz);
    lsn[row] = logsig_f(-zz);
  }
}

// ---------------------------------------------------------------- scores passes
__global__ __launch_bounds__(256) void lse_row_kernel(const float* __restrict__ sco,
                                                      const float* __restrict__ ls0,
                                                      float* __restrict__ rt) {
  int row = blockIdx.x * 4 + (threadIdx.x >> 6);   // 0..8191
  int lane = threadIdx.x & 63;
  int b = row >> 11, m = row & 2047;
  const float* rp = sco + ((size_t)b * NS_ + m) * NS_;
  float v[32];
  float mx = -INFINITY;
#pragma unroll
  for (int i = 0; i < 32; i++) {
    v[i] = 0.5f * rp[i * 64 + lane];
    mx = fmaxf(mx, v[i]);
  }
  for (int o = 1; o < 64; o <<= 1) mx = fmaxf(mx, __shfl_xor(mx, o));
  float s = 0.0f;
#pragma unroll
  for (int i = 0; i < 32; i++) s += __expf(v[i] - mx);
  for (int o = 1; o < 64; o <<= 1) s += __shfl_xor(s, o);
  if (lane == 0) rt[row] = ls0[row] - (mx + logf(s));
}

__global__ void colred1_kernel(const float* __restrict__ sco, float* __restrict__ pm,
                               float* __restrict__ pl) {
  int col = blockIdx.x * 256 + threadIdx.x;
  int rc = blockIdx.y, b = blockIdx.z;
  const float* base = sco + (size_t)b * NS_ * NS_ + col;
  float mr = -INFINITY, lr_ = 0.0f;
  for (int r = rc * 256; r < rc * 256 + 256; r++) {
    float v = 0.5f * base[(size_t)r * NS_];
    float mn = fmaxf(mr, v);
    lr_ = lr_ * __expf(mr - mn) + __expf(v - mn);
    mr = mn;
  }
  size_t o = ((size_t)b * 8 + rc) * 2048 + col;
  pm[o] = mr; pl[o] = lr_;
}

__global__ void colred2_kernel(const float* __restrict__ pm, const float* __restrict__ pl,
                               const float* __restrict__ ls1, float* __restrict__ ct) {
  int i = blockIdx.x * 256 + threadIdx.x;  // b*2048+col
  int b = i >> 11, col = i & 2047;
  float m = -INFINITY, l = 0.0f;
  for (int rc = 0; rc < 8; rc++) {
    size_t o = ((size_t)b * 8 + rc) * 2048 + col;
    float m2 = pm[o], l2 = pl[o];
    float mn = fmaxf(m, m2);
    l = l * __expf(m - mn) + l2 * __expf(m2 - mn);
    m = mn;
  }
  ct[i] = ls1[i] - (m + logf(l));
}

__global__ __launch_bounds__(256) void upd_rowargmax_kernel(const float* __restrict__ rt,
                                                            const float* __restrict__ ct,
                                                            float* __restrict__ sco,
                                                            float* __restrict__ max_out,
                                                            int* __restrict__ am_out) {
  int row = blockIdx.x * 4 + (threadIdx.x >> 6);
  int lane = threadIdx.x & 63;
  int b = row >> 11, m = row & 2047;
  float* rp = sco + ((size_t)b * NS_ + m) * NS_;
  float rterm = rt[row];
  const float* ctb = ct + b * 2048;
  float best = -INFINITY; int bi = 0x7fffffff;
#pragma unroll
  for (int i = 0; i < 32; i++) {
    int c = i * 64 + lane;
    float v = rp[c] + rterm + ctb[c];
    rp[c] = v;
    if (v > best) { best = v; bi = c; }
  }
  for (int o = 1; o < 64; o <<= 1) {
    float v2 = __shfl_xor(best, o);
    int i2 = __shfl_xor(bi, o);
    if (v2 > best || (v2 == best && i2 < bi)) { best = v2; bi = i2; }
  }
  if (lane == 0) { max_out[row] = best; am_out[row] = bi; }
}

__global__ void colamax1_kernel(const float* __restrict__ sco, float* __restrict__ pv,
                                int* __restrict__ pi) {
  int col = blockIdx.x * 256 + threadIdx.x;
  int rc = blockIdx.y, b = blockIdx.z;
  const float* base = sco + (size_t)b * NS_ * NS_ + col;
  float best = -INFINITY; int bi = 0;
  for (int r = rc * 256; r < rc * 256 + 256; r++) {
    float v = base[(size_t)r * NS_];
    if (v > best) { best = v; bi = r; }
  }
  size_t o = ((size_t)b * 8 + rc) * 2048 + col;
  pv[o] = best; pi[o] = bi;
}

__global__ void colamax2_kernel(const float* __restrict__ pv, const int* __restrict__ pi,
                                int* __restrict__ am1) {
  int i = blockIdx.x * 256 + threadIdx.x;
  int b = i >> 11, col = i & 2047;
  float best = -INFINITY; int bi = 0;
  for (int rc = 0; rc < 8; rc++) {
    size_t o = ((size_t)b * 8 + rc) * 2048 + col;
    float v = pv[o];
    if (v > best) { best = v; bi = pi[o]; }
  }
  am1[i] = bi;
}

__global__ void edge_kernel(const float* __restrict__ lsn0, const float* __restrict__ lsn1,
                            float* __restrict__ sco) {
  int i = blockIdx.x * blockDim.x + threadIdx.x;   // B*2048
  if (i >= B_ * M_) return;
  int b = i >> 11, t = i & 2047;
  sco[((size_t)b * NS_ + t) * NS_ + 2048] = lsn0[i];
  sco[((size_t)b * NS_ + 2048) * NS_ + t] = lsn1[i];
  if (t == 0) sco[((size_t)b * NS_ + 2048) * NS_ + 2048] = 0.0f;
}

__global__ void match0ws_kernel(const int* __restrict__ am0, const int* __restrict__ am1,
                                const float* __restrict__ max0, float* __restrict__ ms0f,
                                int* __restrict__ val0) {
  int i = blockIdx.x * blockDim.x + threadIdx.x;
  if (i >= B_ * M_) return;
  int b = i >> 11, m = i & 2047;
  int a0 = am0[i];
  bool mutual = (am1[b * M_ + a0] == m);
  float ms = mutual ? __expf(max0[i]) : 0.0f;
  ms0f[i] = ms;
  val0[i] = (mutual && ms > 0.1f) ? 1 : 0;
}

__global__ void finalout_kernel(const int* __restrict__ am0, const int* __restrict__ am1,
                                const float* __restrict__ ms0f, const int* __restrict__ val0,
                                float* __restrict__ out) {
  int i = blockIdx.x * blockDim.x + threadIdx.x;
  if (i >= B_ * M_) return;
  int b = i >> 11, t = i & 2047;
  int a0 = am0[i];
  bool mut0 = (am1[b * M_ + a0] == t);
  float ms0 = ms0f[i];
  bool v0 = mut0 && (ms0 > 0.1f);
  out[i] = v0 ? (float)a0 : -1.0f;                  // m0
  out[2 * B_ * M_ + i] = ms0;                       // mscores0
  int a1 = am1[i];
  bool mut1 = (am0[b * M_ + a1] == t);
  float ms1 = mut1 ? ms0f[b * M_ + a1] : 0.0f;
  bool v1 = mut1 && (val0[b * M_ + a1] != 0);
  out[B_ * M_ + i] = v1 ? (float)a1 : -1.0f;        // m1
  out[3 * B_ * M_ + i] = ms1;                       // mscores1
}

// ================================================================ host
constexpr size_t WOFF_QKV   = 0;
constexpr size_t WOFF_SAOUT = 196608;
constexpr size_t WOFF_SAW1  = 262144;
constexpr size_t WOFF_SAW2  = 524288;
constexpr size_t WOFF_CAQK  = 655360;   // CAQK(256)+CAV(256) contiguous -> merged N=512
constexpr size_t WOFF_CAOUT = 786432;
constexpr size_t WOFF_CAW1  = 851968;
constexpr size_t WOFF_CAW2  = 1114112;
constexpr size_t WELEMS_    = 1245184;

constexpr size_t PLN  = (size_t)TOK_ * C_;          // 2,097,152 elems per plane-unit
constexpr size_t XHO  = 2 * WELEMS_;                // X hi: [img0 | img1] 2PLN
constexpr size_t XLO  = XHO + 2 * PLN;              // X lo: 2PLN
constexpr size_t POOL = XLO + 2 * PLN;              // P0..P9 (10 PLN); end 31,850,496 < 33,587,208

extern "C" void kernel_launch(void* const* d_in, const int* in_sizes, int n_in,
                              void* d_out, int out_size, void* d_ws, size_t ws_size,
                              hipStream_t stream) {
  const float* kpts0      = (const float*)d_in[0];
  const float* desc0      = (const float*)d_in[1];
  const float* kpts1      = (const float*)d_in[2];
  const float* desc1      = (const float*)d_in[3];
  const float* image_size = (const float*)d_in[4];
  const float* Wr         = (const float*)d_in[5];
  const float* saqkv_W    = (const float*)d_in[6];
  const float* saqkv_b    = (const float*)d_in[7];
  const float* saout_W    = (const float*)d_in[8];
  const float* saout_b    = (const float*)d_in[9];
  const float* saff_W1    = (const float*)d_in[10];
  const float* saff_b1    = (const float*)d_in[11];
  const float* saff_g     = (const float*)d_in[12];
  const float* saff_beta  = (const float*)d_in[13];
  const float* saff_W2    = (const float*)d_in[14];
  const float* saff_b2    = (const float*)d_in[15];
  const float* caqk_W     = (const float*)d_in[16];
  const float* caqk_b     = (const float*)d_in[17];
  const float* cav_W      = (const float*)d_in[18];
  const float* cav_b      = (const float*)d_in[19];
  const float* caout_W    = (const float*)d_in[20];
  const float* caout_b    = (const float*)d_in[21];
  const float* caff_W1    = (const float*)d_in[22];
  const float* caff_b1    = (const float*)d_in[23];
  const float* caff_g     = (const float*)d_in[24];
  const float* caff_beta  = (const float*)d_in[25];
  const float* caff_W2    = (const float*)d_in[26];
  const float* caff_b2    = (const float*)d_in[27];
  const float* fproj_W    = (const float*)d_in[28];
  const float* fproj_b    = (const float*)d_in[29];
  const float* match_w    = (const float*)d_in[30];
  const float* match_b    = (const float*)d_in[31];

  // FP32 output layout: m0@0, m1@8192, mscores0@16384, mscores1@24576, scores@32768
  float* ofp = (float*)d_out;
  float* SCO = ofp + 4 * B_ * M_;
  unsigned short* SCu = (unsigned short*)SCO;

  constexpr size_t N = (size_t)TOK_ * C_;
  constexpr size_t Qc = (size_t)B_ * M_ * 32;
  float* Wp  = (float*)d_ws;
  float* D0  = Wp;                 // fp32 X img0 (residual master)
  float* D1  = D0 + N;             // fp32 X img1 (adjacent -> combined res)
  float* CC0 = D1 + N;
  float* SC0 = CC0 + Qc;
  float* CC1 = SC0 + Qc;
  float* SC1 = CC1 + Qc;
  float* S0  = SC1 + Qc;           // fp32 scratch: combined W1 out spans S0..S3
  float* S1  = S0 + N;
  float* S2  = S1 + N;
  float* S3  = S2 + N;
  float* S4  = S3 + N;

  unsigned short* WTH = SCu;
  unsigned short* WTL = SCu + WELEMS_;
  unsigned short* XH  = SCu + XHO;
  unsigned short* XL  = SCu + XLO;
  auto Pu = [&](int k) { return SCu + POOL + (size_t)k * PLN; };

  // small final-phase arrays in S2
  float* LS0  = S2;
  float* LSN0 = LS0 + 8192;
  float* LS1  = LSN0 + 8192;
  float* LSN1 = LS1 + 8192;
  float* RT   = LSN1 + 8192;
  float* CT   = RT + 8192;
  float* MAX0 = CT + 8192;
  float* MS0F = MAX0 + 8192;
  int*   AM0  = (int*)(MS0F + 8192);
  int*   AM1  = AM0 + 8192;
  int*   VAL0 = AM1 + 8192;
  // partials in S3
  float* PM = S3;
  float* PL = PM + 65536;
  float* PV = PL + 65536;
  int*   PI = (int*)(PV + 65536);
  // cross concat bias (all layers) in S4
  float* CB = S4;
  // md split planes (final) at S0..S1
  unsigned short* MDu = (unsigned short*)S0;

  auto mg = [&](const unsigned short* a1h, const unsigned short* a1l,
                const unsigned short* a2h, const unsigned short* a2l,
                int lda, int kSplit, const unsigned short* wth, const unsigned short* wtl,
                const float* bias, const float* res, float* outf, int ldo,
                unsigned short* outh, unsigned short* outl, int nsplit,
                unsigned short* tvh, unsigned short* tvl,
                const float* ccp, const float* scp,
                unsigned short* qph, unsigned short* qpl,
                unsigned short* kph, unsigned short* kpl,
                int K, int Ncols, int Mrows, float osc) {
    mgemm_kernel<<<dim3(Ncols >> 6, Mrows >> 7), 256, 0, stream>>>(
        a1h, a1l, a2h, a2l, lda, kSplit, wth, wtl, bias, res, outf, ldo,
        outh, outl, nsplit, tvh, tvl, ccp, scp, qph, qpl, kph, kpl, K, osc);
  };

  // combined ffn for both images: msg split in [P0,P1](hi) [P2,P3](lo)
  auto ffn2 = [&](size_t offW1, const float* b1, const float* g, const float* be,
                  size_t offW2, const float* b2) {
    mg(XH, XL, Pu(0), Pu(2), C_, C_, WTH + offW1, WTL + offW1,
       b1, nullptr, S0, C2_, nullptr, nullptr, 0, nullptr, nullptr,
       nullptr, nullptr, nullptr, nullptr, nullptr, nullptr, C2_, C2_, 2 * TOK_, 1.0f);
    ln_gelu_kernel<<<2 * TOK_, 256, 0, stream>>>(S0, g, be, Pu(0), Pu(4));
    mg(Pu(0), Pu(4), Pu(0), Pu(4), C2_, C2_, WTH + offW2, WTL + offW2,
       b2, D0, D0, C_, XH, XL, C_, nullptr, nullptr,
       nullptr, nullptr, nullptr, nullptr, nullptr, nullptr, C2_, C_, 2 * TOK_, 1.0f);
  };

  // ---------------- pipeline
  hipMemcpyAsync(D0, desc0, N * sizeof(float), hipMemcpyDeviceToDevice, stream);
  hipMemcpyAsync(D1, desc1, N * sizeof(float), hipMemcpyDeviceToDevice, stream);
  split_kernel<<<PLN / 256, 256, 0, stream>>>(desc0, XH, XL);
  split_kernel<<<PLN / 256, 256, 0, stream>>>(desc1, XH + PLN, XL + PLN);
  posenc_kernel<<<(B_ * M_ * 32 + 255) / 256, 256, 0, stream>>>(kpts0, image_size, Wr, CC0, SC0);
  posenc_kernel<<<(B_ * M_ * 32 + 255) / 256, 256, 0, stream>>>(kpts1, image_size, Wr, CC1, SC1);
  cbias_kernel<<<(L_ * 512 + 255) / 256, 256, 0, stream>>>(caqk_b, cav_b, CB);

  for (int l = 0; l < L_; l++) {
    wconv_layer_kernel<<<WELEMS_ / 256, 256, 0, stream>>>(
        saqkv_W + (size_t)l * C_ * C3_, saout_W + (size_t)l * C_ * C_,
        saff_W1 + (size_t)l * C2_ * C2_, saff_W2 + (size_t)l * C2_ * C_,
        caqk_W + (size_t)l * C_ * C_, cav_W + (size_t)l * C_ * C_,
        caout_W + (size_t)l * C_ * C_, caff_W1 + (size_t)l * C2_ * C2_,
        caff_W2 + (size_t)l * C2_ * C_, WTH, WTL);
    const float* bqkv = saqkv_b + (size_t)l * C3_;
    const float* bo   = saout_b + (size_t)l * C_;

    // ---- self attention (per image: QKV w/ fused RoPE+split+Vt, then flash)
    for (int i = 0; i < 2; i++) {
      const float* cc = i ? CC1 : CC0;
      const float* sc = i ? SC1 : SC0;
      mg(XH + i * PLN, XL + i * PLN, XH + i * PLN, XL + i * PLN, C_, C_,
         WTH + WOFF_QKV, WTL + WOFF_QKV, bqkv, nullptr, nullptr, C3_,
         nullptr, nullptr, 0, Pu(4), Pu(5),
         cc, sc, Pu(0), Pu(1), Pu(2), Pu(3), C_, C3_, TOK_, 1.0f);
      flashm2_kernel<<<dim3(M_ / 64, B_ * H_), 256, 0, stream>>>(
          Pu(0), Pu(1), 64, 2048 * 64, Pu(2), Pu(3), 64, 2048 * 64,
          Pu(4), Pu(5), 0, Pu(6 + i), Pu(8 + i), 0.125f);
    }
    // Wo combined -> msg in [P0,P1]/[P2,P3]
    mg(Pu(6), Pu(8), Pu(6), Pu(8), C_, C_, WTH + WOFF_SAOUT, WTL + WOFF_SAOUT,
       bo, nullptr, nullptr, C_, Pu(0), Pu(2), C_, nullptr, nullptr,
       nullptr, nullptr, nullptr, nullptr, nullptr, nullptr, C_, C_, 2 * TOK_, 1.0f);
    ffn2(WOFF_SAW1, saff_b1 + (size_t)l * C2_,
         saff_g + (size_t)l * C2_, saff_beta + (size_t)l * C2_,
         WOFF_SAW2, saff_b2 + (size_t)l * C_);

    // ---- cross attention
    // merged qk+v proj combined: qk plain -> [P0,P1]/[P2,P3], vt -> [P4,P5]/[P6,P7]
    mg(XH, XL, XH, XL, C_, C_, WTH + WOFF_CAQK, WTL + WOFF_CAQK,
       CB + (size_t)l * 512, nullptr, nullptr, C2_, Pu(0), Pu(2), C_, Pu(4), Pu(6),
       nullptr, nullptr, nullptr, nullptr, nullptr, nullptr, C_, C2_, 2 * TOK_, 1.0f);
    // m0: Q=qk0,K=qk1,V=v1(voff16) -> P8/P9 ; m1: Q=qk1,K=qk0,V=v0 -> P5/P7 (v1 dead)
    flashm2_kernel<<<dim3(M_ / 64, B_ * H_), 256, 0, stream>>>(
        Pu(0), Pu(2), C_, 64, Pu(1), Pu(3), C_, 64,
        Pu(4), Pu(6), 16, Pu(8), Pu(9), 0.125f);
    flashm2_kernel<<<dim3(M_ / 64, B_ * H_), 256, 0, stream>>>(
        Pu(1), Pu(3), C_, 64, Pu(0), Pu(2), C_, 64,
        Pu(4), Pu(6), 0, Pu(5), Pu(7), 0.125f);
    // Wo per half -> msg halves
    mg(Pu(8), Pu(9), Pu(8), Pu(9), C_, C_, WTH + WOFF_CAOUT, WTL + WOFF_CAOUT,
       caout_b + (size_t)l * C_, nullptr, nullptr, C_, Pu(0), Pu(2), C_,
       nullptr, nullptr, nullptr, nullptr, nullptr, nullptr, nullptr, nullptr,
       C_, C_, TOK_, 1.0f);
    mg(Pu(5), Pu(7), Pu(5), Pu(7), C_, C_, WTH + WOFF_CAOUT, WTL + WOFF_CAOUT,
       caout_b + (size_t)l * C_, nullptr, nullptr, C_, Pu(1), Pu(3), C_,
       nullptr, nullptr, nullptr, nullptr, nullptr, nullptr, nullptr, nullptr,
       C_, C_, TOK_, 1.0f);
    ffn2(WOFF_CAW1, caff_b1 + (size_t)l * C2_,
         caff_g + (size_t)l * C2_, caff_beta + (size_t)l * C2_,
         WOFF_CAW2, caff_b2 + (size_t)l * C_);
  }

  // ---------------- final matching head
  wconv_kernel<<<(C_ << 8) >> 8, 256, 0, stream>>>(fproj_W, WTH, WTL, 8, C_);
  // md combined (both images) -> MDu: hi 2PLN [img0|img1], lo 2PLN
  mg(XH, XL, XH, XL, C_, C_, WTH, WTL, fproj_b, nullptr, nullptr, C_,
     MDu, MDu + 2 * PLN, C_, nullptr, nullptr,
     nullptr, nullptr, nullptr, nullptr, nullptr, nullptr, C_, C_, 2 * TOK_, 0.25f);
  z_kernel<<<2048, 256, 0, stream>>>(D0, match_w, match_b, LS0, LSN0);
  z_kernel<<<2048, 256, 0, stream>>>(D1, match_w, match_b, LS1, LSN1);
  // scores inner = 2*sim via MFMA, per batch
  for (int b = 0; b < B_; b++) {
    size_t ao = (size_t)b * M_ * C_;
    mg(MDu + ao, MDu + 2 * PLN + ao, MDu + ao, MDu + 2 * PLN + ao, C_, C_,
       MDu + PLN + ao, MDu + 3 * PLN + ao, nullptr, nullptr,
       SCO + (size_t)b * NS_ * NS_, NS_, nullptr, nullptr, 0, nullptr, nullptr,
       nullptr, nullptr, nullptr, nullptr, nullptr, nullptr, C_, M_, M_, 2.0f);
  }
  edge_kernel<<<32, 256, 0, stream>>>(LSN0, LSN1, SCO);
  lse_row_kernel<<<2048, 256, 0, stream>>>(SCO, LS0, RT);
  colred1_kernel<<<dim3(8, 8, 4), 256, 0, stream>>>(SCO, PM, PL);
  colred2_kernel<<<32, 256, 0, stream>>>(PM, PL, LS1, CT);
  upd_rowargmax_kernel<<<2048, 256, 0, stream>>>(RT, CT, SCO, MAX0, AM0);
  colamax1_kernel<<<dim3(8, 8, 4), 256, 0, stream>>>(SCO, PV, PI);
  colamax2_kernel<<<32, 256, 0, stream>>>(PV, PI, AM1);
  match0ws_kernel<<<32, 256, 0, stream>>>(AM0, AM1, MAX0, MS0F, VAL0);
  finalout_kernel<<<32, 256, 0, stream>>>(AM0, AM1, MS0F, VAL0, ofp);

  (void)in_sizes; (void)n_in; (void)out_size; (void)ws_size;
}